// Round 9
// baseline (837.642 us; speedup 1.0000x reference)
//
#include <hip/hip_runtime.h>
#include <math.h>

// ---------------------------------------------------------------------------
// MeshGraphUnet2 forward on gfx950.  Round 16: level-0 CSR via counting-sort
// with 40KB LDS histograms (SUBR=10000 -> 4 blocks/CU, fixing round-7's 8%
// occupancy).  CSR neighbor ORDER IS FREE (all consumers are sums / aligned
// remaps), so no rank capture is needed — deg_rank/rank_scatter (the last
// throughput-pinned device atomics, 85us) are deleted.  Keeps: derived CSR
// for levels 1-3, split agg gathers, dual-table + zero row, idxup3, fused
// tie_select, parallel-scan finds, preamble zeroing, gemm3+LN fusion,
// ln+score fusion, 2-pass scan.
// ---------------------------------------------------------------------------

typedef unsigned short u16;
typedef short bf16x8 __attribute__((ext_vector_type(8)));
typedef float f32x4 __attribute__((ext_vector_type(4)));

#define HIST_STRIDE (2 * 65536 + 512)
#define NB 64        // edge chunks (power of 2)
#define NB_LOG 6
#define SUBR 10000   // node sub-range per LDS histogram (40000 B -> 4 blk/CU)

__device__ __forceinline__ unsigned int fkey(float f) {
  unsigned int b = __float_as_uint(f);
  return (b & 0x80000000u) ? ~b : (b | 0x80000000u);  // monotonic float->uint
}

__device__ __forceinline__ float gelu_f(float v) {
  return 0.5f * v * (1.0f + erff(v * 0.70710678118654752f));
}

__device__ __forceinline__ u16 f2bf(float f) {
  unsigned u = __float_as_uint(f);
  u = (u + 0x7FFFu + ((u >> 16) & 1u)) >> 16;  // round-nearest-even
  return (u16)u;
}
__device__ __forceinline__ float bf2f(u16 u) {
  return __uint_as_float(((unsigned)u) << 16);
}

// ---- level-0 scoring: key[i] = (float)(x[i,:].w) f64, valt = tanh(d/||w||)
__global__ void score_kernel(const float* __restrict__ x, const float* __restrict__ w,
                             float* __restrict__ key, float* __restrict__ valt, int n) {
  int wave = threadIdx.x >> 6, lane = threadIdx.x & 63;
  int i = blockIdx.x * 4 + wave;
  if (i >= n) return;
  float2 xv = *(const float2*)&x[(size_t)i * 128 + lane * 2];
  float2 wv = *(const float2*)&w[lane * 2];
  double d  = (double)xv.x * wv.x + (double)xv.y * wv.y;
  double nw = (double)wv.x * wv.x + (double)wv.y * wv.y;
  for (int o = 32; o; o >>= 1) { d += __shfl_down(d, o, 64); nw += __shfl_down(nw, o, 64); }
  if (lane == 0) {
    key[i]  = (float)d;
    valt[i] = (float)tanh(d / sqrt(nw));
  }
}

// fused one-time preamble: xconv + wconv + wnorm + zero dummy rows +
// zero all 3 hist regions.
__global__ void preamble_kernel(const float* __restrict__ x, u16* __restrict__ xb, int n,
                                const float* __restrict__ uW1, const float* __restrict__ uW2,
                                const float* __restrict__ uW3, u16* __restrict__ wt1,
                                u16* __restrict__ wt2, u16* __restrict__ wt3,
                                const float* __restrict__ poolw, double* __restrict__ sqn,
                                u16* __restrict__ z0, u16* __restrict__ z1,
                                u16* __restrict__ z2, int* __restrict__ histAll,
                                int nbX, int nbHZ, int nHist) {
  int b = blockIdx.x;
  if (b < nbX) {  // xconv
    int gid = b * 256 + threadIdx.x;
    if (gid < n * 32) {
      float4 a = *(const float4*)&x[(size_t)gid * 4];
      *(ushort4*)&xb[(size_t)gid * 4] =
          make_ushort4(f2bf(a.x), f2bf(a.y), f2bf(a.z), f2bf(a.w));
    }
    return;
  }
  b -= nbX;
  if (b < 768) {  // wconv: 3*65536 elements exactly
    int i = b * 256 + threadIdx.x;
    int lvl = i >> 16, rem = i & 65535;
    if (rem < 32768) {  // W1: [256][128] -> [128][256]
      int k = rem >> 7, c = rem & 127;
      wt1[(size_t)lvl * 32768 + c * 256 + k] = f2bf(uW1[(size_t)lvl * 32768 + rem]);
    } else if (rem < 49152) {
      int j = rem - 32768; int k = j >> 7, c = j & 127;
      wt2[(size_t)lvl * 16384 + c * 128 + k] = f2bf(uW2[(size_t)lvl * 16384 + j]);
    } else {
      int j = rem - 49152; int k = j >> 7, c = j & 127;
      wt3[(size_t)lvl * 16384 + c * 128 + k] = f2bf(uW3[(size_t)lvl * 16384 + j]);
    }
    return;
  }
  b -= 768;
  if (b == 0) {  // wnorm (one wave)
    if (threadIdx.x < 64) {
      int lane = threadIdx.x;
      for (int l = 0; l < 3; ++l) {
        float2 wv = *(const float2*)&poolw[l * 128 + lane * 2];
        double nw = (double)wv.x * wv.x + (double)wv.y * wv.y;
        for (int o = 32; o; o >>= 1) nw += __shfl_down(nw, o, 64);
        if (lane == 0) sqn[l] = sqrt(nw);
      }
    }
    return;
  }
  b -= 1;
  if (b == 0) {  // zero dummy rows (128 u16 each)
    int t = threadIdx.x;
    if (t < 128) { z0[t] = 0; z1[t] = 0; z2[t] = 0; }
    return;
  }
  b -= 1;
  {  // zero hist regions
    int i = b * 256 + threadIdx.x;
    if (i < nHist) histAll[i] = 0;
  }
}

// ---- histograms; csum accumulated in LDS per block, flushed with few atomics ----
__global__ void hist_hi_kernel(const float* __restrict__ key, int* __restrict__ hist,
                               int* __restrict__ csum, int n) {
  __shared__ int lc[256];
  lc[threadIdx.x] = 0;
  __syncthreads();
  int i = blockIdx.x * 256 + threadIdx.x;
  if (i < n) {
    unsigned b = fkey(key[i]) >> 16;
    atomicAdd(&hist[b], 1);
    atomicAdd(&lc[b >> 8], 1);
  }
  __syncthreads();
  int v = lc[threadIdx.x];
  if (v) atomicAdd(&csum[threadIdx.x], v);
}

__global__ void hist_lo_kernel(const float* __restrict__ key, const int* __restrict__ meta,
                               int* __restrict__ hist, int* __restrict__ csum, int n) {
  __shared__ int lc[256];
  lc[threadIdx.x] = 0;
  __syncthreads();
  int i = blockIdx.x * 256 + threadIdx.x;
  if (i < n) {
    unsigned u = fkey(key[i]);
    if ((u >> 16) == (unsigned)meta[0]) {
      unsigned b = u & 0xFFFFu;
      atomicAdd(&hist[b], 1);
      atomicAdd(&lc[b >> 8], 1);
    }
  }
  __syncthreads();
  int v = lc[threadIdx.x];
  if (v) atomicAdd(&csum[threadIdx.x], v);
}

// parallel suffix inclusive scan over 256 LDS ints
__device__ __forceinline__ void suffix_scan256(int* sA, int t) {
  for (int o = 1; o < 256; o <<= 1) {
    int add = (t + o < 256) ? sA[t + o] : 0;
    __syncthreads();
    sA[t] += add;
    __syncthreads();
  }
}

__global__ void find_hi2_kernel(const int* __restrict__ hist, const int* __restrict__ csum,
                                int* __restrict__ meta, int k) {
  __shared__ int sA[256];
  __shared__ int cSh, cumSh;
  int t = threadIdx.x;
  sA[t] = csum[t];
  __syncthreads();
  suffix_scan256(sA, t);
  int nxt = (t == 255) ? 0 : sA[t + 1];
  if (sA[t] >= k && nxt < k) { cSh = t; cumSh = nxt; }
  __syncthreads();
  int c = cSh;
  int k2 = k - cumSh;
  sA[t] = hist[c * 256 + t];
  __syncthreads();
  suffix_scan256(sA, t);
  nxt = (t == 255) ? 0 : sA[t + 1];
  if (sA[t] >= k2 && nxt < k2) {
    meta[0] = c * 256 + t;
    meta[1] = k2 - nxt;
  }
}

__global__ void find_lo2_kernel(const int* __restrict__ hist, const int* __restrict__ csum,
                                int* __restrict__ meta) {
  __shared__ int sA[256];
  __shared__ int cSh, cumSh;
  int t = threadIdx.x;
  int m = meta[1], B = meta[0];
  sA[t] = csum[t];
  __syncthreads();
  suffix_scan256(sA, t);
  int nxt = (t == 255) ? 0 : sA[t + 1];
  if (sA[t] >= m && nxt < m) { cSh = t; cumSh = nxt; }
  __syncthreads();
  int c = cSh;
  int m2 = m - cumSh;
  sA[t] = hist[c * 256 + t];
  __syncthreads();
  suffix_scan256(sA, t);
  nxt = (t == 255) ? 0 : sA[t + 1];
  if (sA[t] >= m2 && nxt < m2) {
    meta[3] = (int)((((unsigned)B) << 16) | (unsigned)(c * 256 + t));
    meta[4] = m2 - nxt;
  }
  if (t == 0) meta[5] = 0;
}

__global__ void tie_count_kernel(const float* __restrict__ key, const int* __restrict__ meta,
                                 int* __restrict__ tcnt, int n) {
  __shared__ int cnt[4];
  unsigned uT = (unsigned)meta[3];
  int i = blockIdx.x * 256 + threadIdx.x;
  bool tie = (i < n) && (fkey(key[i]) == uT);
  unsigned long long m = __ballot(tie);
  int lane = threadIdx.x & 63, w = threadIdx.x >> 6;
  if (lane == 0) cnt[w] = __popcll(m);
  __syncthreads();
  if (threadIdx.x == 0) tcnt[blockIdx.x] = cnt[0] + cnt[1] + cnt[2] + cnt[3];
}

// fused tie-mark + select: block prefix over tcnt (nb <= 256), per-thread
// selection decision, atomic slot assignment.  Grid covers i in [0, n].
__global__ void tie_select_kernel(const float* __restrict__ key, const float* __restrict__ valt,
                                  const int* __restrict__ tcnt, int* __restrict__ meta,
                                  int* __restrict__ perm, float* __restrict__ vals,
                                  int* __restrict__ nmap, int n, int k) {
  __shared__ int red[256];
  __shared__ int woff[4];
  int t = threadIdx.x;
  red[t] = (t < (int)blockIdx.x) ? tcnt[t] : 0;
  __syncthreads();
  for (int s = 128; s; s >>= 1) {
    if (t < s) red[t] += red[t + s];
    __syncthreads();
  }
  int blockbase = red[0];
  unsigned uT = (unsigned)meta[3];
  int tsel = meta[4];
  int i = blockIdx.x * 256 + t;
  unsigned u = (i < n) ? fkey(key[i]) : 0u;
  bool tie = (i < n) && (u == uT);
  unsigned long long m = __ballot(tie);
  int lane = t & 63, w = t >> 6;
  if (lane == 0) woff[w] = __popcll(m);
  __syncthreads();
  if (t == 0) {
    int c = 0;
    for (int q = 0; q < 4; ++q) { int v = woff[q]; woff[q] = c; c += v; }
  }
  __syncthreads();
  if (i > n) return;
  if (i == n) { nmap[n] = k; return; }
  bool sel;
  if (tie) {
    int pre = __popcll(m & ((1ull << lane) - 1ull));
    int rank = blockbase + woff[w] + pre;
    sel = (rank < tsel);
  } else {
    sel = (u > uT);
  }
  if (sel) {
    int slot = atomicAdd(&meta[5], 1);
    perm[slot] = i; vals[slot] = valt[i]; nmap[i] = slot;
  } else {
    nmap[i] = k;
  }
}

__global__ void pool_kernel(const float* __restrict__ x, const int* __restrict__ perm,
                            const float* __restrict__ vals, float* __restrict__ xp, int k) {
  int gid = blockIdx.x * 256 + threadIdx.x;
  int t = gid >> 5;
  if (t >= k) return;
  int c = (gid & 31) << 2;
  float v = vals[t];
  float4 a = *(const float4*)&x[(size_t)perm[t] * 128 + c];
  a.x *= v; a.y *= v; a.z *= v; a.w *= v;
  *(float4*)&xp[(size_t)t * 128 + c] = a;
}

// ---- level-0 CSR: deterministic counting sort, 40KB LDS histograms ----
__global__ void csr_count_kernel(const int* __restrict__ s, const int* __restrict__ r,
                                 int* __restrict__ H, int N, int E, int CH) {
  __shared__ int cnt[SUBR];
  int b = blockIdx.x & (NB - 1);
  int sub = blockIdx.x >> NB_LOG;
  int base = sub * SUBR;
  int top = base + SUBR; if (top > N) top = N;
  int span = top - base;
  for (int t = threadIdx.x; t < span; t += 256) cnt[t] = 0;
  __syncthreads();
  int lo = b * CH, hi = lo + CH; if (hi > E) hi = E;
  for (int e = lo + threadIdx.x; e < hi; e += 256) {
    int sv = s[e], rv = r[e];
    if ((unsigned)(rv - base) < (unsigned)span) atomicAdd(&cnt[rv - base], 1);
    if ((unsigned)(sv - base) < (unsigned)span) atomicAdd(&cnt[sv - base], 1);
  }
  __syncthreads();
  int* Hb = H + (size_t)b * N + base;
  for (int t = threadIdx.x; t < span; t += 256) Hb[t] = cnt[t];
}

// column-sum of H -> deg, plus per-256-block partial sums (fused scan_part)
__global__ void colsum_part_kernel(const int* __restrict__ H, int* __restrict__ deg,
                                   int* __restrict__ bsum, int n) {
  __shared__ int l[256];
  int i = blockIdx.x * 256 + threadIdx.x;
  int v = 0;
  if (i < n) {
#pragma unroll 4
    for (int b = 0; b < NB; ++b) v += H[(size_t)b * n + i];
    deg[i] = v;
  }
  l[threadIdx.x] = (i < n) ? v : 0;
  __syncthreads();
  for (int s = 128; s; s >>= 1) {
    if (threadIdx.x < s) l[threadIdx.x] += l[threadIdx.x + s];
    __syncthreads();
  }
  if (threadIdx.x == 0) bsum[blockIdx.x] = l[0];
}

// scan_final + H rewrite: off[i] from 2-level scan, then H[b][i] becomes the
// absolute base for chunk b at node i (exclusive running sum over b).
__global__ void scanfix_kernel(const int* __restrict__ deg, const int* __restrict__ bsum,
                               int* __restrict__ off, int* __restrict__ H, int n) {
  __shared__ int red[256];
  __shared__ int l[256];
  int i = blockIdx.x * 256 + threadIdx.x;
  int t = threadIdx.x;
  red[t] = (t < (int)blockIdx.x) ? bsum[t] : 0;
  __syncthreads();
  for (int s = 128; s; s >>= 1) {
    if (t < s) red[t] += red[t + s];
    __syncthreads();
  }
  int base = red[0];
  int v = (i < n) ? deg[i] : 0;
  l[t] = v;
  __syncthreads();
#pragma unroll
  for (int s = 1; s < 256; s <<= 1) {
    int add = (t >= s) ? l[t - s] : 0;
    __syncthreads();
    l[t] += add;
    __syncthreads();
  }
  int incl = l[t];
  if (i < n) {
    int e = base + incl - v;
    off[i] = e;
    if (i == n - 1) off[n] = base + incl;
    int run = e;
#pragma unroll 4
    for (int b = 0; b < NB; ++b) {
      size_t id = (size_t)b * n + i;
      int tv = H[id];
      H[id] = run;
      run += tv;
    }
  }
}

// scatter replay: LDS counter gives local rank; pos = H[b][v] + local.
__global__ void csr_scatter_lds_kernel(const int* __restrict__ s, const int* __restrict__ r,
                                       const int* __restrict__ H, int* __restrict__ idx,
                                       int N, int E, int CH) {
  __shared__ int cnt[SUBR];
  int b = blockIdx.x & (NB - 1);
  int sub = blockIdx.x >> NB_LOG;
  int base = sub * SUBR;
  int top = base + SUBR; if (top > N) top = N;
  int span = top - base;
  for (int t = threadIdx.x; t < span; t += 256) cnt[t] = 0;
  __syncthreads();
  int lo = b * CH, hi = lo + CH; if (hi > E) hi = E;
  const int* Hb = H + (size_t)b * N;
  for (int e = lo + threadIdx.x; e < hi; e += 256) {
    int sv = s[e], rv = r[e];
    if ((unsigned)(rv - base) < (unsigned)span) {
      int loc = atomicAdd(&cnt[rv - base], 1);
      idx[Hb[rv] + loc] = sv;
    }
    if ((unsigned)(sv - base) < (unsigned)span) {
      int loc = atomicAdd(&cnt[sv - base], 1);
      idx[Hb[sv] + loc] = rv;
    }
  }
}

// ---- derived CSR (levels 1-3): wave per next-level node scans parent row ----
// deg[v] = |{ u in rowP(perm[v]) : nm[u] < k }|
__global__ void derive_deg_kernel(const int* __restrict__ permL, const int* __restrict__ nm,
                                  const int* __restrict__ offP, const int* __restrict__ idxP,
                                  int* __restrict__ deg, int k) {
  int wave = threadIdx.x >> 6, lane = threadIdx.x & 63;
  int v = blockIdx.x * 4 + wave;
  if (v >= k) return;
  int p = permL[v];
  int lo = __builtin_amdgcn_readfirstlane(offP[p]);
  int hi = __builtin_amdgcn_readfirstlane(offP[p + 1]);
  int cnt = 0;
  for (int j0 = lo; j0 < hi; j0 += 64) {
    int j = j0 + lane;
    bool ok = (j < hi) && (nm[idxP[j]] < k);
    unsigned long long msk = __ballot(ok);
    cnt += __popcll(msk);
  }
  if (lane == 0) deg[v] = cnt;
}

// idxL row of v = compacted { nm[u] : u in rowP(perm[v]), nm[u] < k }
__global__ void derive_fill_kernel(const int* __restrict__ permL, const int* __restrict__ nm,
                                   const int* __restrict__ offP, const int* __restrict__ idxP,
                                   const int* __restrict__ offL, int* __restrict__ idxL,
                                   int k) {
  int wave = threadIdx.x >> 6, lane = threadIdx.x & 63;
  int v = blockIdx.x * 4 + wave;
  if (v >= k) return;
  int p = permL[v];
  int lo = __builtin_amdgcn_readfirstlane(offP[p]);
  int hi = __builtin_amdgcn_readfirstlane(offP[p + 1]);
  int base = __builtin_amdgcn_readfirstlane(offL[v]);
  for (int j0 = lo; j0 < hi; j0 += 64) {
    int j = j0 + lane;
    int m = k;
    if (j < hi) m = nm[idxP[j]];
    bool ok = m < k;
    unsigned long long msk = __ballot(ok);
    int rank = __popcll(msk & ((1ull << lane) - 1ull));
    if (ok) idxL[base + rank] = m;
    base += __popcll(msk);
  }
}

// ---- 2-pass parallel exclusive scan (self-prefix final; nb <= 256) ----
__global__ void scan_part_kernel(const int* __restrict__ deg, int* __restrict__ bsum, int n) {
  __shared__ int l[256];
  int i = blockIdx.x * 256 + threadIdx.x;
  l[threadIdx.x] = (i < n) ? deg[i] : 0;
  __syncthreads();
  for (int s = 128; s; s >>= 1) {
    if (threadIdx.x < s) l[threadIdx.x] += l[threadIdx.x + s];
    __syncthreads();
  }
  if (threadIdx.x == 0) bsum[blockIdx.x] = l[0];
}

__global__ void scan_final_kernel(const int* __restrict__ deg, const int* __restrict__ bsum,
                                  int* __restrict__ off, int n) {
  __shared__ int red[256];
  __shared__ int l[256];
  int i = blockIdx.x * 256 + threadIdx.x;
  int t = threadIdx.x;
  red[t] = (t < (int)blockIdx.x) ? bsum[t] : 0;
  __syncthreads();
  for (int s = 128; s; s >>= 1) {
    if (t < s) red[t] += red[t + s];
    __syncthreads();
  }
  int base = red[0];
  int v = (i < n) ? deg[i] : 0;
  l[t] = v;
  __syncthreads();
#pragma unroll
  for (int s = 1; s < 256; s <<= 1) {
    int add = (t >= s) ? l[t - s] : 0;
    __syncthreads();
    l[t] += add;
    __syncthreads();
  }
  int incl = l[t];
  if (i < n) {
    int e = base + incl - v;
    off[i] = e;
    if (i == n - 1) off[n] = base + incl;
  }
}

// fused 1-hop remap for the up gather: idxu[j] = nmap[idx[j]] for 3 levels
__global__ void idxup3_kernel(const int* __restrict__ idxA, const int* __restrict__ nmA,
                              const int* __restrict__ lenA, int* __restrict__ outA,
                              const int* __restrict__ idxB, const int* __restrict__ nmB,
                              const int* __restrict__ lenB, int* __restrict__ outB,
                              const int* __restrict__ idxC, const int* __restrict__ nmC,
                              const int* __restrict__ lenC, int* __restrict__ outC,
                              int nbSeg, int maxlen) {
  int seg = blockIdx.x / nbSeg;
  int j = (blockIdx.x - seg * nbSeg) * 256 + threadIdx.x;
  if (j >= maxlen) return;
  const int* idx; const int* nm; const int* len; int* out;
  if (seg == 0)      { idx = idxA; nm = nmA; len = lenA; out = outA; }
  else if (seg == 1) { idx = idxB; nm = nmB; len = lenB; out = outB; }
  else               { idx = idxC; nm = nmC; len = lenC; out = outC; }
  if (j >= len[0]) return;
  out[j] = nm[idx[j]];
}

// ---- down-path f32 aggregation (512B rows, 2 rows per wave-load pair) ----
__global__ void agg_kernel(const float* __restrict__ x, const int* __restrict__ off,
                           const int* __restrict__ idx, float* __restrict__ agg, int n) {
  int wave = threadIdx.x >> 6, lane = threadIdx.x & 63;
  int v = blockIdx.x * 4 + wave;
  if (v >= n) return;
  int lo = __builtin_amdgcn_readfirstlane(off[v]);
  int hi = __builtin_amdgcn_readfirstlane(off[v + 1]);
  int g = lane >> 5, sl = lane & 31;
  const float* bp = x + sl * 4;
  float4 acc = {0.f, 0.f, 0.f, 0.f};
#define ACC_F(EE)                                        \
  do {                                                   \
    float4 w_ = *(const float4*)(bp + (size_t)(EE) * 128);\
    acc.x += w_.x; acc.y += w_.y; acc.z += w_.z; acc.w += w_.w; \
  } while (0)
  int j = lo;
  for (; j + 8 <= hi; j += 8) {
    int q0 = idx[j],     q1 = idx[j + 1], q2 = idx[j + 2], q3 = idx[j + 3];
    int q4 = idx[j + 4], q5 = idx[j + 5], q6 = idx[j + 6], q7 = idx[j + 7];
    ACC_F(g ? q1 : q0);
    ACC_F(g ? q3 : q2);
    ACC_F(g ? q5 : q4);
    ACC_F(g ? q7 : q6);
  }
  for (; j + 2 <= hi; j += 2) {
    int q0 = idx[j], q1 = idx[j + 1];
    ACC_F(g ? q1 : q0);
  }
  if (j < hi) {
    int q0 = idx[j];
    if (!g) ACC_F(q0);
  }
#undef ACC_F
  acc.x += __shfl_xor(acc.x, 32, 64);
  acc.y += __shfl_xor(acc.y, 32, 64);
  acc.z += __shfl_xor(acc.z, 32, 64);
  acc.w += __shfl_xor(acc.w, 32, 64);
  if (!g) *(float4*)&agg[(size_t)v * 128 + sl * 4] = acc;
}

// ---- up-path gather-sum over ONE 256B-row bf16 table ----
template <int OFS>
__global__ void agg_gather_kernel(const u16* __restrict__ tab, const int* __restrict__ idx,
                                  const int* __restrict__ off, u16* __restrict__ agg, int n) {
  int wave = threadIdx.x >> 6, lane = threadIdx.x & 63;
  int v = blockIdx.x * 4 + wave;
  if (v >= n) return;
  int lo = __builtin_amdgcn_readfirstlane(off[v]);
  int hi = __builtin_amdgcn_readfirstlane(off[v + 1]);
  int g = lane >> 4, sl = lane & 15;
  const u16* bp = tab + sl * 8;
  float4 a0 = {0.f, 0.f, 0.f, 0.f}, a1 = {0.f, 0.f, 0.f, 0.f};

#define ACC_ROW(EE)                                     \
  do {                                                  \
    uint4 wq = *(const uint4*)(bp + (size_t)(EE) * 128);\
    a0.x += __uint_as_float(wq.x << 16);                \
    a0.y += __uint_as_float(wq.x & 0xffff0000u);        \
    a0.z += __uint_as_float(wq.y << 16);                \
    a0.w += __uint_as_float(wq.y & 0xffff0000u);        \
    a1.x += __uint_as_float(wq.z << 16);                \
    a1.y += __uint_as_float(wq.z & 0xffff0000u);        \
    a1.z += __uint_as_float(wq.w << 16);                \
    a1.w += __uint_as_float(wq.w & 0xffff0000u);        \
  } while (0)

  int j = lo;
  for (; j + 16 <= hi; j += 16) {
    int e0 = idx[j + g];
    int e1 = idx[j + g + 4];
    int e2 = idx[j + g + 8];
    int e3 = idx[j + g + 12];
    ACC_ROW(e0); ACC_ROW(e1); ACC_ROW(e2); ACC_ROW(e3);
  }
  for (; j + 4 <= hi; j += 4) {
    int e0 = idx[j + g];
    ACC_ROW(e0);
  }
  int rmn = hi - j;
  if (g < rmn) {
    int e = idx[j + g];
    ACC_ROW(e);
  }
#undef ACC_ROW

  a0.x += __shfl_xor(a0.x, 16, 64);
  a0.y += __shfl_xor(a0.y, 16, 64);
  a0.z += __shfl_xor(a0.z, 16, 64);
  a0.w += __shfl_xor(a0.w, 16, 64);
  a1.x += __shfl_xor(a1.x, 16, 64);
  a1.y += __shfl_xor(a1.y, 16, 64);
  a1.z += __shfl_xor(a1.z, 16, 64);
  a1.w += __shfl_xor(a1.w, 16, 64);
  a0.x += __shfl_xor(a0.x, 32, 64);
  a0.y += __shfl_xor(a0.y, 32, 64);
  a0.z += __shfl_xor(a0.z, 32, 64);
  a0.w += __shfl_xor(a0.w, 32, 64);
  a1.x += __shfl_xor(a1.x, 32, 64);
  a1.y += __shfl_xor(a1.y, 32, 64);
  a1.z += __shfl_xor(a1.z, 32, 64);
  a1.w += __shfl_xor(a1.w, 32, 64);

  if (lane < 16) {
    bf16x8 ov;
    ov[0] = (short)f2bf(a0.x); ov[1] = (short)f2bf(a0.y);
    ov[2] = (short)f2bf(a0.z); ov[3] = (short)f2bf(a0.w);
    ov[4] = (short)f2bf(a1.x); ov[5] = (short)f2bf(a1.y);
    ov[6] = (short)f2bf(a1.z); ov[7] = (short)f2bf(a1.w);
    *(bf16x8*)&agg[(size_t)v * 256 + OFS + sl * 8] = ov;
  }
}

// ---- down-path f32 GEMM (CIN=128), 32-row tile ----
template <bool GELU>
__global__ __launch_bounds__(256) void gemm_kernel(const float* __restrict__ A,
                                                   const float* __restrict__ W,
                                                   const float* __restrict__ bias,
                                                   float* __restrict__ out, int n) {
  __shared__ float As[32 * 32];
  __shared__ float Ws[32 * 128];
  int t = threadIdx.x;
  int row0 = blockIdx.x * 32;
  int colg = (t & 31) << 2;
  int rowg = (t >> 5) << 2;
  float acc[4][4];
#pragma unroll
  for (int i = 0; i < 4; ++i)
#pragma unroll
    for (int j = 0; j < 4; ++j) acc[i][j] = 0.f;

  for (int k0 = 0; k0 < 128; k0 += 32) {
    __syncthreads();
    {
      int ar = t >> 3, ac = (t & 7) << 2;
      float4 av = make_float4(0.f, 0.f, 0.f, 0.f);
      if (row0 + ar < n) av = *(const float4*)&A[(size_t)(row0 + ar) * 128 + k0 + ac];
      *(float4*)&As[ar * 32 + ac] = av;
    }
#pragma unroll
    for (int l = 0; l < 4; ++l) {
      int id = t + l * 256;
      int kk = id >> 5, wc = (id & 31) << 2;
      *(float4*)&Ws[kk * 128 + wc] = *(const float4*)&W[(size_t)(k0 + kk) * 128 + wc];
    }
    __syncthreads();
#pragma unroll
    for (int kk = 0; kk < 32; kk += 4) {
      float4 wv[4];
#pragma unroll
      for (int j = 0; j < 4; ++j) wv[j] = *(const float4*)&Ws[(kk + j) * 128 + colg];
#pragma unroll
      for (int i = 0; i < 4; ++i) {
        float4 av = *(const float4*)&As[(rowg + i) * 32 + kk];
        acc[i][0] += av.x * wv[0].x + av.y * wv[1].x + av.z * wv[2].x + av.w * wv[3].x;
        acc[i][1] += av.x * wv[0].y + av.y * wv[1].y + av.z * wv[2].y + av.w * wv[3].y;
        acc[i][2] += av.x * wv[0].z + av.y * wv[1].z + av.z * wv[2].z + av.w * wv[3].z;
        acc[i][3] += av.x * wv[0].w + av.y * wv[1].w + av.z * wv[2].w + av.w * wv[3].w;
      }
    }
  }
  float4 bv = *(const float4*)&bias[colg];
#pragma unroll
  for (int i = 0; i < 4; ++i) {
    int rr = row0 + rowg + i;
    if (rr < n) {
      float4 o = make_float4(acc[i][0] + bv.x, acc[i][1] + bv.y, acc[i][2] + bv.z, acc[i][3] + bv.w);
      if (GELU) { o.x = gelu_f(o.x); o.y = gelu_f(o.y); o.z = gelu_f(o.z); o.w = gelu_f(o.w); }
      *(float4*)&out[(size_t)rr * 128 + colg] = o;
    }
  }
}

// ---- up-path MFMA GEMM (gelu, bf16 out) ----
template <int K>
__global__ __launch_bounds__(256) void gemm_mfma_kernel(const u16* __restrict__ A,
                                                        const u16* __restrict__ WT,
                                                        const float* __restrict__ bias,
                                                        u16* __restrict__ out, int n) {
  __shared__ u16 As[64 * 72];
  __shared__ u16 Ws[128 * 72];
  int t = threadIdx.x;
  int lane = t & 63, wave = t >> 6;
  int row0 = blockIdx.x * 64;
  f32x4 acc[8];
#pragma unroll
  for (int i = 0; i < 8; ++i) acc[i] = (f32x4){0.f, 0.f, 0.f, 0.f};

  for (int k0 = 0; k0 < K; k0 += 64) {
    __syncthreads();
#pragma unroll
    for (int i = 0; i < 2; ++i) {
      int c = t + i * 256;
      int r = c >> 3, seg = c & 7;
      bf16x8 v = {0, 0, 0, 0, 0, 0, 0, 0};
      if (row0 + r < n) v = *(const bf16x8*)&A[(size_t)(row0 + r) * K + k0 + seg * 8];
      *(bf16x8*)&As[r * 72 + seg * 8] = v;
    }
#pragma unroll
    for (int i = 0; i < 4; ++i) {
      int c = t + i * 256;
      int r = c >> 3, seg = c & 7;
      *(bf16x8*)&Ws[r * 72 + seg * 8] = *(const bf16x8*)&WT[(size_t)r * K + k0 + seg * 8];
    }
    __syncthreads();
#pragma unroll
    for (int kk = 0; kk < 64; kk += 32) {
      bf16x8 a = *(const bf16x8*)&As[(wave * 16 + (lane & 15)) * 72 + kk + (lane >> 4) * 8];
#pragma unroll
      for (int ct = 0; ct < 8; ++ct) {
        bf16x8 b = *(const bf16x8*)&Ws[(ct * 16 + (lane & 15)) * 72 + kk + (lane >> 4) * 8];
        acc[ct] = __builtin_amdgcn_mfma_f32_16x16x32_bf16(a, b, acc[ct], 0, 0, 0);
      }
    }
  }
  int colb = lane & 15, rquad = lane >> 4;
#pragma unroll
  for (int ct = 0; ct < 8; ++ct) {
#pragma unroll
    for (int r = 0; r < 4; ++r) {
      int row = row0 + wave * 16 + rquad * 4 + r;
      if (row < n) {
        int col = ct * 16 + colb;
        out[(size_t)row * 128 + col] = f2bf(gelu_f(acc[ct][r] + bias[col]));
      }
    }
  }
}

// ---- up-path MFMA GEMM3 + fused LayerNorm ----
template <bool WF32, bool WBF>
__global__ __launch_bounds__(256) void gemm_mfma_ln_kernel(
    const u16* __restrict__ A, const u16* __restrict__ WT, const float* __restrict__ bias,
    const float* __restrict__ g, const float* __restrict__ beta,
    float* __restrict__ out, u16* __restrict__ outbf, int n) {
  __shared__ u16 As[64 * 72];
  __shared__ u16 Ws[128 * 72];
  int t = threadIdx.x;
  int lane = t & 63, wave = t >> 6;
  int row0 = blockIdx.x * 64;
  f32x4 acc[8];
#pragma unroll
  for (int i = 0; i < 8; ++i) acc[i] = (f32x4){0.f, 0.f, 0.f, 0.f};

  for (int k0 = 0; k0 < 128; k0 += 64) {
    __syncthreads();
#pragma unroll
    for (int i = 0; i < 2; ++i) {
      int c = t + i * 256;
      int r = c >> 3, seg = c & 7;
      bf16x8 v = {0, 0, 0, 0, 0, 0, 0, 0};
      if (row0 + r < n) v = *(const bf16x8*)&A[(size_t)(row0 + r) * 128 + k0 + seg * 8];
      *(bf16x8*)&As[r * 72 + seg * 8] = v;
    }
#pragma unroll
    for (int i = 0; i < 4; ++i) {
      int c = t + i * 256;
      int r = c >> 3, seg = c & 7;
      *(bf16x8*)&Ws[r * 72 + seg * 8] = *(const bf16x8*)&WT[(size_t)r * 128 + k0 + seg * 8];
    }
    __syncthreads();
#pragma unroll
    for (int kk = 0; kk < 64; kk += 32) {
      bf16x8 a = *(const bf16x8*)&As[(wave * 16 + (lane & 15)) * 72 + kk + (lane >> 4) * 8];
#pragma unroll
      for (int ct = 0; ct < 8; ++ct) {
        bf16x8 b = *(const bf16x8*)&Ws[(ct * 16 + (lane & 15)) * 72 + kk + (lane >> 4) * 8];
        acc[ct] = __builtin_amdgcn_mfma_f32_16x16x32_bf16(a, b, acc[ct], 0, 0, 0);
      }
    }
  }
  int colb = lane & 15, rquad = lane >> 4;
  float bv[8], gv[8], bev[8];
#pragma unroll
  for (int ct = 0; ct < 8; ++ct) {
    int col = ct * 16 + colb;
    bv[ct] = bias[col]; gv[ct] = g[col]; bev[ct] = beta[col];
  }
#pragma unroll
  for (int r = 0; r < 4; ++r) {
    float s1 = 0.f;
#pragma unroll
    for (int ct = 0; ct < 8; ++ct) s1 += acc[ct][r] + bv[ct];
#pragma unroll
    for (int o = 1; o <= 8; o <<= 1) s1 += __shfl_xor(s1, o, 64);
    float mu = s1 * (1.0f / 128.0f);
    float s2 = 0.f;
#pragma unroll
    for (int ct = 0; ct < 8; ++ct) { float d = acc[ct][r] + bv[ct] - mu; s2 += d * d; }
#pragma unroll
    for (int o = 1; o <= 8; o <<= 1) s2 += __shfl_xor(s2, o, 64);
    float rs = rsqrtf(s2 * (1.0f / 128.0f) + 1e-5f);
    int row = row0 + wave * 16 + rquad * 4 + r;
    if (row < n) {
#pragma unroll
      for (int ct = 0; ct < 8; ++ct) {
        int col = ct * 16 + colb;
        float o = gv[ct] * (acc[ct][r] + bv[ct] - mu) * rs + bev[ct];
        if (WF32) out[(size_t)row * 128 + col] = o;
        if (WBF)  outbf[(size_t)row * 128 + col] = f2bf(o);
      }
    }
  }
}

// ---- down-path LN (+ optional bf16 copy, + optional fused next-level score) ----
template <bool SCORE, bool WBF>
__global__ void ln_kernel(const float* __restrict__ h, const float* __restrict__ g,
                          const float* __restrict__ beta, float* __restrict__ out,
                          u16* __restrict__ outbf, const float* __restrict__ wnext,
                          const double* __restrict__ sqn, float* __restrict__ key,
                          float* __restrict__ valt, int n) {
  int wave = threadIdx.x >> 6, lane = threadIdx.x & 63;
  int i = blockIdx.x * 4 + wave;
  if (i >= n) return;
  float2 hv = *(const float2*)&h[(size_t)i * 128 + lane * 2];
  float s = hv.x + hv.y;
  for (int o = 32; o; o >>= 1) s += __shfl_down(s, o, 64);
  float mu = __shfl(s, 0, 64) * (1.0f / 128.0f);
  float dx = hv.x - mu, dy = hv.y - mu;
  float q = dx * dx + dy * dy;
  for (int o = 32; o; o >>= 1) q += __shfl_down(q, o, 64);
  float var = __shfl(q, 0, 64) * (1.0f / 128.0f);
  float rs = rsqrtf(var + 1e-5f);
  float2 gv = *(const float2*)&g[lane * 2];
  float2 bv = *(const float2*)&beta[lane * 2];
  float2 o2; o2.x = gv.x * dx * rs + bv.x; o2.y = gv.y * dy * rs + bv.y;
  *(float2*)&out[(size_t)i * 128 + lane * 2] = o2;
  if (WBF)
    *(ushort2*)&outbf[(size_t)i * 128 + lane * 2] = make_ushort2(f2bf(o2.x), f2bf(o2.y));
  if (SCORE) {
    float2 wv = *(const float2*)&wnext[lane * 2];
    double d = (double)o2.x * wv.x + (double)o2.y * wv.y;
    for (int o = 32; o; o >>= 1) d += __shfl_down(d, o, 64);
    if (lane == 0) {
      key[i]  = (float)d;
      valt[i] = (float)tanh(d / sqn[0]);
    }
  }
}

// ---------------------------------------------------------------------------

static inline int cdiv(int a, int b) { return (a + b - 1) / b; }

extern "C" void kernel_launch(void* const* d_in, const int* in_sizes, int n_in,
                              void* d_out, int out_size, void* d_ws, size_t ws_size,
                              hipStream_t stream) {
  const float* x0   = (const float*)d_in[0];
  const int*   snd  = (const int*)d_in[1];
  const int*   rcv  = (const int*)d_in[2];
  const float* poolw = (const float*)d_in[3];
  const float* dW1 = (const float*)d_in[4];
  const float* db1 = (const float*)d_in[5];
  const float* dW2 = (const float*)d_in[6];
  const float* db2 = (const float*)d_in[7];
  const float* dW3 = (const float*)d_in[8];
  const float* db3 = (const float*)d_in[9];
  const float* dg  = (const float*)d_in[10];
  const float* dbe = (const float*)d_in[11];
  const float* uW1 = (const float*)d_in[12];
  const float* ub1 = (const float*)d_in[13];
  const float* uW2 = (const float*)d_in[14];
  const float* ub2 = (const float*)d_in[15];
  const float* uW3 = (const float*)d_in[16];
  const float* ub3 = (const float*)d_in[17];
  const float* ug  = (const float*)d_in[18];
  const float* ube = (const float*)d_in[19];

  const int N0 = in_sizes[0] / 128;
  const int E  = in_sizes[1];
  const int N1 = (N0 + 1) / 2, N2 = (N1 + 1) / 2, N3 = (N2 + 1) / 2;

  // ---- workspace carve ----
  char* p = (char*)d_ws;
  auto alloc = [&](size_t bytes) -> void* {
    void* r = (void*)p;
    p += (bytes + 255) & ~(size_t)255;
    return r;
  };
  float* key  = (float*)alloc((size_t)N0 * 4);
  float* valt = (float*)alloc((size_t)N0 * 4);
  int*   histAll = (int*)alloc((size_t)3 * HIST_STRIDE * 4);
  int*   meta = (int*)alloc(64 * 4);
  int*   tcnt = (int*)alloc(512 * 4);
  int*   bsum = (int*)alloc(256 * 4);
  int*   nm1 = (int*)alloc((size_t)(N0 + 1) * 4);
  int*   nm2 = (int*)alloc((size_t)(N1 + 1) * 4);
  int*   nm3 = (int*)alloc((size_t)(N2 + 1) * 4);
  int*   perm0 = (int*)alloc((size_t)N1 * 4);
  int*   perm1 = (int*)alloc((size_t)N2 * 4);
  int*   perm2 = (int*)alloc((size_t)N3 * 4);
  float* vals  = (float*)alloc((size_t)N1 * 4);
  double* sqn  = (double*)alloc(8 * 8);
  float* x1 = (float*)alloc((size_t)N1 * 128 * 4);
  float* x2 = (float*)alloc((size_t)N2 * 128 * 4);
  float* x3 = (float*)alloc((size_t)N3 * 128 * 4);
  float* xp = (float*)alloc((size_t)N1 * 128 * 4);   // down only; h1b aliases in up
  float* aggf = (float*)alloc((size_t)N1 * 128 * 4);
  float* h1f  = (float*)alloc((size_t)N1 * 128 * 4);
  float* h2f  = (float*)alloc((size_t)N1 * 128 * 4);
  u16* agg_bf = (u16*)alloc((size_t)N0 * 256 * 2);
  u16* res0_bf = (u16*)alloc((size_t)N0 * 128 * 2);
  u16* res1_bf = (u16*)alloc((size_t)N1 * 128 * 2);
  u16* res2_bf = (u16*)alloc((size_t)N2 * 128 * 2);
  u16* x3_bf   = (u16*)alloc((size_t)(N3 + 1) * 128 * 2);  // +1 zero row
  u16* xu2_bf  = (u16*)alloc((size_t)(N2 + 1) * 128 * 2);  // +1 zero row
  u16* xu1_bf  = (u16*)alloc((size_t)(N1 + 1) * 128 * 2);  // +1 zero row
  u16* wt1 = (u16*)alloc((size_t)3 * 128 * 256 * 2);
  u16* wt2 = (u16*)alloc((size_t)3 * 128 * 128 * 2);
  u16* wt3 = (u16*)alloc((size_t)3 * 128 * 128 * 2);
  int* degAll = (int*)alloc((size_t)(N0 + N1 + N2 + N3) * 4);
  int* deg0 = degAll;
  int* deg1 = degAll + N0;
  int* deg2 = deg1 + N1;
  int* deg3 = deg2 + N2;
  int* off0 = (int*)alloc((size_t)(N0 + 1) * 4);
  int* idx0 = (int*)alloc((size_t)2 * E * 4);
  int* off1 = (int*)alloc((size_t)(N1 + 1) * 4);
  int* idx1 = (int*)alloc((size_t)2 * E * 4);
  int* off2 = (int*)alloc((size_t)(N2 + 1) * 4);
  int* idx2 = (int*)alloc((size_t)2 * E * 4);
  int* off3 = (int*)alloc((size_t)(N3 + 1) * 4);
  int* idx3 = (int*)alloc((size_t)2 * E * 4);
  int* idxu0 = (int*)alloc((size_t)2 * E * 4);   // nmap-remapped idx0 (for up lvl 2)
  int* idxu1 = (int*)alloc((size_t)2 * E * 4);   // remapped idx1 (up lvl 1)
  int* idxu2 = (int*)alloc((size_t)2 * E * 4);   // remapped idx2 (up lvl 0)
  int* H = (int*)alloc((size_t)NB * N0 * 4);     // level-0 count/base matrix
  u16* h1b = (u16*)xp;                           // up-phase alias over xp
  u16* h2b = (u16*)alloc((size_t)N0 * 128 * 2);  // up-phase h2 (own buffer)

  auto run_scan = [&](int* degB, int* offB, int n) {
    int nb = cdiv(n, 256);
    scan_part_kernel<<<nb, 256, 0, stream>>>(degB, bsum, n);
    scan_final_kernel<<<nb, 256, 0, stream>>>(degB, bsum, offB, n);
  };

  // ---- fused one-time preamble ----
  {
    int nbX = cdiv(N0 * 32, 256);
    int nHist = 3 * HIST_STRIDE;
    int nbHZ = cdiv(nHist, 256);
    preamble_kernel<<<nbX + 768 + 1 + 1 + nbHZ, 256, 0, stream>>>(
        x0, res0_bf, N0, uW1, uW2, uW3, wt1, wt2, wt3, poolw, sqn,
        x3_bf + (size_t)N3 * 128, xu2_bf + (size_t)N2 * 128,
        xu1_bf + (size_t)N1 * 128, histAll, nbX, nbHZ, nHist);
  }

  // ---- level-0 CSR: counting sort with LDS histograms (no device atomics) ----
  {
    int nSub = cdiv(N0, SUBR);
    int CH = cdiv(E, NB);
    int nbN = cdiv(N0, 256);
    csr_count_kernel<<<NB * nSub, 256, 0, stream>>>(snd, rcv, H, N0, E, CH);
    colsum_part_kernel<<<nbN, 256, 0, stream>>>(H, deg0, bsum, N0);
    scanfix_kernel<<<nbN, 256, 0, stream>>>(deg0, bsum, off0, H, N0);
    csr_scatter_lds_kernel<<<NB * nSub, 256, 0, stream>>>(snd, rcv, H, idx0, N0, E, CH);
  }

  // ---- generic down step: top-k + derived CSR + agg + MLP + LN ----
  auto down_step = [&](int n, int k, const float* xcur, int* permL, int* nmL,
                       float* xnext, u16* xnext_bf, int lvl,
                       const int* offP, const int* idxP,
                       int* offL, int* degL, int* idxL) {
    int nb = cdiv(n, 256);
    int* histL = histAll + (size_t)lvl * HIST_STRIDE;
    int* csum_hi = histL + 2 * 65536;
    int* csum_lo = csum_hi + 256;
    hist_hi_kernel<<<nb, 256, 0, stream>>>(key, histL, csum_hi, n);
    find_hi2_kernel<<<1, 256, 0, stream>>>(histL, csum_hi, meta, k);
    hist_lo_kernel<<<nb, 256, 0, stream>>>(key, meta, histL + 65536, csum_lo, n);
    find_lo2_kernel<<<1, 256, 0, stream>>>(histL + 65536, csum_lo, meta);
    tie_count_kernel<<<nb, 256, 0, stream>>>(key, meta, tcnt, n);
    tie_select_kernel<<<cdiv(n + 1, 256), 256, 0, stream>>>(
        key, valt, tcnt, meta, permL, vals, nmL, n, k);
    pool_kernel<<<cdiv(k * 32, 256), 256, 0, stream>>>(xcur, permL, vals, xp, k);
    derive_deg_kernel<<<cdiv(k, 4), 256, 0, stream>>>(permL, nmL, offP, idxP, degL, k);
    run_scan(degL, offL, k);
    derive_fill_kernel<<<cdiv(k, 4), 256, 0, stream>>>(permL, nmL, offP, idxP, offL, idxL, k);
    agg_kernel<<<cdiv(k, 4), 256, 0, stream>>>(xp, offL, idxL, aggf, k);
    gemm_kernel<true><<<cdiv(k, 32), 256, 0, stream>>>(
        aggf, dW1 + (size_t)lvl * 128 * 128, db1 + (size_t)lvl * 128, h1f, k);
    gemm_kernel<true><<<cdiv(k, 32), 256, 0, stream>>>(
        h1f, dW2 + (size_t)lvl * 128 * 128, db2 + (size_t)lvl * 128, h2f, k);
    gemm_kernel<false><<<cdiv(k, 32), 256, 0, stream>>>(
        h2f, dW3 + (size_t)lvl * 128 * 128, db3 + (size_t)lvl * 128, h1f, k);
    if (lvl < 2)
      ln_kernel<true, true><<<cdiv(k, 4), 256, 0, stream>>>(
          h1f, dg + (size_t)lvl * 128, dbe + (size_t)lvl * 128, xnext, xnext_bf,
          poolw + (size_t)(lvl + 1) * 128, sqn + (lvl + 1), key, valt, k);
    else
      ln_kernel<false, true><<<cdiv(k, 4), 256, 0, stream>>>(
          h1f, dg + (size_t)lvl * 128, dbe + (size_t)lvl * 128, xnext, xnext_bf,
          nullptr, nullptr, nullptr, nullptr, k);
  };

  // level-0 score from x0
  score_kernel<<<cdiv(N0, 4), 256, 0, stream>>>(x0, poolw, key, valt, N0);
  down_step(N0, N1, x0, perm0, nm1, x1, res1_bf, 0, off0, idx0, off1, deg1, idx1);
  down_step(N1, N2, x1, perm1, nm2, x2, res2_bf, 1, off1, idx1, off2, deg2, idx2);
  down_step(N2, N3, x2, perm2, nm3, x3, x3_bf,   2, off2, idx2, off3, deg3, idx3);

  // ---- remapped up-gather indices (1-hop), fused 3 levels ----
  {
    int nbSeg = cdiv(2 * E, 256);
    idxup3_kernel<<<3 * nbSeg, 256, 0, stream>>>(
        idx2, nm3, off2 + N2, idxu2,
        idx1, nm2, off1 + N1, idxu1,
        idx0, nm1, off0 + N0, idxu0, nbSeg, 2 * E);
  }

  // ---- generic up step (split gathers + MFMA GEMM3 + fused LN) ----
  auto up_step = [&](int n, const u16* resb, const u16* xdb, int lvl,
                     const int* offL, const int* idxL, const int* idxUL,
                     bool wantF32, float* outF32, u16* outBF) {
    agg_gather_kernel<0><<<cdiv(n, 4), 256, 0, stream>>>(resb, idxL, offL, agg_bf, n);
    agg_gather_kernel<128><<<cdiv(n, 4), 256, 0, stream>>>(xdb, idxUL, offL, agg_bf, n);
    gemm_mfma_kernel<256><<<cdiv(n, 64), 256, 0, stream>>>(
        agg_bf, wt1 + (size_t)lvl * 128 * 256, ub1 + (size_t)lvl * 128, h1b, n);
    gemm_mfma_kernel<128><<<cdiv(n, 64), 256, 0, stream>>>(
        h1b, wt2 + (size_t)lvl * 128 * 128, ub2 + (size_t)lvl * 128, h2b, n);
    if (wantF32)
      gemm_mfma_ln_kernel<true, false><<<cdiv(n, 64), 256, 0, stream>>>(
          h2b, wt3 + (size_t)lvl * 128 * 128, ub3 + (size_t)lvl * 128,
          ug + (size_t)lvl * 128, ube + (size_t)lvl * 128, outF32, nullptr, n);
    else
      gemm_mfma_ln_kernel<false, true><<<cdiv(n, 64), 256, 0, stream>>>(
          h2b, wt3 + (size_t)lvl * 128 * 128, ub3 + (size_t)lvl * 128,
          ug + (size_t)lvl * 128, ube + (size_t)lvl * 128, nullptr, outBF, n);
  };

  up_step(N2, res2_bf, x3_bf,  0, off2, idx2, idxu2, false, nullptr, xu2_bf);
  up_step(N1, res1_bf, xu2_bf, 1, off1, idx1, idxu1, false, nullptr, xu1_bf);
  up_step(N0, res0_bf, xu1_bf, 2, off0, idx0, idxu0, true, (float*)d_out, nullptr);

  (void)n_in; (void)out_size; (void)ws_size;
}

// Round 10
// 831.239 us; speedup vs baseline: 1.0077x; 1.0077x over previous
//
#include <hip/hip_runtime.h>
#include <math.h>

// ---------------------------------------------------------------------------
// MeshGraphUnet2 forward on gfx950.  Round 17: counting-sort CSR grid scaled
// on both axes — NB=128 chunks x SUBR=5000 (20KB LDS -> 8 blk/CU) x nSub=10
// -> 1280 blocks (round-9's 320 blocks = 1.25/CU was the scatter's latency
// wall; occupancy 10.6%).  H grows to 25.6MB (streaming passes +~10us) but
// the latency-bound count/scatter gain 4x TLP.  Everything else = round-16
// structure verbatim (derived CSR lvl1-3, split agg gathers, dual-table +
// zero row, idxup3, fused tie_select, parallel-scan finds, preamble zeroing,
// gemm3+LN fusion, ln+score fusion, 2-pass scan).
// ---------------------------------------------------------------------------

typedef unsigned short u16;
typedef short bf16x8 __attribute__((ext_vector_type(8)));
typedef float f32x4 __attribute__((ext_vector_type(4)));

#define HIST_STRIDE (2 * 65536 + 512)
#define NB 128       // edge chunks (power of 2)
#define NB_LOG 7
#define SUBR 5000    // node sub-range per LDS histogram (20000 B -> 8 blk/CU)

__device__ __forceinline__ unsigned int fkey(float f) {
  unsigned int b = __float_as_uint(f);
  return (b & 0x80000000u) ? ~b : (b | 0x80000000u);  // monotonic float->uint
}

__device__ __forceinline__ float gelu_f(float v) {
  return 0.5f * v * (1.0f + erff(v * 0.70710678118654752f));
}

__device__ __forceinline__ u16 f2bf(float f) {
  unsigned u = __float_as_uint(f);
  u = (u + 0x7FFFu + ((u >> 16) & 1u)) >> 16;  // round-nearest-even
  return (u16)u;
}
__device__ __forceinline__ float bf2f(u16 u) {
  return __uint_as_float(((unsigned)u) << 16);
}

// ---- level-0 scoring: key[i] = (float)(x[i,:].w) f64, valt = tanh(d/||w||)
__global__ void score_kernel(const float* __restrict__ x, const float* __restrict__ w,
                             float* __restrict__ key, float* __restrict__ valt, int n) {
  int wave = threadIdx.x >> 6, lane = threadIdx.x & 63;
  int i = blockIdx.x * 4 + wave;
  if (i >= n) return;
  float2 xv = *(const float2*)&x[(size_t)i * 128 + lane * 2];
  float2 wv = *(const float2*)&w[lane * 2];
  double d  = (double)xv.x * wv.x + (double)xv.y * wv.y;
  double nw = (double)wv.x * wv.x + (double)wv.y * wv.y;
  for (int o = 32; o; o >>= 1) { d += __shfl_down(d, o, 64); nw += __shfl_down(nw, o, 64); }
  if (lane == 0) {
    key[i]  = (float)d;
    valt[i] = (float)tanh(d / sqrt(nw));
  }
}

// fused one-time preamble: xconv + wconv + wnorm + zero dummy rows +
// zero all 3 hist regions.
__global__ void preamble_kernel(const float* __restrict__ x, u16* __restrict__ xb, int n,
                                const float* __restrict__ uW1, const float* __restrict__ uW2,
                                const float* __restrict__ uW3, u16* __restrict__ wt1,
                                u16* __restrict__ wt2, u16* __restrict__ wt3,
                                const float* __restrict__ poolw, double* __restrict__ sqn,
                                u16* __restrict__ z0, u16* __restrict__ z1,
                                u16* __restrict__ z2, int* __restrict__ histAll,
                                int nbX, int nbHZ, int nHist) {
  int b = blockIdx.x;
  if (b < nbX) {  // xconv
    int gid = b * 256 + threadIdx.x;
    if (gid < n * 32) {
      float4 a = *(const float4*)&x[(size_t)gid * 4];
      *(ushort4*)&xb[(size_t)gid * 4] =
          make_ushort4(f2bf(a.x), f2bf(a.y), f2bf(a.z), f2bf(a.w));
    }
    return;
  }
  b -= nbX;
  if (b < 768) {  // wconv: 3*65536 elements exactly
    int i = b * 256 + threadIdx.x;
    int lvl = i >> 16, rem = i & 65535;
    if (rem < 32768) {  // W1: [256][128] -> [128][256]
      int k = rem >> 7, c = rem & 127;
      wt1[(size_t)lvl * 32768 + c * 256 + k] = f2bf(uW1[(size_t)lvl * 32768 + rem]);
    } else if (rem < 49152) {
      int j = rem - 32768; int k = j >> 7, c = j & 127;
      wt2[(size_t)lvl * 16384 + c * 128 + k] = f2bf(uW2[(size_t)lvl * 16384 + j]);
    } else {
      int j = rem - 49152; int k = j >> 7, c = j & 127;
      wt3[(size_t)lvl * 16384 + c * 128 + k] = f2bf(uW3[(size_t)lvl * 16384 + j]);
    }
    return;
  }
  b -= 768;
  if (b == 0) {  // wnorm (one wave)
    if (threadIdx.x < 64) {
      int lane = threadIdx.x;
      for (int l = 0; l < 3; ++l) {
        float2 wv = *(const float2*)&poolw[l * 128 + lane * 2];
        double nw = (double)wv.x * wv.x + (double)wv.y * wv.y;
        for (int o = 32; o; o >>= 1) nw += __shfl_down(nw, o, 64);
        if (lane == 0) sqn[l] = sqrt(nw);
      }
    }
    return;
  }
  b -= 1;
  if (b == 0) {  // zero dummy rows (128 u16 each)
    int t = threadIdx.x;
    if (t < 128) { z0[t] = 0; z1[t] = 0; z2[t] = 0; }
    return;
  }
  b -= 1;
  {  // zero hist regions
    int i = b * 256 + threadIdx.x;
    if (i < nHist) histAll[i] = 0;
  }
}

// ---- histograms; csum accumulated in LDS per block, flushed with few atomics ----
__global__ void hist_hi_kernel(const float* __restrict__ key, int* __restrict__ hist,
                               int* __restrict__ csum, int n) {
  __shared__ int lc[256];
  lc[threadIdx.x] = 0;
  __syncthreads();
  int i = blockIdx.x * 256 + threadIdx.x;
  if (i < n) {
    unsigned b = fkey(key[i]) >> 16;
    atomicAdd(&hist[b], 1);
    atomicAdd(&lc[b >> 8], 1);
  }
  __syncthreads();
  int v = lc[threadIdx.x];
  if (v) atomicAdd(&csum[threadIdx.x], v);
}

__global__ void hist_lo_kernel(const float* __restrict__ key, const int* __restrict__ meta,
                               int* __restrict__ hist, int* __restrict__ csum, int n) {
  __shared__ int lc[256];
  lc[threadIdx.x] = 0;
  __syncthreads();
  int i = blockIdx.x * 256 + threadIdx.x;
  if (i < n) {
    unsigned u = fkey(key[i]);
    if ((u >> 16) == (unsigned)meta[0]) {
      unsigned b = u & 0xFFFFu;
      atomicAdd(&hist[b], 1);
      atomicAdd(&lc[b >> 8], 1);
    }
  }
  __syncthreads();
  int v = lc[threadIdx.x];
  if (v) atomicAdd(&csum[threadIdx.x], v);
}

// parallel suffix inclusive scan over 256 LDS ints
__device__ __forceinline__ void suffix_scan256(int* sA, int t) {
  for (int o = 1; o < 256; o <<= 1) {
    int add = (t + o < 256) ? sA[t + o] : 0;
    __syncthreads();
    sA[t] += add;
    __syncthreads();
  }
}

__global__ void find_hi2_kernel(const int* __restrict__ hist, const int* __restrict__ csum,
                                int* __restrict__ meta, int k) {
  __shared__ int sA[256];
  __shared__ int cSh, cumSh;
  int t = threadIdx.x;
  sA[t] = csum[t];
  __syncthreads();
  suffix_scan256(sA, t);
  int nxt = (t == 255) ? 0 : sA[t + 1];
  if (sA[t] >= k && nxt < k) { cSh = t; cumSh = nxt; }
  __syncthreads();
  int c = cSh;
  int k2 = k - cumSh;
  sA[t] = hist[c * 256 + t];
  __syncthreads();
  suffix_scan256(sA, t);
  nxt = (t == 255) ? 0 : sA[t + 1];
  if (sA[t] >= k2 && nxt < k2) {
    meta[0] = c * 256 + t;
    meta[1] = k2 - nxt;
  }
}

__global__ void find_lo2_kernel(const int* __restrict__ hist, const int* __restrict__ csum,
                                int* __restrict__ meta) {
  __shared__ int sA[256];
  __shared__ int cSh, cumSh;
  int t = threadIdx.x;
  int m = meta[1], B = meta[0];
  sA[t] = csum[t];
  __syncthreads();
  suffix_scan256(sA, t);
  int nxt = (t == 255) ? 0 : sA[t + 1];
  if (sA[t] >= m && nxt < m) { cSh = t; cumSh = nxt; }
  __syncthreads();
  int c = cSh;
  int m2 = m - cumSh;
  sA[t] = hist[c * 256 + t];
  __syncthreads();
  suffix_scan256(sA, t);
  nxt = (t == 255) ? 0 : sA[t + 1];
  if (sA[t] >= m2 && nxt < m2) {
    meta[3] = (int)((((unsigned)B) << 16) | (unsigned)(c * 256 + t));
    meta[4] = m2 - nxt;
  }
  if (t == 0) meta[5] = 0;
}

__global__ void tie_count_kernel(const float* __restrict__ key, const int* __restrict__ meta,
                                 int* __restrict__ tcnt, int n) {
  __shared__ int cnt[4];
  unsigned uT = (unsigned)meta[3];
  int i = blockIdx.x * 256 + threadIdx.x;
  bool tie = (i < n) && (fkey(key[i]) == uT);
  unsigned long long m = __ballot(tie);
  int lane = threadIdx.x & 63, w = threadIdx.x >> 6;
  if (lane == 0) cnt[w] = __popcll(m);
  __syncthreads();
  if (threadIdx.x == 0) tcnt[blockIdx.x] = cnt[0] + cnt[1] + cnt[2] + cnt[3];
}

// fused tie-mark + select: block prefix over tcnt (nb <= 256), per-thread
// selection decision, atomic slot assignment.  Grid covers i in [0, n].
__global__ void tie_select_kernel(const float* __restrict__ key, const float* __restrict__ valt,
                                  const int* __restrict__ tcnt, int* __restrict__ meta,
                                  int* __restrict__ perm, float* __restrict__ vals,
                                  int* __restrict__ nmap, int n, int k) {
  __shared__ int red[256];
  __shared__ int woff[4];
  int t = threadIdx.x;
  red[t] = (t < (int)blockIdx.x) ? tcnt[t] : 0;
  __syncthreads();
  for (int s = 128; s; s >>= 1) {
    if (t < s) red[t] += red[t + s];
    __syncthreads();
  }
  int blockbase = red[0];
  unsigned uT = (unsigned)meta[3];
  int tsel = meta[4];
  int i = blockIdx.x * 256 + t;
  unsigned u = (i < n) ? fkey(key[i]) : 0u;
  bool tie = (i < n) && (u == uT);
  unsigned long long m = __ballot(tie);
  int lane = t & 63, w = t >> 6;
  if (lane == 0) woff[w] = __popcll(m);
  __syncthreads();
  if (t == 0) {
    int c = 0;
    for (int q = 0; q < 4; ++q) { int v = woff[q]; woff[q] = c; c += v; }
  }
  __syncthreads();
  if (i > n) return;
  if (i == n) { nmap[n] = k; return; }
  bool sel;
  if (tie) {
    int pre = __popcll(m & ((1ull << lane) - 1ull));
    int rank = blockbase + woff[w] + pre;
    sel = (rank < tsel);
  } else {
    sel = (u > uT);
  }
  if (sel) {
    int slot = atomicAdd(&meta[5], 1);
    perm[slot] = i; vals[slot] = valt[i]; nmap[i] = slot;
  } else {
    nmap[i] = k;
  }
}

__global__ void pool_kernel(const float* __restrict__ x, const int* __restrict__ perm,
                            const float* __restrict__ vals, float* __restrict__ xp, int k) {
  int gid = blockIdx.x * 256 + threadIdx.x;
  int t = gid >> 5;
  if (t >= k) return;
  int c = (gid & 31) << 2;
  float v = vals[t];
  float4 a = *(const float4*)&x[(size_t)perm[t] * 128 + c];
  a.x *= v; a.y *= v; a.z *= v; a.w *= v;
  *(float4*)&xp[(size_t)t * 128 + c] = a;
}

// ---- level-0 CSR: deterministic counting sort, 20KB LDS histograms ----
__global__ void csr_count_kernel(const int* __restrict__ s, const int* __restrict__ r,
                                 int* __restrict__ H, int N, int E, int CH) {
  __shared__ int cnt[SUBR];
  int b = blockIdx.x & (NB - 1);
  int sub = blockIdx.x >> NB_LOG;
  int base = sub * SUBR;
  int top = base + SUBR; if (top > N) top = N;
  int span = top - base;
  for (int t = threadIdx.x; t < span; t += 256) cnt[t] = 0;
  __syncthreads();
  int lo = b * CH, hi = lo + CH; if (hi > E) hi = E;
  for (int e = lo + threadIdx.x; e < hi; e += 256) {
    int sv = s[e], rv = r[e];
    if ((unsigned)(rv - base) < (unsigned)span) atomicAdd(&cnt[rv - base], 1);
    if ((unsigned)(sv - base) < (unsigned)span) atomicAdd(&cnt[sv - base], 1);
  }
  __syncthreads();
  int* Hb = H + (size_t)b * N + base;
  for (int t = threadIdx.x; t < span; t += 256) Hb[t] = cnt[t];
}

// column-sum of H -> deg, plus per-256-block partial sums (fused scan_part)
__global__ void colsum_part_kernel(const int* __restrict__ H, int* __restrict__ deg,
                                   int* __restrict__ bsum, int n) {
  __shared__ int l[256];
  int i = blockIdx.x * 256 + threadIdx.x;
  int v = 0;
  if (i < n) {
#pragma unroll 4
    for (int b = 0; b < NB; ++b) v += H[(size_t)b * n + i];
    deg[i] = v;
  }
  l[threadIdx.x] = (i < n) ? v : 0;
  __syncthreads();
  for (int s = 128; s; s >>= 1) {
    if (threadIdx.x < s) l[threadIdx.x] += l[threadIdx.x + s];
    __syncthreads();
  }
  if (threadIdx.x == 0) bsum[blockIdx.x] = l[0];
}

// scan_final + H rewrite: off[i] from 2-level scan, then H[b][i] becomes the
// absolute base for chunk b at node i (exclusive running sum over b).
__global__ void scanfix_kernel(const int* __restrict__ deg, const int* __restrict__ bsum,
                               int* __restrict__ off, int* __restrict__ H, int n) {
  __shared__ int red[256];
  __shared__ int l[256];
  int i = blockIdx.x * 256 + threadIdx.x;
  int t = threadIdx.x;
  red[t] = (t < (int)blockIdx.x) ? bsum[t] : 0;
  __syncthreads();
  for (int s = 128; s; s >>= 1) {
    if (t < s) red[t] += red[t + s];
    __syncthreads();
  }
  int base = red[0];
  int v = (i < n) ? deg[i] : 0;
  l[t] = v;
  __syncthreads();
#pragma unroll
  for (int s = 1; s < 256; s <<= 1) {
    int add = (t >= s) ? l[t - s] : 0;
    __syncthreads();
    l[t] += add;
    __syncthreads();
  }
  int incl = l[t];
  if (i < n) {
    int e = base + incl - v;
    off[i] = e;
    if (i == n - 1) off[n] = base + incl;
    int run = e;
#pragma unroll 4
    for (int b = 0; b < NB; ++b) {
      size_t id = (size_t)b * n + i;
      int tv = H[id];
      H[id] = run;
      run += tv;
    }
  }
}

// scatter replay: LDS counter gives local rank; pos = H[b][v] + local.
__global__ void csr_scatter_lds_kernel(const int* __restrict__ s, const int* __restrict__ r,
                                       const int* __restrict__ H, int* __restrict__ idx,
                                       int N, int E, int CH) {
  __shared__ int cnt[SUBR];
  int b = blockIdx.x & (NB - 1);
  int sub = blockIdx.x >> NB_LOG;
  int base = sub * SUBR;
  int top = base + SUBR; if (top > N) top = N;
  int span = top - base;
  for (int t = threadIdx.x; t < span; t += 256) cnt[t] = 0;
  __syncthreads();
  int lo = b * CH, hi = lo + CH; if (hi > E) hi = E;
  const int* Hb = H + (size_t)b * N;
  for (int e = lo + threadIdx.x; e < hi; e += 256) {
    int sv = s[e], rv = r[e];
    if ((unsigned)(rv - base) < (unsigned)span) {
      int loc = atomicAdd(&cnt[rv - base], 1);
      idx[Hb[rv] + loc] = sv;
    }
    if ((unsigned)(sv - base) < (unsigned)span) {
      int loc = atomicAdd(&cnt[sv - base], 1);
      idx[Hb[sv] + loc] = rv;
    }
  }
}

// ---- derived CSR (levels 1-3): wave per next-level node scans parent row ----
// deg[v] = |{ u in rowP(perm[v]) : nm[u] < k }|
__global__ void derive_deg_kernel(const int* __restrict__ permL, const int* __restrict__ nm,
                                  const int* __restrict__ offP, const int* __restrict__ idxP,
                                  int* __restrict__ deg, int k) {
  int wave = threadIdx.x >> 6, lane = threadIdx.x & 63;
  int v = blockIdx.x * 4 + wave;
  if (v >= k) return;
  int p = permL[v];
  int lo = __builtin_amdgcn_readfirstlane(offP[p]);
  int hi = __builtin_amdgcn_readfirstlane(offP[p + 1]);
  int cnt = 0;
  for (int j0 = lo; j0 < hi; j0 += 64) {
    int j = j0 + lane;
    bool ok = (j < hi) && (nm[idxP[j]] < k);
    unsigned long long msk = __ballot(ok);
    cnt += __popcll(msk);
  }
  if (lane == 0) deg[v] = cnt;
}

// idxL row of v = compacted { nm[u] : u in rowP(perm[v]), nm[u] < k }
__global__ void derive_fill_kernel(const int* __restrict__ permL, const int* __restrict__ nm,
                                   const int* __restrict__ offP, const int* __restrict__ idxP,
                                   const int* __restrict__ offL, int* __restrict__ idxL,
                                   int k) {
  int wave = threadIdx.x >> 6, lane = threadIdx.x & 63;
  int v = blockIdx.x * 4 + wave;
  if (v >= k) return;
  int p = permL[v];
  int lo = __builtin_amdgcn_readfirstlane(offP[p]);
  int hi = __builtin_amdgcn_readfirstlane(offP[p + 1]);
  int base = __builtin_amdgcn_readfirstlane(offL[v]);
  for (int j0 = lo; j0 < hi; j0 += 64) {
    int j = j0 + lane;
    int m = k;
    if (j < hi) m = nm[idxP[j]];
    bool ok = m < k;
    unsigned long long msk = __ballot(ok);
    int rank = __popcll(msk & ((1ull << lane) - 1ull));
    if (ok) idxL[base + rank] = m;
    base += __popcll(msk);
  }
}

// ---- 2-pass parallel exclusive scan (self-prefix final; nb <= 256) ----
__global__ void scan_part_kernel(const int* __restrict__ deg, int* __restrict__ bsum, int n) {
  __shared__ int l[256];
  int i = blockIdx.x * 256 + threadIdx.x;
  l[threadIdx.x] = (i < n) ? deg[i] : 0;
  __syncthreads();
  for (int s = 128; s; s >>= 1) {
    if (threadIdx.x < s) l[threadIdx.x] += l[threadIdx.x + s];
    __syncthreads();
  }
  if (threadIdx.x == 0) bsum[blockIdx.x] = l[0];
}

__global__ void scan_final_kernel(const int* __restrict__ deg, const int* __restrict__ bsum,
                                  int* __restrict__ off, int n) {
  __shared__ int red[256];
  __shared__ int l[256];
  int i = blockIdx.x * 256 + threadIdx.x;
  int t = threadIdx.x;
  red[t] = (t < (int)blockIdx.x) ? bsum[t] : 0;
  __syncthreads();
  for (int s = 128; s; s >>= 1) {
    if (t < s) red[t] += red[t + s];
    __syncthreads();
  }
  int base = red[0];
  int v = (i < n) ? deg[i] : 0;
  l[t] = v;
  __syncthreads();
#pragma unroll
  for (int s = 1; s < 256; s <<= 1) {
    int add = (t >= s) ? l[t - s] : 0;
    __syncthreads();
    l[t] += add;
    __syncthreads();
  }
  int incl = l[t];
  if (i < n) {
    int e = base + incl - v;
    off[i] = e;
    if (i == n - 1) off[n] = base + incl;
  }
}

// fused 1-hop remap for the up gather: idxu[j] = nmap[idx[j]] for 3 levels
__global__ void idxup3_kernel(const int* __restrict__ idxA, const int* __restrict__ nmA,
                              const int* __restrict__ lenA, int* __restrict__ outA,
                              const int* __restrict__ idxB, const int* __restrict__ nmB,
                              const int* __restrict__ lenB, int* __restrict__ outB,
                              const int* __restrict__ idxC, const int* __restrict__ nmC,
                              const int* __restrict__ lenC, int* __restrict__ outC,
                              int nbSeg, int maxlen) {
  int seg = blockIdx.x / nbSeg;
  int j = (blockIdx.x - seg * nbSeg) * 256 + threadIdx.x;
  if (j >= maxlen) return;
  const int* idx; const int* nm; const int* len; int* out;
  if (seg == 0)      { idx = idxA; nm = nmA; len = lenA; out = outA; }
  else if (seg == 1) { idx = idxB; nm = nmB; len = lenB; out = outB; }
  else               { idx = idxC; nm = nmC; len = lenC; out = outC; }
  if (j >= len[0]) return;
  out[j] = nm[idx[j]];
}

// ---- down-path f32 aggregation (512B rows, 2 rows per wave-load pair) ----
__global__ void agg_kernel(const float* __restrict__ x, const int* __restrict__ off,
                           const int* __restrict__ idx, float* __restrict__ agg, int n) {
  int wave = threadIdx.x >> 6, lane = threadIdx.x & 63;
  int v = blockIdx.x * 4 + wave;
  if (v >= n) return;
  int lo = __builtin_amdgcn_readfirstlane(off[v]);
  int hi = __builtin_amdgcn_readfirstlane(off[v + 1]);
  int g = lane >> 5, sl = lane & 31;
  const float* bp = x + sl * 4;
  float4 acc = {0.f, 0.f, 0.f, 0.f};
#define ACC_F(EE)                                        \
  do {                                                   \
    float4 w_ = *(const float4*)(bp + (size_t)(EE) * 128);\
    acc.x += w_.x; acc.y += w_.y; acc.z += w_.z; acc.w += w_.w; \
  } while (0)
  int j = lo;
  for (; j + 8 <= hi; j += 8) {
    int q0 = idx[j],     q1 = idx[j + 1], q2 = idx[j + 2], q3 = idx[j + 3];
    int q4 = idx[j + 4], q5 = idx[j + 5], q6 = idx[j + 6], q7 = idx[j + 7];
    ACC_F(g ? q1 : q0);
    ACC_F(g ? q3 : q2);
    ACC_F(g ? q5 : q4);
    ACC_F(g ? q7 : q6);
  }
  for (; j + 2 <= hi; j += 2) {
    int q0 = idx[j], q1 = idx[j + 1];
    ACC_F(g ? q1 : q0);
  }
  if (j < hi) {
    int q0 = idx[j];
    if (!g) ACC_F(q0);
  }
#undef ACC_F
  acc.x += __shfl_xor(acc.x, 32, 64);
  acc.y += __shfl_xor(acc.y, 32, 64);
  acc.z += __shfl_xor(acc.z, 32, 64);
  acc.w += __shfl_xor(acc.w, 32, 64);
  if (!g) *(float4*)&agg[(size_t)v * 128 + sl * 4] = acc;
}

// ---- up-path gather-sum over ONE 256B-row bf16 table ----
template <int OFS>
__global__ void agg_gather_kernel(const u16* __restrict__ tab, const int* __restrict__ idx,
                                  const int* __restrict__ off, u16* __restrict__ agg, int n) {
  int wave = threadIdx.x >> 6, lane = threadIdx.x & 63;
  int v = blockIdx.x * 4 + wave;
  if (v >= n) return;
  int lo = __builtin_amdgcn_readfirstlane(off[v]);
  int hi = __builtin_amdgcn_readfirstlane(off[v + 1]);
  int g = lane >> 4, sl = lane & 15;
  const u16* bp = tab + sl * 8;
  float4 a0 = {0.f, 0.f, 0.f, 0.f}, a1 = {0.f, 0.f, 0.f, 0.f};

#define ACC_ROW(EE)                                     \
  do {                                                  \
    uint4 wq = *(const uint4*)(bp + (size_t)(EE) * 128);\
    a0.x += __uint_as_float(wq.x << 16);                \
    a0.y += __uint_as_float(wq.x & 0xffff0000u);        \
    a0.z += __uint_as_float(wq.y << 16);                \
    a0.w += __uint_as_float(wq.y & 0xffff0000u);        \
    a1.x += __uint_as_float(wq.z << 16);                \
    a1.y += __uint_as_float(wq.z & 0xffff0000u);        \
    a1.z += __uint_as_float(wq.w << 16);                \
    a1.w += __uint_as_float(wq.w & 0xffff0000u);        \
  } while (0)

  int j = lo;
  for (; j + 16 <= hi; j += 16) {
    int e0 = idx[j + g];
    int e1 = idx[j + g + 4];
    int e2 = idx[j + g + 8];
    int e3 = idx[j + g + 12];
    ACC_ROW(e0); ACC_ROW(e1); ACC_ROW(e2); ACC_ROW(e3);
  }
  for (; j + 4 <= hi; j += 4) {
    int e0 = idx[j + g];
    ACC_ROW(e0);
  }
  int rmn = hi - j;
  if (g < rmn) {
    int e = idx[j + g];
    ACC_ROW(e);
  }
#undef ACC_ROW

  a0.x += __shfl_xor(a0.x, 16, 64);
  a0.y += __shfl_xor(a0.y, 16, 64);
  a0.z += __shfl_xor(a0.z, 16, 64);
  a0.w += __shfl_xor(a0.w, 16, 64);
  a1.x += __shfl_xor(a1.x, 16, 64);
  a1.y += __shfl_xor(a1.y, 16, 64);
  a1.z += __shfl_xor(a1.z, 16, 64);
  a1.w += __shfl_xor(a1.w, 16, 64);
  a0.x += __shfl_xor(a0.x, 32, 64);
  a0.y += __shfl_xor(a0.y, 32, 64);
  a0.z += __shfl_xor(a0.z, 32, 64);
  a0.w += __shfl_xor(a0.w, 32, 64);
  a1.x += __shfl_xor(a1.x, 32, 64);
  a1.y += __shfl_xor(a1.y, 32, 64);
  a1.z += __shfl_xor(a1.z, 32, 64);
  a1.w += __shfl_xor(a1.w, 32, 64);

  if (lane < 16) {
    bf16x8 ov;
    ov[0] = (short)f2bf(a0.x); ov[1] = (short)f2bf(a0.y);
    ov[2] = (short)f2bf(a0.z); ov[3] = (short)f2bf(a0.w);
    ov[4] = (short)f2bf(a1.x); ov[5] = (short)f2bf(a1.y);
    ov[6] = (short)f2bf(a1.z); ov[7] = (short)f2bf(a1.w);
    *(bf16x8*)&agg[(size_t)v * 256 + OFS + sl * 8] = ov;
  }
}

// ---- down-path f32 GEMM (CIN=128), 32-row tile ----
template <bool GELU>
__global__ __launch_bounds__(256) void gemm_kernel(const float* __restrict__ A,
                                                   const float* __restrict__ W,
                                                   const float* __restrict__ bias,
                                                   float* __restrict__ out, int n) {
  __shared__ float As[32 * 32];
  __shared__ float Ws[32 * 128];
  int t = threadIdx.x;
  int row0 = blockIdx.x * 32;
  int colg = (t & 31) << 2;
  int rowg = (t >> 5) << 2;
  float acc[4][4];
#pragma unroll
  for (int i = 0; i < 4; ++i)
#pragma unroll
    for (int j = 0; j < 4; ++j) acc[i][j] = 0.f;

  for (int k0 = 0; k0 < 128; k0 += 32) {
    __syncthreads();
    {
      int ar = t >> 3, ac = (t & 7) << 2;
      float4 av = make_float4(0.f, 0.f, 0.f, 0.f);
      if (row0 + ar < n) av = *(const float4*)&A[(size_t)(row0 + ar) * 128 + k0 + ac];
      *(float4*)&As[ar * 32 + ac] = av;
    }
#pragma unroll
    for (int l = 0; l < 4; ++l) {
      int id = t + l * 256;
      int kk = id >> 5, wc = (id & 31) << 2;
      *(float4*)&Ws[kk * 128 + wc] = *(const float4*)&W[(size_t)(k0 + kk) * 128 + wc];
    }
    __syncthreads();
#pragma unroll
    for (int kk = 0; kk < 32; kk += 4) {
      float4 wv[4];
#pragma unroll
      for (int j = 0; j < 4; ++j) wv[j] = *(const float4*)&Ws[(kk + j) * 128 + colg];
#pragma unroll
      for (int i = 0; i < 4; ++i) {
        float4 av = *(const float4*)&As[(rowg + i) * 32 + kk];
        acc[i][0] += av.x * wv[0].x + av.y * wv[1].x + av.z * wv[2].x + av.w * wv[3].x;
        acc[i][1] += av.x * wv[0].y + av.y * wv[1].y + av.z * wv[2].y + av.w * wv[3].y;
        acc[i][2] += av.x * wv[0].z + av.y * wv[1].z + av.z * wv[2].z + av.w * wv[3].z;
        acc[i][3] += av.x * wv[0].w + av.y * wv[1].w + av.z * wv[2].w + av.w * wv[3].w;
      }
    }
  }
  float4 bv = *(const float4*)&bias[colg];
#pragma unroll
  for (int i = 0; i < 4; ++i) {
    int rr = row0 + rowg + i;
    if (rr < n) {
      float4 o = make_float4(acc[i][0] + bv.x, acc[i][1] + bv.y, acc[i][2] + bv.z, acc[i][3] + bv.w);
      if (GELU) { o.x = gelu_f(o.x); o.y = gelu_f(o.y); o.z = gelu_f(o.z); o.w = gelu_f(o.w); }
      *(float4*)&out[(size_t)rr * 128 + colg] = o;
    }
  }
}

// ---- up-path MFMA GEMM (gelu, bf16 out) ----
template <int K>
__global__ __launch_bounds__(256) void gemm_mfma_kernel(const u16* __restrict__ A,
                                                        const u16* __restrict__ WT,
                                                        const float* __restrict__ bias,
                                                        u16* __restrict__ out, int n) {
  __shared__ u16 As[64 * 72];
  __shared__ u16 Ws[128 * 72];
  int t = threadIdx.x;
  int lane = t & 63, wave = t >> 6;
  int row0 = blockIdx.x * 64;
  f32x4 acc[8];
#pragma unroll
  for (int i = 0; i < 8; ++i) acc[i] = (f32x4){0.f, 0.f, 0.f, 0.f};

  for (int k0 = 0; k0 < K; k0 += 64) {
    __syncthreads();
#pragma unroll
    for (int i = 0; i < 2; ++i) {
      int c = t + i * 256;
      int r = c >> 3, seg = c & 7;
      bf16x8 v = {0, 0, 0, 0, 0, 0, 0, 0};
      if (row0 + r < n) v = *(const bf16x8*)&A[(size_t)(row0 + r) * K + k0 + seg * 8];
      *(bf16x8*)&As[r * 72 + seg * 8] = v;
    }
#pragma unroll
    for (int i = 0; i < 4; ++i) {
      int c = t + i * 256;
      int r = c >> 3, seg = c & 7;
      *(bf16x8*)&Ws[r * 72 + seg * 8] = *(const bf16x8*)&WT[(size_t)r * K + k0 + seg * 8];
    }
    __syncthreads();
#pragma unroll
    for (int kk = 0; kk < 64; kk += 32) {
      bf16x8 a = *(const bf16x8*)&As[(wave * 16 + (lane & 15)) * 72 + kk + (lane >> 4) * 8];
#pragma unroll
      for (int ct = 0; ct < 8; ++ct) {
        bf16x8 b = *(const bf16x8*)&Ws[(ct * 16 + (lane & 15)) * 72 + kk + (lane >> 4) * 8];
        acc[ct] = __builtin_amdgcn_mfma_f32_16x16x32_bf16(a, b, acc[ct], 0, 0, 0);
      }
    }
  }
  int colb = lane & 15, rquad = lane >> 4;
#pragma unroll
  for (int ct = 0; ct < 8; ++ct) {
#pragma unroll
    for (int r = 0; r < 4; ++r) {
      int row = row0 + wave * 16 + rquad * 4 + r;
      if (row < n) {
        int col = ct * 16 + colb;
        out[(size_t)row * 128 + col] = f2bf(gelu_f(acc[ct][r] + bias[col]));
      }
    }
  }
}

// ---- up-path MFMA GEMM3 + fused LayerNorm ----
template <bool WF32, bool WBF>
__global__ __launch_bounds__(256) void gemm_mfma_ln_kernel(
    const u16* __restrict__ A, const u16* __restrict__ WT, const float* __restrict__ bias,
    const float* __restrict__ g, const float* __restrict__ beta,
    float* __restrict__ out, u16* __restrict__ outbf, int n) {
  __shared__ u16 As[64 * 72];
  __shared__ u16 Ws[128 * 72];
  int t = threadIdx.x;
  int lane = t & 63, wave = t >> 6;
  int row0 = blockIdx.x * 64;
  f32x4 acc[8];
#pragma unroll
  for (int i = 0; i < 8; ++i) acc[i] = (f32x4){0.f, 0.f, 0.f, 0.f};

  for (int k0 = 0; k0 < 128; k0 += 64) {
    __syncthreads();
#pragma unroll
    for (int i = 0; i < 2; ++i) {
      int c = t + i * 256;
      int r = c >> 3, seg = c & 7;
      bf16x8 v = {0, 0, 0, 0, 0, 0, 0, 0};
      if (row0 + r < n) v = *(const bf16x8*)&A[(size_t)(row0 + r) * 128 + k0 + seg * 8];
      *(bf16x8*)&As[r * 72 + seg * 8] = v;
    }
#pragma unroll
    for (int i = 0; i < 4; ++i) {
      int c = t + i * 256;
      int r = c >> 3, seg = c & 7;
      *(bf16x8*)&Ws[r * 72 + seg * 8] = *(const bf16x8*)&WT[(size_t)r * 128 + k0 + seg * 8];
    }
    __syncthreads();
#pragma unroll
    for (int kk = 0; kk < 64; kk += 32) {
      bf16x8 a = *(const bf16x8*)&As[(wave * 16 + (lane & 15)) * 72 + kk + (lane >> 4) * 8];
#pragma unroll
      for (int ct = 0; ct < 8; ++ct) {
        bf16x8 b = *(const bf16x8*)&Ws[(ct * 16 + (lane & 15)) * 72 + kk + (lane >> 4) * 8];
        acc[ct] = __builtin_amdgcn_mfma_f32_16x16x32_bf16(a, b, acc[ct], 0, 0, 0);
      }
    }
  }
  int colb = lane & 15, rquad = lane >> 4;
  float bv[8], gv[8], bev[8];
#pragma unroll
  for (int ct = 0; ct < 8; ++ct) {
    int col = ct * 16 + colb;
    bv[ct] = bias[col]; gv[ct] = g[col]; bev[ct] = beta[col];
  }
#pragma unroll
  for (int r = 0; r < 4; ++r) {
    float s1 = 0.f;
#pragma unroll
    for (int ct = 0; ct < 8; ++ct) s1 += acc[ct][r] + bv[ct];
#pragma unroll
    for (int o = 1; o <= 8; o <<= 1) s1 += __shfl_xor(s1, o, 64);
    float mu = s1 * (1.0f / 128.0f);
    float s2 = 0.f;
#pragma unroll
    for (int ct = 0; ct < 8; ++ct) { float d = acc[ct][r] + bv[ct] - mu; s2 += d * d; }
#pragma unroll
    for (int o = 1; o <= 8; o <<= 1) s2 += __shfl_xor(s2, o, 64);
    float rs = rsqrtf(s2 * (1.0f / 128.0f) + 1e-5f);
    int row = row0 + wave * 16 + rquad * 4 + r;
    if (row < n) {
#pragma unroll
      for (int ct = 0; ct < 8; ++ct) {
        int col = ct * 16 + colb;
        float o = gv[ct] * (acc[ct][r] + bv[ct] - mu) * rs + bev[ct];
        if (WF32) out[(size_t)row * 128 + col] = o;
        if (WBF)  outbf[(size_t)row * 128 + col] = f2bf(o);
      }
    }
  }
}

// ---- down-path LN (+ optional bf16 copy, + optional fused next-level score) ----
template <bool SCORE, bool WBF>
__global__ void ln_kernel(const float* __restrict__ h, const float* __restrict__ g,
                          const float* __restrict__ beta, float* __restrict__ out,
                          u16* __restrict__ outbf, const float* __restrict__ wnext,
                          const double* __restrict__ sqn, float* __restrict__ key,
                          float* __restrict__ valt, int n) {
  int wave = threadIdx.x >> 6, lane = threadIdx.x & 63;
  int i = blockIdx.x * 4 + wave;
  if (i >= n) return;
  float2 hv = *(const float2*)&h[(size_t)i * 128 + lane * 2];
  float s = hv.x + hv.y;
  for (int o = 32; o; o >>= 1) s += __shfl_down(s, o, 64);
  float mu = __shfl(s, 0, 64) * (1.0f / 128.0f);
  float dx = hv.x - mu, dy = hv.y - mu;
  float q = dx * dx + dy * dy;
  for (int o = 32; o; o >>= 1) q += __shfl_down(q, o, 64);
  float var = __shfl(q, 0, 64) * (1.0f / 128.0f);
  float rs = rsqrtf(var + 1e-5f);
  float2 gv = *(const float2*)&g[lane * 2];
  float2 bv = *(const float2*)&beta[lane * 2];
  float2 o2; o2.x = gv.x * dx * rs + bv.x; o2.y = gv.y * dy * rs + bv.y;
  *(float2*)&out[(size_t)i * 128 + lane * 2] = o2;
  if (WBF)
    *(ushort2*)&outbf[(size_t)i * 128 + lane * 2] = make_ushort2(f2bf(o2.x), f2bf(o2.y));
  if (SCORE) {
    float2 wv = *(const float2*)&wnext[lane * 2];
    double d = (double)o2.x * wv.x + (double)o2.y * wv.y;
    for (int o = 32; o; o >>= 1) d += __shfl_down(d, o, 64);
    if (lane == 0) {
      key[i]  = (float)d;
      valt[i] = (float)tanh(d / sqn[0]);
    }
  }
}

// ---------------------------------------------------------------------------

static inline int cdiv(int a, int b) { return (a + b - 1) / b; }

extern "C" void kernel_launch(void* const* d_in, const int* in_sizes, int n_in,
                              void* d_out, int out_size, void* d_ws, size_t ws_size,
                              hipStream_t stream) {
  const float* x0   = (const float*)d_in[0];
  const int*   snd  = (const int*)d_in[1];
  const int*   rcv  = (const int*)d_in[2];
  const float* poolw = (const float*)d_in[3];
  const float* dW1 = (const float*)d_in[4];
  const float* db1 = (const float*)d_in[5];
  const float* dW2 = (const float*)d_in[6];
  const float* db2 = (const float*)d_in[7];
  const float* dW3 = (const float*)d_in[8];
  const float* db3 = (const float*)d_in[9];
  const float* dg  = (const float*)d_in[10];
  const float* dbe = (const float*)d_in[11];
  const float* uW1 = (const float*)d_in[12];
  const float* ub1 = (const float*)d_in[13];
  const float* uW2 = (const float*)d_in[14];
  const float* ub2 = (const float*)d_in[15];
  const float* uW3 = (const float*)d_in[16];
  const float* ub3 = (const float*)d_in[17];
  const float* ug  = (const float*)d_in[18];
  const float* ube = (const float*)d_in[19];

  const int N0 = in_sizes[0] / 128;
  const int E  = in_sizes[1];
  const int N1 = (N0 + 1) / 2, N2 = (N1 + 1) / 2, N3 = (N2 + 1) / 2;

  // ---- workspace carve ----
  char* p = (char*)d_ws;
  auto alloc = [&](size_t bytes) -> void* {
    void* r = (void*)p;
    p += (bytes + 255) & ~(size_t)255;
    return r;
  };
  float* key  = (float*)alloc((size_t)N0 * 4);
  float* valt = (float*)alloc((size_t)N0 * 4);
  int*   histAll = (int*)alloc((size_t)3 * HIST_STRIDE * 4);
  int*   meta = (int*)alloc(64 * 4);
  int*   tcnt = (int*)alloc(512 * 4);
  int*   bsum = (int*)alloc(256 * 4);
  int*   nm1 = (int*)alloc((size_t)(N0 + 1) * 4);
  int*   nm2 = (int*)alloc((size_t)(N1 + 1) * 4);
  int*   nm3 = (int*)alloc((size_t)(N2 + 1) * 4);
  int*   perm0 = (int*)alloc((size_t)N1 * 4);
  int*   perm1 = (int*)alloc((size_t)N2 * 4);
  int*   perm2 = (int*)alloc((size_t)N3 * 4);
  float* vals  = (float*)alloc((size_t)N1 * 4);
  double* sqn  = (double*)alloc(8 * 8);
  float* x1 = (float*)alloc((size_t)N1 * 128 * 4);
  float* x2 = (float*)alloc((size_t)N2 * 128 * 4);
  float* x3 = (float*)alloc((size_t)N3 * 128 * 4);
  float* xp = (float*)alloc((size_t)N1 * 128 * 4);   // down only; h1b aliases in up
  float* aggf = (float*)alloc((size_t)N1 * 128 * 4);
  float* h1f  = (float*)alloc((size_t)N1 * 128 * 4);
  float* h2f  = (float*)alloc((size_t)N1 * 128 * 4);
  u16* agg_bf = (u16*)alloc((size_t)N0 * 256 * 2);
  u16* res0_bf = (u16*)alloc((size_t)N0 * 128 * 2);
  u16* res1_bf = (u16*)alloc((size_t)N1 * 128 * 2);
  u16* res2_bf = (u16*)alloc((size_t)N2 * 128 * 2);
  u16* x3_bf   = (u16*)alloc((size_t)(N3 + 1) * 128 * 2);  // +1 zero row
  u16* xu2_bf  = (u16*)alloc((size_t)(N2 + 1) * 128 * 2);  // +1 zero row
  u16* xu1_bf  = (u16*)alloc((size_t)(N1 + 1) * 128 * 2);  // +1 zero row
  u16* wt1 = (u16*)alloc((size_t)3 * 128 * 256 * 2);
  u16* wt2 = (u16*)alloc((size_t)3 * 128 * 128 * 2);
  u16* wt3 = (u16*)alloc((size_t)3 * 128 * 128 * 2);
  int* degAll = (int*)alloc((size_t)(N0 + N1 + N2 + N3) * 4);
  int* deg0 = degAll;
  int* deg1 = degAll + N0;
  int* deg2 = deg1 + N1;
  int* deg3 = deg2 + N2;
  int* off0 = (int*)alloc((size_t)(N0 + 1) * 4);
  int* idx0 = (int*)alloc((size_t)2 * E * 4);
  int* off1 = (int*)alloc((size_t)(N1 + 1) * 4);
  int* idx1 = (int*)alloc((size_t)2 * E * 4);
  int* off2 = (int*)alloc((size_t)(N2 + 1) * 4);
  int* idx2 = (int*)alloc((size_t)2 * E * 4);
  int* off3 = (int*)alloc((size_t)(N3 + 1) * 4);
  int* idx3 = (int*)alloc((size_t)2 * E * 4);
  int* idxu0 = (int*)alloc((size_t)2 * E * 4);   // nmap-remapped idx0 (for up lvl 2)
  int* idxu1 = (int*)alloc((size_t)2 * E * 4);   // remapped idx1 (up lvl 1)
  int* idxu2 = (int*)alloc((size_t)2 * E * 4);   // remapped idx2 (up lvl 0)
  int* H = (int*)alloc((size_t)NB * N0 * 4);     // level-0 count/base matrix
  u16* h1b = (u16*)xp;                           // up-phase alias over xp
  u16* h2b = (u16*)alloc((size_t)N0 * 128 * 2);  // up-phase h2 (own buffer)

  auto run_scan = [&](int* degB, int* offB, int n) {
    int nb = cdiv(n, 256);
    scan_part_kernel<<<nb, 256, 0, stream>>>(degB, bsum, n);
    scan_final_kernel<<<nb, 256, 0, stream>>>(degB, bsum, offB, n);
  };

  // ---- fused one-time preamble ----
  {
    int nbX = cdiv(N0 * 32, 256);
    int nHist = 3 * HIST_STRIDE;
    int nbHZ = cdiv(nHist, 256);
    preamble_kernel<<<nbX + 768 + 1 + 1 + nbHZ, 256, 0, stream>>>(
        x0, res0_bf, N0, uW1, uW2, uW3, wt1, wt2, wt3, poolw, sqn,
        x3_bf + (size_t)N3 * 128, xu2_bf + (size_t)N2 * 128,
        xu1_bf + (size_t)N1 * 128, histAll, nbX, nbHZ, nHist);
  }

  // ---- level-0 CSR: counting sort with LDS histograms (no device atomics) ----
  {
    int nSub = cdiv(N0, SUBR);
    int CH = cdiv(E, NB);
    int nbN = cdiv(N0, 256);
    csr_count_kernel<<<NB * nSub, 256, 0, stream>>>(snd, rcv, H, N0, E, CH);
    colsum_part_kernel<<<nbN, 256, 0, stream>>>(H, deg0, bsum, N0);
    scanfix_kernel<<<nbN, 256, 0, stream>>>(deg0, bsum, off0, H, N0);
    csr_scatter_lds_kernel<<<NB * nSub, 256, 0, stream>>>(snd, rcv, H, idx0, N0, E, CH);
  }

  // ---- generic down step: top-k + derived CSR + agg + MLP + LN ----
  auto down_step = [&](int n, int k, const float* xcur, int* permL, int* nmL,
                       float* xnext, u16* xnext_bf, int lvl,
                       const int* offP, const int* idxP,
                       int* offL, int* degL, int* idxL) {
    int nb = cdiv(n, 256);
    int* histL = histAll + (size_t)lvl * HIST_STRIDE;
    int* csum_hi = histL + 2 * 65536;
    int* csum_lo = csum_hi + 256;
    hist_hi_kernel<<<nb, 256, 0, stream>>>(key, histL, csum_hi, n);
    find_hi2_kernel<<<1, 256, 0, stream>>>(histL, csum_hi, meta, k);
    hist_lo_kernel<<<nb, 256, 0, stream>>>(key, meta, histL + 65536, csum_lo, n);
    find_lo2_kernel<<<1, 256, 0, stream>>>(histL + 65536, csum_lo, meta);
    tie_count_kernel<<<nb, 256, 0, stream>>>(key, meta, tcnt, n);
    tie_select_kernel<<<cdiv(n + 1, 256), 256, 0, stream>>>(
        key, valt, tcnt, meta, permL, vals, nmL, n, k);
    pool_kernel<<<cdiv(k * 32, 256), 256, 0, stream>>>(xcur, permL, vals, xp, k);
    derive_deg_kernel<<<cdiv(k, 4), 256, 0, stream>>>(permL, nmL, offP, idxP, degL, k);
    run_scan(degL, offL, k);
    derive_fill_kernel<<<cdiv(k, 4), 256, 0, stream>>>(permL, nmL, offP, idxP, offL, idxL, k);
    agg_kernel<<<cdiv(k, 4), 256, 0, stream>>>(xp, offL, idxL, aggf, k);
    gemm_kernel<true><<<cdiv(k, 32), 256, 0, stream>>>(
        aggf, dW1 + (size_t)lvl * 128 * 128, db1 + (size_t)lvl * 128, h1f, k);
    gemm_kernel<true><<<cdiv(k, 32), 256, 0, stream>>>(
        h1f, dW2 + (size_t)lvl * 128 * 128, db2 + (size_t)lvl * 128, h2f, k);
    gemm_kernel<false><<<cdiv(k, 32), 256, 0, stream>>>(
        h2f, dW3 + (size_t)lvl * 128 * 128, db3 + (size_t)lvl * 128, h1f, k);
    if (lvl < 2)
      ln_kernel<true, true><<<cdiv(k, 4), 256, 0, stream>>>(
          h1f, dg + (size_t)lvl * 128, dbe + (size_t)lvl * 128, xnext, xnext_bf,
          poolw + (size_t)(lvl + 1) * 128, sqn + (lvl + 1), key, valt, k);
    else
      ln_kernel<false, true><<<cdiv(k, 4), 256, 0, stream>>>(
          h1f, dg + (size_t)lvl * 128, dbe + (size_t)lvl * 128, xnext, xnext_bf,
          nullptr, nullptr, nullptr, nullptr, k);
  };

  // level-0 score from x0
  score_kernel<<<cdiv(N0, 4), 256, 0, stream>>>(x0, poolw, key, valt, N0);
  down_step(N0, N1, x0, perm0, nm1, x1, res1_bf, 0, off0, idx0, off1, deg1, idx1);
  down_step(N1, N2, x1, perm1, nm2, x2, res2_bf, 1, off1, idx1, off2, deg2, idx2);
  down_step(N2, N3, x2, perm2, nm3, x3, x3_bf,   2, off2, idx2, off3, deg3, idx3);

  // ---- remapped up-gather indices (1-hop), fused 3 levels ----
  {
    int nbSeg = cdiv(2 * E, 256);
    idxup3_kernel<<<3 * nbSeg, 256, 0, stream>>>(
        idx2, nm3, off2 + N2, idxu2,
        idx1, nm2, off1 + N1, idxu1,
        idx0, nm1, off0 + N0, idxu0, nbSeg, 2 * E);
  }

  // ---- generic up step (split gathers + MFMA GEMM3 + fused LN) ----
  auto up_step = [&](int n, const u16* resb, const u16* xdb, int lvl,
                     const int* offL, const int* idxL, const int* idxUL,
                     bool wantF32, float* outF32, u16* outBF) {
    agg_gather_kernel<0><<<cdiv(n, 4), 256, 0, stream>>>(resb, idxL, offL, agg_bf, n);
    agg_gather_kernel<128><<<cdiv(n, 4), 256, 0, stream>>>(xdb, idxUL, offL, agg_bf, n);
    gemm_mfma_kernel<256><<<cdiv(n, 64), 256, 0, stream>>>(
        agg_bf, wt1 + (size_t)lvl * 128 * 256, ub1 + (size_t)lvl * 128, h1b, n);
    gemm_mfma_kernel<128><<<cdiv(n, 64), 256, 0, stream>>>(
        h1b, wt2 + (size_t)lvl * 128 * 128, ub2 + (size_t)lvl * 128, h2b, n);
    if (wantF32)
      gemm_mfma_ln_kernel<true, false><<<cdiv(n, 64), 256, 0, stream>>>(
          h2b, wt3 + (size_t)lvl * 128 * 128, ub3 + (size_t)lvl * 128,
          ug + (size_t)lvl * 128, ube + (size_t)lvl * 128, outF32, nullptr, n);
    else
      gemm_mfma_ln_kernel<false, true><<<cdiv(n, 64), 256, 0, stream>>>(
          h2b, wt3 + (size_t)lvl * 128 * 128, ub3 + (size_t)lvl * 128,
          ug + (size_t)lvl * 128, ube + (size_t)lvl * 128, nullptr, outBF, n);
  };

  up_step(N2, res2_bf, x3_bf,  0, off2, idx2, idxu2, false, nullptr, xu2_bf);
  up_step(N1, res1_bf, xu2_bf, 1, off1, idx1, idxu1, false, nullptr, xu1_bf);
  up_step(N0, res0_bf, xu1_bf, 2, off0, idx0, idxu0, true, (float*)d_out, nullptr);

  (void)n_in; (void)out_size; (void)ws_size;
}

// Round 11
// 821.051 us; speedup vs baseline: 1.0202x; 1.0124x over previous
//
#include <hip/hip_runtime.h>
#include <math.h>

// ---------------------------------------------------------------------------
// MeshGraphUnet2 forward on gfx950.  Round 18: dispatch-count attack — the
// profile is flat (top-5 = harness fills; all our kernels < 40us; ~300us is
// inter-dispatch serialization over ~70 launches).  MLPs are ROW-LOCAL, so:
//  * mlp_down_kernel: gemm x3 + LN(+score) fused into ONE kernel/level,
//    inter-layer activations live in a 16KB LDS buffer (no h1f/h2f).
//  * mlp_up_kernel: 3 MFMA gemms + LN fused into ONE kernel/level; gelu bf16
//    inter-layer tile in stride-136 LDS (aligned, ~2-way-conflict fragment
//    reads); layers 2/3 read MFMA fragments straight from LDS.
//  * agg_gather2: res/up gather pair merged into one launch.
// 70 -> 52 dispatches.  Keeps: counting-sort lvl0 CSR, derived CSR lvl1-3,
// dual-table + zero row, idxup3, fused tie_select, parallel-scan finds,
// preamble zeroing, 2-pass scan.
// ---------------------------------------------------------------------------

typedef unsigned short u16;
typedef short bf16x8 __attribute__((ext_vector_type(8)));
typedef float f32x4 __attribute__((ext_vector_type(4)));

#define HIST_STRIDE (2 * 65536 + 512)
#define NB 128       // edge chunks (power of 2)
#define NB_LOG 7
#define SUBR 5000    // node sub-range per LDS histogram (20000 B -> 8 blk/CU)

__device__ __forceinline__ unsigned int fkey(float f) {
  unsigned int b = __float_as_uint(f);
  return (b & 0x80000000u) ? ~b : (b | 0x80000000u);  // monotonic float->uint
}

__device__ __forceinline__ float gelu_f(float v) {
  return 0.5f * v * (1.0f + erff(v * 0.70710678118654752f));
}

__device__ __forceinline__ u16 f2bf(float f) {
  unsigned u = __float_as_uint(f);
  u = (u + 0x7FFFu + ((u >> 16) & 1u)) >> 16;  // round-nearest-even
  return (u16)u;
}
__device__ __forceinline__ float bf2f(u16 u) {
  return __uint_as_float(((unsigned)u) << 16);
}

// ---- level-0 scoring: key[i] = (float)(x[i,:].w) f64, valt = tanh(d/||w||)
__global__ void score_kernel(const float* __restrict__ x, const float* __restrict__ w,
                             float* __restrict__ key, float* __restrict__ valt, int n) {
  int wave = threadIdx.x >> 6, lane = threadIdx.x & 63;
  int i = blockIdx.x * 4 + wave;
  if (i >= n) return;
  float2 xv = *(const float2*)&x[(size_t)i * 128 + lane * 2];
  float2 wv = *(const float2*)&w[lane * 2];
  double d  = (double)xv.x * wv.x + (double)xv.y * wv.y;
  double nw = (double)wv.x * wv.x + (double)wv.y * wv.y;
  for (int o = 32; o; o >>= 1) { d += __shfl_down(d, o, 64); nw += __shfl_down(nw, o, 64); }
  if (lane == 0) {
    key[i]  = (float)d;
    valt[i] = (float)tanh(d / sqrt(nw));
  }
}

// fused one-time preamble: xconv + wconv + wnorm + zero dummy rows +
// zero all 3 hist regions.
__global__ void preamble_kernel(const float* __restrict__ x, u16* __restrict__ xb, int n,
                                const float* __restrict__ uW1, const float* __restrict__ uW2,
                                const float* __restrict__ uW3, u16* __restrict__ wt1,
                                u16* __restrict__ wt2, u16* __restrict__ wt3,
                                const float* __restrict__ poolw, double* __restrict__ sqn,
                                u16* __restrict__ z0, u16* __restrict__ z1,
                                u16* __restrict__ z2, int* __restrict__ histAll,
                                int nbX, int nbHZ, int nHist) {
  int b = blockIdx.x;
  if (b < nbX) {  // xconv
    int gid = b * 256 + threadIdx.x;
    if (gid < n * 32) {
      float4 a = *(const float4*)&x[(size_t)gid * 4];
      *(ushort4*)&xb[(size_t)gid * 4] =
          make_ushort4(f2bf(a.x), f2bf(a.y), f2bf(a.z), f2bf(a.w));
    }
    return;
  }
  b -= nbX;
  if (b < 768) {  // wconv: 3*65536 elements exactly
    int i = b * 256 + threadIdx.x;
    int lvl = i >> 16, rem = i & 65535;
    if (rem < 32768) {  // W1: [256][128] -> [128][256]
      int k = rem >> 7, c = rem & 127;
      wt1[(size_t)lvl * 32768 + c * 256 + k] = f2bf(uW1[(size_t)lvl * 32768 + rem]);
    } else if (rem < 49152) {
      int j = rem - 32768; int k = j >> 7, c = j & 127;
      wt2[(size_t)lvl * 16384 + c * 128 + k] = f2bf(uW2[(size_t)lvl * 16384 + j]);
    } else {
      int j = rem - 49152; int k = j >> 7, c = j & 127;
      wt3[(size_t)lvl * 16384 + c * 128 + k] = f2bf(uW3[(size_t)lvl * 16384 + j]);
    }
    return;
  }
  b -= 768;
  if (b == 0) {  // wnorm (one wave)
    if (threadIdx.x < 64) {
      int lane = threadIdx.x;
      for (int l = 0; l < 3; ++l) {
        float2 wv = *(const float2*)&poolw[l * 128 + lane * 2];
        double nw = (double)wv.x * wv.x + (double)wv.y * wv.y;
        for (int o = 32; o; o >>= 1) nw += __shfl_down(nw, o, 64);
        if (lane == 0) sqn[l] = sqrt(nw);
      }
    }
    return;
  }
  b -= 1;
  if (b == 0) {  // zero dummy rows (128 u16 each)
    int t = threadIdx.x;
    if (t < 128) { z0[t] = 0; z1[t] = 0; z2[t] = 0; }
    return;
  }
  b -= 1;
  {  // zero hist regions
    int i = b * 256 + threadIdx.x;
    if (i < nHist) histAll[i] = 0;
  }
}

// ---- histograms; csum accumulated in LDS per block, flushed with few atomics ----
__global__ void hist_hi_kernel(const float* __restrict__ key, int* __restrict__ hist,
                               int* __restrict__ csum, int n) {
  __shared__ int lc[256];
  lc[threadIdx.x] = 0;
  __syncthreads();
  int i = blockIdx.x * 256 + threadIdx.x;
  if (i < n) {
    unsigned b = fkey(key[i]) >> 16;
    atomicAdd(&hist[b], 1);
    atomicAdd(&lc[b >> 8], 1);
  }
  __syncthreads();
  int v = lc[threadIdx.x];
  if (v) atomicAdd(&csum[threadIdx.x], v);
}

__global__ void hist_lo_kernel(const float* __restrict__ key, const int* __restrict__ meta,
                               int* __restrict__ hist, int* __restrict__ csum, int n) {
  __shared__ int lc[256];
  lc[threadIdx.x] = 0;
  __syncthreads();
  int i = blockIdx.x * 256 + threadIdx.x;
  if (i < n) {
    unsigned u = fkey(key[i]);
    if ((u >> 16) == (unsigned)meta[0]) {
      unsigned b = u & 0xFFFFu;
      atomicAdd(&hist[b], 1);
      atomicAdd(&lc[b >> 8], 1);
    }
  }
  __syncthreads();
  int v = lc[threadIdx.x];
  if (v) atomicAdd(&csum[threadIdx.x], v);
}

// parallel suffix inclusive scan over 256 LDS ints
__device__ __forceinline__ void suffix_scan256(int* sA, int t) {
  for (int o = 1; o < 256; o <<= 1) {
    int add = (t + o < 256) ? sA[t + o] : 0;
    __syncthreads();
    sA[t] += add;
    __syncthreads();
  }
}

__global__ void find_hi2_kernel(const int* __restrict__ hist, const int* __restrict__ csum,
                                int* __restrict__ meta, int k) {
  __shared__ int sA[256];
  __shared__ int cSh, cumSh;
  int t = threadIdx.x;
  sA[t] = csum[t];
  __syncthreads();
  suffix_scan256(sA, t);
  int nxt = (t == 255) ? 0 : sA[t + 1];
  if (sA[t] >= k && nxt < k) { cSh = t; cumSh = nxt; }
  __syncthreads();
  int c = cSh;
  int k2 = k - cumSh;
  sA[t] = hist[c * 256 + t];
  __syncthreads();
  suffix_scan256(sA, t);
  nxt = (t == 255) ? 0 : sA[t + 1];
  if (sA[t] >= k2 && nxt < k2) {
    meta[0] = c * 256 + t;
    meta[1] = k2 - nxt;
  }
}

__global__ void find_lo2_kernel(const int* __restrict__ hist, const int* __restrict__ csum,
                                int* __restrict__ meta) {
  __shared__ int sA[256];
  __shared__ int cSh, cumSh;
  int t = threadIdx.x;
  int m = meta[1], B = meta[0];
  sA[t] = csum[t];
  __syncthreads();
  suffix_scan256(sA, t);
  int nxt = (t == 255) ? 0 : sA[t + 1];
  if (sA[t] >= m && nxt < m) { cSh = t; cumSh = nxt; }
  __syncthreads();
  int c = cSh;
  int m2 = m - cumSh;
  sA[t] = hist[c * 256 + t];
  __syncthreads();
  suffix_scan256(sA, t);
  nxt = (t == 255) ? 0 : sA[t + 1];
  if (sA[t] >= m2 && nxt < m2) {
    meta[3] = (int)((((unsigned)B) << 16) | (unsigned)(c * 256 + t));
    meta[4] = m2 - nxt;
  }
  if (t == 0) meta[5] = 0;
}

__global__ void tie_count_kernel(const float* __restrict__ key, const int* __restrict__ meta,
                                 int* __restrict__ tcnt, int n) {
  __shared__ int cnt[4];
  unsigned uT = (unsigned)meta[3];
  int i = blockIdx.x * 256 + threadIdx.x;
  bool tie = (i < n) && (fkey(key[i]) == uT);
  unsigned long long m = __ballot(tie);
  int lane = threadIdx.x & 63, w = threadIdx.x >> 6;
  if (lane == 0) cnt[w] = __popcll(m);
  __syncthreads();
  if (threadIdx.x == 0) tcnt[blockIdx.x] = cnt[0] + cnt[1] + cnt[2] + cnt[3];
}

// fused tie-mark + select
__global__ void tie_select_kernel(const float* __restrict__ key, const float* __restrict__ valt,
                                  const int* __restrict__ tcnt, int* __restrict__ meta,
                                  int* __restrict__ perm, float* __restrict__ vals,
                                  int* __restrict__ nmap, int n, int k) {
  __shared__ int red[256];
  __shared__ int woff[4];
  int t = threadIdx.x;
  red[t] = (t < (int)blockIdx.x) ? tcnt[t] : 0;
  __syncthreads();
  for (int s = 128; s; s >>= 1) {
    if (t < s) red[t] += red[t + s];
    __syncthreads();
  }
  int blockbase = red[0];
  unsigned uT = (unsigned)meta[3];
  int tsel = meta[4];
  int i = blockIdx.x * 256 + t;
  unsigned u = (i < n) ? fkey(key[i]) : 0u;
  bool tie = (i < n) && (u == uT);
  unsigned long long m = __ballot(tie);
  int lane = t & 63, w = t >> 6;
  if (lane == 0) woff[w] = __popcll(m);
  __syncthreads();
  if (t == 0) {
    int c = 0;
    for (int q = 0; q < 4; ++q) { int v = woff[q]; woff[q] = c; c += v; }
  }
  __syncthreads();
  if (i > n) return;
  if (i == n) { nmap[n] = k; return; }
  bool sel;
  if (tie) {
    int pre = __popcll(m & ((1ull << lane) - 1ull));
    int rank = blockbase + woff[w] + pre;
    sel = (rank < tsel);
  } else {
    sel = (u > uT);
  }
  if (sel) {
    int slot = atomicAdd(&meta[5], 1);
    perm[slot] = i; vals[slot] = valt[i]; nmap[i] = slot;
  } else {
    nmap[i] = k;
  }
}

__global__ void pool_kernel(const float* __restrict__ x, const int* __restrict__ perm,
                            const float* __restrict__ vals, float* __restrict__ xp, int k) {
  int gid = blockIdx.x * 256 + threadIdx.x;
  int t = gid >> 5;
  if (t >= k) return;
  int c = (gid & 31) << 2;
  float v = vals[t];
  float4 a = *(const float4*)&x[(size_t)perm[t] * 128 + c];
  a.x *= v; a.y *= v; a.z *= v; a.w *= v;
  *(float4*)&xp[(size_t)t * 128 + c] = a;
}

// ---- level-0 CSR: deterministic counting sort, 20KB LDS histograms ----
__global__ void csr_count_kernel(const int* __restrict__ s, const int* __restrict__ r,
                                 int* __restrict__ H, int N, int E, int CH) {
  __shared__ int cnt[SUBR];
  int b = blockIdx.x & (NB - 1);
  int sub = blockIdx.x >> NB_LOG;
  int base = sub * SUBR;
  int top = base + SUBR; if (top > N) top = N;
  int span = top - base;
  for (int t = threadIdx.x; t < span; t += 256) cnt[t] = 0;
  __syncthreads();
  int lo = b * CH, hi = lo + CH; if (hi > E) hi = E;
  for (int e = lo + threadIdx.x; e < hi; e += 256) {
    int sv = s[e], rv = r[e];
    if ((unsigned)(rv - base) < (unsigned)span) atomicAdd(&cnt[rv - base], 1);
    if ((unsigned)(sv - base) < (unsigned)span) atomicAdd(&cnt[sv - base], 1);
  }
  __syncthreads();
  int* Hb = H + (size_t)b * N + base;
  for (int t = threadIdx.x; t < span; t += 256) Hb[t] = cnt[t];
}

__global__ void colsum_part_kernel(const int* __restrict__ H, int* __restrict__ deg,
                                   int* __restrict__ bsum, int n) {
  __shared__ int l[256];
  int i = blockIdx.x * 256 + threadIdx.x;
  int v = 0;
  if (i < n) {
#pragma unroll 4
    for (int b = 0; b < NB; ++b) v += H[(size_t)b * n + i];
    deg[i] = v;
  }
  l[threadIdx.x] = (i < n) ? v : 0;
  __syncthreads();
  for (int s = 128; s; s >>= 1) {
    if (threadIdx.x < s) l[threadIdx.x] += l[threadIdx.x + s];
    __syncthreads();
  }
  if (threadIdx.x == 0) bsum[blockIdx.x] = l[0];
}

__global__ void scanfix_kernel(const int* __restrict__ deg, const int* __restrict__ bsum,
                               int* __restrict__ off, int* __restrict__ H, int n) {
  __shared__ int red[256];
  __shared__ int l[256];
  int i = blockIdx.x * 256 + threadIdx.x;
  int t = threadIdx.x;
  red[t] = (t < (int)blockIdx.x) ? bsum[t] : 0;
  __syncthreads();
  for (int s = 128; s; s >>= 1) {
    if (t < s) red[t] += red[t + s];
    __syncthreads();
  }
  int base = red[0];
  int v = (i < n) ? deg[i] : 0;
  l[t] = v;
  __syncthreads();
#pragma unroll
  for (int s = 1; s < 256; s <<= 1) {
    int add = (t >= s) ? l[t - s] : 0;
    __syncthreads();
    l[t] += add;
    __syncthreads();
  }
  int incl = l[t];
  if (i < n) {
    int e = base + incl - v;
    off[i] = e;
    if (i == n - 1) off[n] = base + incl;
    int run = e;
#pragma unroll 4
    for (int b = 0; b < NB; ++b) {
      size_t id = (size_t)b * n + i;
      int tv = H[id];
      H[id] = run;
      run += tv;
    }
  }
}

__global__ void csr_scatter_lds_kernel(const int* __restrict__ s, const int* __restrict__ r,
                                       const int* __restrict__ H, int* __restrict__ idx,
                                       int N, int E, int CH) {
  __shared__ int cnt[SUBR];
  int b = blockIdx.x & (NB - 1);
  int sub = blockIdx.x >> NB_LOG;
  int base = sub * SUBR;
  int top = base + SUBR; if (top > N) top = N;
  int span = top - base;
  for (int t = threadIdx.x; t < span; t += 256) cnt[t] = 0;
  __syncthreads();
  int lo = b * CH, hi = lo + CH; if (hi > E) hi = E;
  const int* Hb = H + (size_t)b * N;
  for (int e = lo + threadIdx.x; e < hi; e += 256) {
    int sv = s[e], rv = r[e];
    if ((unsigned)(rv - base) < (unsigned)span) {
      int loc = atomicAdd(&cnt[rv - base], 1);
      idx[Hb[rv] + loc] = sv;
    }
    if ((unsigned)(sv - base) < (unsigned)span) {
      int loc = atomicAdd(&cnt[sv - base], 1);
      idx[Hb[sv] + loc] = rv;
    }
  }
}

// ---- derived CSR (levels 1-3) ----
__global__ void derive_deg_kernel(const int* __restrict__ permL, const int* __restrict__ nm,
                                  const int* __restrict__ offP, const int* __restrict__ idxP,
                                  int* __restrict__ deg, int k) {
  int wave = threadIdx.x >> 6, lane = threadIdx.x & 63;
  int v = blockIdx.x * 4 + wave;
  if (v >= k) return;
  int p = permL[v];
  int lo = __builtin_amdgcn_readfirstlane(offP[p]);
  int hi = __builtin_amdgcn_readfirstlane(offP[p + 1]);
  int cnt = 0;
  for (int j0 = lo; j0 < hi; j0 += 64) {
    int j = j0 + lane;
    bool ok = (j < hi) && (nm[idxP[j]] < k);
    unsigned long long msk = __ballot(ok);
    cnt += __popcll(msk);
  }
  if (lane == 0) deg[v] = cnt;
}

__global__ void derive_fill_kernel(const int* __restrict__ permL, const int* __restrict__ nm,
                                   const int* __restrict__ offP, const int* __restrict__ idxP,
                                   const int* __restrict__ offL, int* __restrict__ idxL,
                                   int k) {
  int wave = threadIdx.x >> 6, lane = threadIdx.x & 63;
  int v = blockIdx.x * 4 + wave;
  if (v >= k) return;
  int p = permL[v];
  int lo = __builtin_amdgcn_readfirstlane(offP[p]);
  int hi = __builtin_amdgcn_readfirstlane(offP[p + 1]);
  int base = __builtin_amdgcn_readfirstlane(offL[v]);
  for (int j0 = lo; j0 < hi; j0 += 64) {
    int j = j0 + lane;
    int m = k;
    if (j < hi) m = nm[idxP[j]];
    bool ok = m < k;
    unsigned long long msk = __ballot(ok);
    int rank = __popcll(msk & ((1ull << lane) - 1ull));
    if (ok) idxL[base + rank] = m;
    base += __popcll(msk);
  }
}

// ---- 2-pass parallel exclusive scan ----
__global__ void scan_part_kernel(const int* __restrict__ deg, int* __restrict__ bsum, int n) {
  __shared__ int l[256];
  int i = blockIdx.x * 256 + threadIdx.x;
  l[threadIdx.x] = (i < n) ? deg[i] : 0;
  __syncthreads();
  for (int s = 128; s; s >>= 1) {
    if (threadIdx.x < s) l[threadIdx.x] += l[threadIdx.x + s];
    __syncthreads();
  }
  if (threadIdx.x == 0) bsum[blockIdx.x] = l[0];
}

__global__ void scan_final_kernel(const int* __restrict__ deg, const int* __restrict__ bsum,
                                  int* __restrict__ off, int n) {
  __shared__ int red[256];
  __shared__ int l[256];
  int i = blockIdx.x * 256 + threadIdx.x;
  int t = threadIdx.x;
  red[t] = (t < (int)blockIdx.x) ? bsum[t] : 0;
  __syncthreads();
  for (int s = 128; s; s >>= 1) {
    if (t < s) red[t] += red[t + s];
    __syncthreads();
  }
  int base = red[0];
  int v = (i < n) ? deg[i] : 0;
  l[t] = v;
  __syncthreads();
#pragma unroll
  for (int s = 1; s < 256; s <<= 1) {
    int add = (t >= s) ? l[t - s] : 0;
    __syncthreads();
    l[t] += add;
    __syncthreads();
  }
  int incl = l[t];
  if (i < n) {
    int e = base + incl - v;
    off[i] = e;
    if (i == n - 1) off[n] = base + incl;
  }
}

// fused 1-hop remap for the up gather, 3 levels
__global__ void idxup3_kernel(const int* __restrict__ idxA, const int* __restrict__ nmA,
                              const int* __restrict__ lenA, int* __restrict__ outA,
                              const int* __restrict__ idxB, const int* __restrict__ nmB,
                              const int* __restrict__ lenB, int* __restrict__ outB,
                              const int* __restrict__ idxC, const int* __restrict__ nmC,
                              const int* __restrict__ lenC, int* __restrict__ outC,
                              int nbSeg, int maxlen) {
  int seg = blockIdx.x / nbSeg;
  int j = (blockIdx.x - seg * nbSeg) * 256 + threadIdx.x;
  if (j >= maxlen) return;
  const int* idx; const int* nm; const int* len; int* out;
  if (seg == 0)      { idx = idxA; nm = nmA; len = lenA; out = outA; }
  else if (seg == 1) { idx = idxB; nm = nmB; len = lenB; out = outB; }
  else               { idx = idxC; nm = nmC; len = lenC; out = outC; }
  if (j >= len[0]) return;
  out[j] = nm[idx[j]];
}

// ---- down-path f32 aggregation ----
__global__ void agg_kernel(const float* __restrict__ x, const int* __restrict__ off,
                           const int* __restrict__ idx, float* __restrict__ agg, int n) {
  int wave = threadIdx.x >> 6, lane = threadIdx.x & 63;
  int v = blockIdx.x * 4 + wave;
  if (v >= n) return;
  int lo = __builtin_amdgcn_readfirstlane(off[v]);
  int hi = __builtin_amdgcn_readfirstlane(off[v + 1]);
  int g = lane >> 5, sl = lane & 31;
  const float* bp = x + sl * 4;
  float4 acc = {0.f, 0.f, 0.f, 0.f};
#define ACC_F(EE)                                        \
  do {                                                   \
    float4 w_ = *(const float4*)(bp + (size_t)(EE) * 128);\
    acc.x += w_.x; acc.y += w_.y; acc.z += w_.z; acc.w += w_.w; \
  } while (0)
  int j = lo;
  for (; j + 8 <= hi; j += 8) {
    int q0 = idx[j],     q1 = idx[j + 1], q2 = idx[j + 2], q3 = idx[j + 3];
    int q4 = idx[j + 4], q5 = idx[j + 5], q6 = idx[j + 6], q7 = idx[j + 7];
    ACC_F(g ? q1 : q0);
    ACC_F(g ? q3 : q2);
    ACC_F(g ? q5 : q4);
    ACC_F(g ? q7 : q6);
  }
  for (; j + 2 <= hi; j += 2) {
    int q0 = idx[j], q1 = idx[j + 1];
    ACC_F(g ? q1 : q0);
  }
  if (j < hi) {
    int q0 = idx[j];
    if (!g) ACC_F(q0);
  }
#undef ACC_F
  acc.x += __shfl_xor(acc.x, 32, 64);
  acc.y += __shfl_xor(acc.y, 32, 64);
  acc.z += __shfl_xor(acc.z, 32, 64);
  acc.w += __shfl_xor(acc.w, 32, 64);
  if (!g) *(float4*)&agg[(size_t)v * 128 + sl * 4] = acc;
}

// ---- merged up-path gather (res half + up half in one launch) ----
__global__ void agg_gather2_kernel(const u16* __restrict__ tabR, const int* __restrict__ idxR,
                                   const u16* __restrict__ tabU, const int* __restrict__ idxU,
                                   const int* __restrict__ off, u16* __restrict__ agg,
                                   int n, int nbHalf) {
  bool upH = (int)blockIdx.x >= nbHalf;
  int blk = upH ? (int)blockIdx.x - nbHalf : (int)blockIdx.x;
  const u16* tab = upH ? tabU : tabR;
  const int* idx = upH ? idxU : idxR;
  int OFS = upH ? 128 : 0;
  int wave = threadIdx.x >> 6, lane = threadIdx.x & 63;
  int v = blk * 4 + wave;
  if (v >= n) return;
  int lo = __builtin_amdgcn_readfirstlane(off[v]);
  int hi = __builtin_amdgcn_readfirstlane(off[v + 1]);
  int g = lane >> 4, sl = lane & 15;
  const u16* bp = tab + sl * 8;
  float4 a0 = {0.f, 0.f, 0.f, 0.f}, a1 = {0.f, 0.f, 0.f, 0.f};

#define ACC_ROW(EE)                                     \
  do {                                                  \
    uint4 wq = *(const uint4*)(bp + (size_t)(EE) * 128);\
    a0.x += __uint_as_float(wq.x << 16);                \
    a0.y += __uint_as_float(wq.x & 0xffff0000u);        \
    a0.z += __uint_as_float(wq.y << 16);                \
    a0.w += __uint_as_float(wq.y & 0xffff0000u);        \
    a1.x += __uint_as_float(wq.z << 16);                \
    a1.y += __uint_as_float(wq.z & 0xffff0000u);        \
    a1.z += __uint_as_float(wq.w << 16);                \
    a1.w += __uint_as_float(wq.w & 0xffff0000u);        \
  } while (0)

  int j = lo;
  for (; j + 16 <= hi; j += 16) {
    int e0 = idx[j + g];
    int e1 = idx[j + g + 4];
    int e2 = idx[j + g + 8];
    int e3 = idx[j + g + 12];
    ACC_ROW(e0); ACC_ROW(e1); ACC_ROW(e2); ACC_ROW(e3);
  }
  for (; j + 4 <= hi; j += 4) {
    int e0 = idx[j + g];
    ACC_ROW(e0);
  }
  int rmn = hi - j;
  if (g < rmn) {
    int e = idx[j + g];
    ACC_ROW(e);
  }
#undef ACC_ROW

  a0.x += __shfl_xor(a0.x, 16, 64);
  a0.y += __shfl_xor(a0.y, 16, 64);
  a0.z += __shfl_xor(a0.z, 16, 64);
  a0.w += __shfl_xor(a0.w, 16, 64);
  a1.x += __shfl_xor(a1.x, 16, 64);
  a1.y += __shfl_xor(a1.y, 16, 64);
  a1.z += __shfl_xor(a1.z, 16, 64);
  a1.w += __shfl_xor(a1.w, 16, 64);
  a0.x += __shfl_xor(a0.x, 32, 64);
  a0.y += __shfl_xor(a0.y, 32, 64);
  a0.z += __shfl_xor(a0.z, 32, 64);
  a0.w += __shfl_xor(a0.w, 32, 64);
  a1.x += __shfl_xor(a1.x, 32, 64);
  a1.y += __shfl_xor(a1.y, 32, 64);
  a1.z += __shfl_xor(a1.z, 32, 64);
  a1.w += __shfl_xor(a1.w, 32, 64);

  if (lane < 16) {
    bf16x8 ov;
    ov[0] = (short)f2bf(a0.x); ov[1] = (short)f2bf(a0.y);
    ov[2] = (short)f2bf(a0.z); ov[3] = (short)f2bf(a0.w);
    ov[4] = (short)f2bf(a1.x); ov[5] = (short)f2bf(a1.y);
    ov[6] = (short)f2bf(a1.z); ov[7] = (short)f2bf(a1.w);
    *(bf16x8*)&agg[(size_t)v * 256 + OFS + sl * 8] = ov;
  }
}

// ---- FUSED down-path MLP: 3x f32 GEMM + gelu + LN (+score), 32 rows/block --
template <bool SCORE>
__global__ __launch_bounds__(256) void mlp_down_kernel(
    const float* __restrict__ A,
    const float* __restrict__ W1, const float* __restrict__ b1,
    const float* __restrict__ W2, const float* __restrict__ b2,
    const float* __restrict__ W3, const float* __restrict__ b3,
    const float* __restrict__ g, const float* __restrict__ beta,
    float* __restrict__ out, u16* __restrict__ outbf,
    const float* __restrict__ wnext, const double* __restrict__ sqn,
    float* __restrict__ key, float* __restrict__ valt, int n) {
  __shared__ float cur[32 * 128];
  __shared__ float As[32 * 32];
  __shared__ float Ws[32 * 128];
  int t = threadIdx.x;
  int row0 = blockIdx.x * 32;
  int colg = (t & 31) << 2;
  int rowg = (t >> 5) << 2;
  float acc[4][4];
  const float* Wl[3] = {W1, W2, W3};
  const float* bl[3] = {b1, b2, b3};
#pragma unroll
  for (int l = 0; l < 3; ++l) {
    const float* W = Wl[l];
#pragma unroll
    for (int i = 0; i < 4; ++i)
#pragma unroll
      for (int j = 0; j < 4; ++j) acc[i][j] = 0.f;
    for (int k0 = 0; k0 < 128; k0 += 32) {
      __syncthreads();
      {
        int ar = t >> 3, ac = (t & 7) << 2;
        float4 av;
        if (l == 0) {
          av = make_float4(0.f, 0.f, 0.f, 0.f);
          if (row0 + ar < n) av = *(const float4*)&A[(size_t)(row0 + ar) * 128 + k0 + ac];
        } else {
          av = *(const float4*)&cur[ar * 128 + k0 + ac];
        }
        *(float4*)&As[ar * 32 + ac] = av;
      }
#pragma unroll
      for (int ll = 0; ll < 4; ++ll) {
        int id = t + ll * 256;
        int kk = id >> 5, wc = (id & 31) << 2;
        *(float4*)&Ws[kk * 128 + wc] = *(const float4*)&W[(size_t)(k0 + kk) * 128 + wc];
      }
      __syncthreads();
#pragma unroll
      for (int kk = 0; kk < 32; kk += 4) {
        float4 wv[4];
#pragma unroll
        for (int j = 0; j < 4; ++j) wv[j] = *(const float4*)&Ws[(kk + j) * 128 + colg];
#pragma unroll
        for (int i = 0; i < 4; ++i) {
          float4 av = *(const float4*)&As[(rowg + i) * 32 + kk];
          acc[i][0] += av.x * wv[0].x + av.y * wv[1].x + av.z * wv[2].x + av.w * wv[3].x;
          acc[i][1] += av.x * wv[0].y + av.y * wv[1].y + av.z * wv[2].y + av.w * wv[3].y;
          acc[i][2] += av.x * wv[0].z + av.y * wv[1].z + av.z * wv[2].z + av.w * wv[3].z;
          acc[i][3] += av.x * wv[0].w + av.y * wv[1].w + av.z * wv[2].w + av.w * wv[3].w;
        }
      }
    }
    float4 bv = *(const float4*)&bl[l][colg];
    if (l < 2) {
      __syncthreads();
#pragma unroll
      for (int i = 0; i < 4; ++i) {
        float4 o = make_float4(gelu_f(acc[i][0] + bv.x), gelu_f(acc[i][1] + bv.y),
                               gelu_f(acc[i][2] + bv.z), gelu_f(acc[i][3] + bv.w));
        *(float4*)&cur[(rowg + i) * 128 + colg] = o;
      }
    } else {
#pragma unroll
      for (int i = 0; i < 4; ++i) {
        acc[i][0] += bv.x; acc[i][1] += bv.y; acc[i][2] += bv.z; acc[i][3] += bv.w;
      }
    }
  }
  // LayerNorm per row (32 lanes hold one row: 4 cols each) + optional score
  float4 gvv = *(const float4*)&g[colg];
  float4 bev = *(const float4*)&beta[colg];
  float4 wv4 = make_float4(0.f, 0.f, 0.f, 0.f);
  if (SCORE) wv4 = *(const float4*)&wnext[colg];
#pragma unroll
  for (int i = 0; i < 4; ++i) {
    float s1 = acc[i][0] + acc[i][1] + acc[i][2] + acc[i][3];
#pragma unroll
    for (int o = 1; o <= 16; o <<= 1) s1 += __shfl_xor(s1, o, 64);
    float mu = s1 * (1.0f / 128.0f);
    float d0 = acc[i][0] - mu, d1 = acc[i][1] - mu, d2 = acc[i][2] - mu, d3 = acc[i][3] - mu;
    float s2 = d0 * d0 + d1 * d1 + d2 * d2 + d3 * d3;
#pragma unroll
    for (int o = 1; o <= 16; o <<= 1) s2 += __shfl_xor(s2, o, 64);
    float rs = rsqrtf(s2 * (1.0f / 128.0f) + 1e-5f);
    int rr = row0 + rowg + i;
    float o0 = gvv.x * d0 * rs + bev.x;
    float o1 = gvv.y * d1 * rs + bev.y;
    float o2 = gvv.z * d2 * rs + bev.z;
    float o3 = gvv.w * d3 * rs + bev.w;
    if (rr < n) {
      *(float4*)&out[(size_t)rr * 128 + colg] = make_float4(o0, o1, o2, o3);
      *(ushort4*)&outbf[(size_t)rr * 128 + colg] =
          make_ushort4(f2bf(o0), f2bf(o1), f2bf(o2), f2bf(o3));
    }
    if (SCORE) {
      double d = (double)o0 * wv4.x + (double)o1 * wv4.y +
                 (double)o2 * wv4.z + (double)o3 * wv4.w;
#pragma unroll
      for (int o = 1; o <= 16; o <<= 1) d += __shfl_xor(d, o, 64);
      if ((t & 31) == 0 && rr < n) {
        key[rr]  = (float)d;
        valt[rr] = (float)tanh(d / sqn[0]);
      }
    }
  }
}

// ---- FUSED up-path MLP: 3x MFMA GEMM (K=256,128,128) + gelu + LN ----------
// Inter-layer bf16 tile lives in LDS cur[64][136] (byte stride 272: 16B
// aligned, 2-way-conflict fragment reads).
template <bool WF32, bool WBF>
__global__ __launch_bounds__(256) void mlp_up_kernel(
    const u16* __restrict__ A,
    const u16* __restrict__ WT1, const float* __restrict__ b1,
    const u16* __restrict__ WT2, const float* __restrict__ b2,
    const u16* __restrict__ WT3, const float* __restrict__ b3,
    const float* __restrict__ g, const float* __restrict__ beta,
    float* __restrict__ out, u16* __restrict__ outbf, int n) {
  __shared__ u16 As[64 * 72];
  __shared__ u16 Ws[128 * 72];
  __shared__ u16 cur[64 * 136];
  int t = threadIdx.x;
  int lane = t & 63, wave = t >> 6;
  int row0 = blockIdx.x * 64;
  int colb = lane & 15, rquad = lane >> 4;
  f32x4 acc[8];

  // ---- layer 1: K=256, A from global ----
#pragma unroll
  for (int i = 0; i < 8; ++i) acc[i] = (f32x4){0.f, 0.f, 0.f, 0.f};
  for (int k0 = 0; k0 < 256; k0 += 64) {
    __syncthreads();
#pragma unroll
    for (int i = 0; i < 2; ++i) {
      int c = t + i * 256;
      int r = c >> 3, seg = c & 7;
      bf16x8 v = {0, 0, 0, 0, 0, 0, 0, 0};
      if (row0 + r < n) v = *(const bf16x8*)&A[(size_t)(row0 + r) * 256 + k0 + seg * 8];
      *(bf16x8*)&As[r * 72 + seg * 8] = v;
    }
#pragma unroll
    for (int i = 0; i < 4; ++i) {
      int c = t + i * 256;
      int r = c >> 3, seg = c & 7;
      *(bf16x8*)&Ws[r * 72 + seg * 8] = *(const bf16x8*)&WT1[(size_t)r * 256 + k0 + seg * 8];
    }
    __syncthreads();
#pragma unroll
    for (int kk = 0; kk < 64; kk += 32) {
      bf16x8 a = *(const bf16x8*)&As[(wave * 16 + (lane & 15)) * 72 + kk + (lane >> 4) * 8];
#pragma unroll
      for (int ct = 0; ct < 8; ++ct) {
        bf16x8 b = *(const bf16x8*)&Ws[(ct * 16 + (lane & 15)) * 72 + kk + (lane >> 4) * 8];
        acc[ct] = __builtin_amdgcn_mfma_f32_16x16x32_bf16(a, b, acc[ct], 0, 0, 0);
      }
    }
  }
  __syncthreads();
#pragma unroll
  for (int ct = 0; ct < 8; ++ct) {
    int col = ct * 16 + colb;
    float bb = b1[col];
#pragma unroll
    for (int r = 0; r < 4; ++r) {
      int row = wave * 16 + rquad * 4 + r;
      cur[row * 136 + col] = f2bf(gelu_f(acc[ct][r] + bb));
    }
  }

  // ---- layer 2: K=128, A from cur ----
#pragma unroll
  for (int i = 0; i < 8; ++i) acc[i] = (f32x4){0.f, 0.f, 0.f, 0.f};
  for (int k0 = 0; k0 < 128; k0 += 64) {
    __syncthreads();
#pragma unroll
    for (int i = 0; i < 4; ++i) {
      int c = t + i * 256;
      int r = c >> 3, seg = c & 7;
      *(bf16x8*)&Ws[r * 72 + seg * 8] = *(const bf16x8*)&WT2[(size_t)r * 128 + k0 + seg * 8];
    }
    __syncthreads();
#pragma unroll
    for (int kk = 0; kk < 64; kk += 32) {
      bf16x8 a = *(const bf16x8*)&cur[(wave * 16 + (lane & 15)) * 136 + k0 + kk + (lane >> 4) * 8];
#pragma unroll
      for (int ct = 0; ct < 8; ++ct) {
        bf16x8 b = *(const bf16x8*)&Ws[(ct * 16 + (lane & 15)) * 72 + kk + (lane >> 4) * 8];
        acc[ct] = __builtin_amdgcn_mfma_f32_16x16x32_bf16(a, b, acc[ct], 0, 0, 0);
      }
    }
  }
  __syncthreads();  // all cur reads done before overwrite
#pragma unroll
  for (int ct = 0; ct < 8; ++ct) {
    int col = ct * 16 + colb;
    float bb = b2[col];
#pragma unroll
    for (int r = 0; r < 4; ++r) {
      int row = wave * 16 + rquad * 4 + r;
      cur[row * 136 + col] = f2bf(gelu_f(acc[ct][r] + bb));
    }
  }

  // ---- layer 3: K=128, A from cur, epilogue LN ----
#pragma unroll
  for (int i = 0; i < 8; ++i) acc[i] = (f32x4){0.f, 0.f, 0.f, 0.f};
  for (int k0 = 0; k0 < 128; k0 += 64) {
    __syncthreads();
#pragma unroll
    for (int i = 0; i < 4; ++i) {
      int c = t + i * 256;
      int r = c >> 3, seg = c & 7;
      *(bf16x8*)&Ws[r * 72 + seg * 8] = *(const bf16x8*)&WT3[(size_t)r * 128 + k0 + seg * 8];
    }
    __syncthreads();
#pragma unroll
    for (int kk = 0; kk < 64; kk += 32) {
      bf16x8 a = *(const bf16x8*)&cur[(wave * 16 + (lane & 15)) * 136 + k0 + kk + (lane >> 4) * 8];
#pragma unroll
      for (int ct = 0; ct < 8; ++ct) {
        bf16x8 b = *(const bf16x8*)&Ws[(ct * 16 + (lane & 15)) * 72 + kk + (lane >> 4) * 8];
        acc[ct] = __builtin_amdgcn_mfma_f32_16x16x32_bf16(a, b, acc[ct], 0, 0, 0);
      }
    }
  }
  float bv[8], gv[8], bev[8];
#pragma unroll
  for (int ct = 0; ct < 8; ++ct) {
    int col = ct * 16 + colb;
    bv[ct] = b3[col]; gv[ct] = g[col]; bev[ct] = beta[col];
  }
#pragma unroll
  for (int r = 0; r < 4; ++r) {
    float s1 = 0.f;
#pragma unroll
    for (int ct = 0; ct < 8; ++ct) s1 += acc[ct][r] + bv[ct];
#pragma unroll
    for (int o = 1; o <= 8; o <<= 1) s1 += __shfl_xor(s1, o, 64);
    float mu = s1 * (1.0f / 128.0f);
    float s2 = 0.f;
#pragma unroll
    for (int ct = 0; ct < 8; ++ct) { float d = acc[ct][r] + bv[ct] - mu; s2 += d * d; }
#pragma unroll
    for (int o = 1; o <= 8; o <<= 1) s2 += __shfl_xor(s2, o, 64);
    float rs = rsqrtf(s2 * (1.0f / 128.0f) + 1e-5f);
    int row = row0 + wave * 16 + rquad * 4 + r;
    if (row < n) {
#pragma unroll
      for (int ct = 0; ct < 8; ++ct) {
        int col = ct * 16 + colb;
        float o = gv[ct] * (acc[ct][r] + bv[ct] - mu) * rs + bev[ct];
        if (WF32) out[(size_t)row * 128 + col] = o;
        if (WBF)  outbf[(size_t)row * 128 + col] = f2bf(o);
      }
    }
  }
}

// ---------------------------------------------------------------------------

static inline int cdiv(int a, int b) { return (a + b - 1) / b; }

extern "C" void kernel_launch(void* const* d_in, const int* in_sizes, int n_in,
                              void* d_out, int out_size, void* d_ws, size_t ws_size,
                              hipStream_t stream) {
  const float* x0   = (const float*)d_in[0];
  const int*   snd  = (const int*)d_in[1];
  const int*   rcv  = (const int*)d_in[2];
  const float* poolw = (const float*)d_in[3];
  const float* dW1 = (const float*)d_in[4];
  const float* db1 = (const float*)d_in[5];
  const float* dW2 = (const float*)d_in[6];
  const float* db2 = (const float*)d_in[7];
  const float* dW3 = (const float*)d_in[8];
  const float* db3 = (const float*)d_in[9];
  const float* dg  = (const float*)d_in[10];
  const float* dbe = (const float*)d_in[11];
  const float* uW1 = (const float*)d_in[12];
  const float* ub1 = (const float*)d_in[13];
  const float* uW2 = (const float*)d_in[14];
  const float* ub2 = (const float*)d_in[15];
  const float* uW3 = (const float*)d_in[16];
  const float* ub3 = (const float*)d_in[17];
  const float* ug  = (const float*)d_in[18];
  const float* ube = (const float*)d_in[19];

  const int N0 = in_sizes[0] / 128;
  const int E  = in_sizes[1];
  const int N1 = (N0 + 1) / 2, N2 = (N1 + 1) / 2, N3 = (N2 + 1) / 2;

  // ---- workspace carve ----
  char* p = (char*)d_ws;
  auto alloc = [&](size_t bytes) -> void* {
    void* r = (void*)p;
    p += (bytes + 255) & ~(size_t)255;
    return r;
  };
  float* key  = (float*)alloc((size_t)N0 * 4);
  float* valt = (float*)alloc((size_t)N0 * 4);
  int*   histAll = (int*)alloc((size_t)3 * HIST_STRIDE * 4);
  int*   meta = (int*)alloc(64 * 4);
  int*   tcnt = (int*)alloc(512 * 4);
  int*   bsum = (int*)alloc(256 * 4);
  int*   nm1 = (int*)alloc((size_t)(N0 + 1) * 4);
  int*   nm2 = (int*)alloc((size_t)(N1 + 1) * 4);
  int*   nm3 = (int*)alloc((size_t)(N2 + 1) * 4);
  int*   perm0 = (int*)alloc((size_t)N1 * 4);
  int*   perm1 = (int*)alloc((size_t)N2 * 4);
  int*   perm2 = (int*)alloc((size_t)N3 * 4);
  float* vals  = (float*)alloc((size_t)N1 * 4);
  double* sqn  = (double*)alloc(8 * 8);
  float* x1 = (float*)alloc((size_t)N1 * 128 * 4);
  float* x2 = (float*)alloc((size_t)N2 * 128 * 4);
  float* x3 = (float*)alloc((size_t)N3 * 128 * 4);
  float* xp = (float*)alloc((size_t)N1 * 128 * 4);
  float* aggf = (float*)alloc((size_t)N1 * 128 * 4);
  u16* agg_bf = (u16*)alloc((size_t)N0 * 256 * 2);
  u16* res0_bf = (u16*)alloc((size_t)N0 * 128 * 2);
  u16* res1_bf = (u16*)alloc((size_t)N1 * 128 * 2);
  u16* res2_bf = (u16*)alloc((size_t)N2 * 128 * 2);
  u16* x3_bf   = (u16*)alloc((size_t)(N3 + 1) * 128 * 2);  // +1 zero row
  u16* xu2_bf  = (u16*)alloc((size_t)(N2 + 1) * 128 * 2);  // +1 zero row
  u16* xu1_bf  = (u16*)alloc((size_t)(N1 + 1) * 128 * 2);  // +1 zero row
  u16* wt1 = (u16*)alloc((size_t)3 * 128 * 256 * 2);
  u16* wt2 = (u16*)alloc((size_t)3 * 128 * 128 * 2);
  u16* wt3 = (u16*)alloc((size_t)3 * 128 * 128 * 2);
  int* degAll = (int*)alloc((size_t)(N0 + N1 + N2 + N3) * 4);
  int* deg0 = degAll;
  int* deg1 = degAll + N0;
  int* deg2 = deg1 + N1;
  int* deg3 = deg2 + N2;
  int* off0 = (int*)alloc((size_t)(N0 + 1) * 4);
  int* idx0 = (int*)alloc((size_t)2 * E * 4);
  int* off1 = (int*)alloc((size_t)(N1 + 1) * 4);
  int* idx1 = (int*)alloc((size_t)2 * E * 4);
  int* off2 = (int*)alloc((size_t)(N2 + 1) * 4);
  int* idx2 = (int*)alloc((size_t)2 * E * 4);
  int* off3 = (int*)alloc((size_t)(N3 + 1) * 4);
  int* idx3 = (int*)alloc((size_t)2 * E * 4);
  int* idxu0 = (int*)alloc((size_t)2 * E * 4);   // remapped idx0 (up lvl 2)
  int* idxu1 = (int*)alloc((size_t)2 * E * 4);   // remapped idx1 (up lvl 1)
  int* idxu2 = (int*)alloc((size_t)2 * E * 4);   // remapped idx2 (up lvl 0)
  int* H = (int*)alloc((size_t)NB * N0 * 4);     // level-0 count/base matrix

  // ---- fused one-time preamble ----
  {
    int nbX = cdiv(N0 * 32, 256);
    int nHist = 3 * HIST_STRIDE;
    int nbHZ = cdiv(nHist, 256);
    preamble_kernel<<<nbX + 768 + 1 + 1 + nbHZ, 256, 0, stream>>>(
        x0, res0_bf, N0, uW1, uW2, uW3, wt1, wt2, wt3, poolw, sqn,
        x3_bf + (size_t)N3 * 128, xu2_bf + (size_t)N2 * 128,
        xu1_bf + (size_t)N1 * 128, histAll, nbX, nbHZ, nHist);
  }

  // ---- level-0 CSR: counting sort with LDS histograms ----
  {
    int nSub = cdiv(N0, SUBR);
    int CH = cdiv(E, NB);
    int nbN = cdiv(N0, 256);
    csr_count_kernel<<<NB * nSub, 256, 0, stream>>>(snd, rcv, H, N0, E, CH);
    colsum_part_kernel<<<nbN, 256, 0, stream>>>(H, deg0, bsum, N0);
    scanfix_kernel<<<nbN, 256, 0, stream>>>(deg0, bsum, off0, H, N0);
    csr_scatter_lds_kernel<<<NB * nSub, 256, 0, stream>>>(snd, rcv, H, idx0, N0, E, CH);
  }

  auto run_scan = [&](int* degB, int* offB, int n) {
    int nb = cdiv(n, 256);
    scan_part_kernel<<<nb, 256, 0, stream>>>(degB, bsum, n);
    scan_final_kernel<<<nb, 256, 0, stream>>>(degB, bsum, offB, n);
  };

  // ---- generic down step: top-k + derived CSR + agg + fused MLP/LN ----
  auto down_step = [&](int n, int k, const float* xcur, int* permL, int* nmL,
                       float* xnext, u16* xnext_bf, int lvl,
                       const int* offP, const int* idxP,
                       int* offL, int* degL, int* idxL) {
    int nb = cdiv(n, 256);
    int* histL = histAll + (size_t)lvl * HIST_STRIDE;
    int* csum_hi = histL + 2 * 65536;
    int* csum_lo = csum_hi + 256;
    hist_hi_kernel<<<nb, 256, 0, stream>>>(key, histL, csum_hi, n);
    find_hi2_kernel<<<1, 256, 0, stream>>>(histL, csum_hi, meta, k);
    hist_lo_kernel<<<nb, 256, 0, stream>>>(key, meta, histL + 65536, csum_lo, n);
    find_lo2_kernel<<<1, 256, 0, stream>>>(histL + 65536, csum_lo, meta);
    tie_count_kernel<<<nb, 256, 0, stream>>>(key, meta, tcnt, n);
    tie_select_kernel<<<cdiv(n + 1, 256), 256, 0, stream>>>(
        key, valt, tcnt, meta, permL, vals, nmL, n, k);
    pool_kernel<<<cdiv(k * 32, 256), 256, 0, stream>>>(xcur, permL, vals, xp, k);
    derive_deg_kernel<<<cdiv(k, 4), 256, 0, stream>>>(permL, nmL, offP, idxP, degL, k);
    run_scan(degL, offL, k);
    derive_fill_kernel<<<cdiv(k, 4), 256, 0, stream>>>(permL, nmL, offP, idxP, offL, idxL, k);
    agg_kernel<<<cdiv(k, 4), 256, 0, stream>>>(xp, offL, idxL, aggf, k);
    if (lvl < 2)
      mlp_down_kernel<true><<<cdiv(k, 32), 256, 0, stream>>>(
          aggf,
          dW1 + (size_t)lvl * 128 * 128, db1 + (size_t)lvl * 128,
          dW2 + (size_t)lvl * 128 * 128, db2 + (size_t)lvl * 128,
          dW3 + (size_t)lvl * 128 * 128, db3 + (size_t)lvl * 128,
          dg + (size_t)lvl * 128, dbe + (size_t)lvl * 128,
          xnext, xnext_bf, poolw + (size_t)(lvl + 1) * 128, sqn + (lvl + 1),
          key, valt, k);
    else
      mlp_down_kernel<false><<<cdiv(k, 32), 256, 0, stream>>>(
          aggf,
          dW1 + (size_t)lvl * 128 * 128, db1 + (size_t)lvl * 128,
          dW2 + (size_t)lvl * 128 * 128, db2 + (size_t)lvl * 128,
          dW3 + (size_t)lvl * 128 * 128, db3 + (size_t)lvl * 128,
          dg + (size_t)lvl * 128, dbe + (size_t)lvl * 128,
          xnext, xnext_bf, nullptr, nullptr, nullptr, nullptr, k);
  };

  // level-0 score from x0
  score_kernel<<<cdiv(N0, 4), 256, 0, stream>>>(x0, poolw, key, valt, N0);
  down_step(N0, N1, x0, perm0, nm1, x1, res1_bf, 0, off0, idx0, off1, deg1, idx1);
  down_step(N1, N2, x1, perm1, nm2, x2, res2_bf, 1, off1, idx1, off2, deg2, idx2);
  down_step(N2, N3, x2, perm2, nm3, x3, x3_bf,   2, off2, idx2, off3, deg3, idx3);

  // ---- remapped up-gather indices (1-hop), fused 3 levels ----
  {
    int nbSeg = cdiv(2 * E, 256);
    idxup3_kernel<<<3 * nbSeg, 256, 0, stream>>>(
        idx2, nm3, off2 + N2, idxu2,
        idx1, nm2, off1 + N1, idxu1,
        idx0, nm1, off0 + N0, idxu0, nbSeg, 2 * E);
  }

  // ---- generic up step (merged gathers + fused MFMA MLP/LN) ----
  auto up_step = [&](int n, const u16* resb, const u16* xdb, int lvl,
                     const int* offL, const int* idxL, const int* idxUL,
                     bool wantF32, float* outF32, u16* outBF) {
    int nbh = cdiv(n, 4);
    agg_gather2_kernel<<<2 * nbh, 256, 0, stream>>>(
        resb, idxL, xdb, idxUL, offL, agg_bf, n, nbh);
    if (wantF32)
      mlp_up_kernel<true, false><<<cdiv(n, 64), 256, 0, stream>>>(
          agg_bf,
          wt1 + (size_t)lvl * 128 * 256, ub1 + (size_t)lvl * 128,
          wt2 + (size_t)lvl * 128 * 128, ub2 + (size_t)lvl * 128,
          wt3 + (size_t)lvl * 128 * 128, ub3 + (size_t)lvl * 128,
          ug + (size_t)lvl * 128, ube + (size_t)lvl * 128,
          outF32, nullptr, n);
    else
      mlp_up_kernel<false, true><<<cdiv(n, 64), 256, 0, stream>>>(
          agg_bf,
          wt1 + (size_t)lvl * 128 * 256, ub1 + (size_t)lvl * 128,
          wt2 + (size_t)lvl * 128 * 128, ub2 + (size_t)lvl * 128,
          wt3 + (size_t)lvl * 128 * 128, ub3 + (size_t)lvl * 128,
          ug + (size_t)lvl * 128, ube + (size_t)lvl * 128,
          nullptr, outBF, n);
  };

  up_step(N2, res2_bf, x3_bf,  0, off2, idx2, idxu2, false, nullptr, xu2_bf);
  up_step(N1, res1_bf, xu2_bf, 1, off1, idx1, idxu1, false, nullptr, xu1_bf);
  up_step(N0, res0_bf, xu1_bf, 2, off0, idx0, idxu0, true, (float*)d_out, nullptr);

  (void)n_in; (void)out_size; (void)ws_size;
}

// Round 12
// 779.745 us; speedup vs baseline: 1.0743x; 1.0530x over previous
//
#include <hip/hip_runtime.h>
#include <math.h>

// ---------------------------------------------------------------------------
// MeshGraphUnet2 forward on gfx950.  Round 19: keep the winning half of the
// round-18 fusion (mlp_up MFMA 3-layer fusion + agg_gather2 + launch trims)
// and REVERT the down-path MLP fusion: mlp_down at lvl0 ran 128us at 8.6%
// occupancy (36KB LDS + 148 VGPR killed TLP) vs ~45us for the separate
// gemm x3 + ln path.  Down path returns to gemm_kernel/ln_kernel (20KB LDS,
// high occupancy, f32-exact for top-k).  Keeps: counting-sort lvl0 CSR,
// derived CSR lvl1-3, dual-table + zero row, idxup3, fused tie_select,
// parallel-scan finds, preamble zeroing, 2-pass scan.
// ---------------------------------------------------------------------------

typedef unsigned short u16;
typedef short bf16x8 __attribute__((ext_vector_type(8)));
typedef float f32x4 __attribute__((ext_vector_type(4)));

#define HIST_STRIDE (2 * 65536 + 512)
#define NB 128       // edge chunks (power of 2)
#define NB_LOG 7
#define SUBR 5000    // node sub-range per LDS histogram (20000 B -> 8 blk/CU)

__device__ __forceinline__ unsigned int fkey(float f) {
  unsigned int b = __float_as_uint(f);
  return (b & 0x80000000u) ? ~b : (b | 0x80000000u);  // monotonic float->uint
}

__device__ __forceinline__ float gelu_f(float v) {
  return 0.5f * v * (1.0f + erff(v * 0.70710678118654752f));
}

__device__ __forceinline__ u16 f2bf(float f) {
  unsigned u = __float_as_uint(f);
  u = (u + 0x7FFFu + ((u >> 16) & 1u)) >> 16;  // round-nearest-even
  return (u16)u;
}
__device__ __forceinline__ float bf2f(u16 u) {
  return __uint_as_float(((unsigned)u) << 16);
}

// ---- level-0 scoring: key[i] = (float)(x[i,:].w) f64, valt = tanh(d/||w||)
__global__ void score_kernel(const float* __restrict__ x, const float* __restrict__ w,
                             float* __restrict__ key, float* __restrict__ valt, int n) {
  int wave = threadIdx.x >> 6, lane = threadIdx.x & 63;
  int i = blockIdx.x * 4 + wave;
  if (i >= n) return;
  float2 xv = *(const float2*)&x[(size_t)i * 128 + lane * 2];
  float2 wv = *(const float2*)&w[lane * 2];
  double d  = (double)xv.x * wv.x + (double)xv.y * wv.y;
  double nw = (double)wv.x * wv.x + (double)wv.y * wv.y;
  for (int o = 32; o; o >>= 1) { d += __shfl_down(d, o, 64); nw += __shfl_down(nw, o, 64); }
  if (lane == 0) {
    key[i]  = (float)d;
    valt[i] = (float)tanh(d / sqrt(nw));
  }
}

// fused one-time preamble: xconv + wconv + wnorm + zero dummy rows +
// zero all 3 hist regions.
__global__ void preamble_kernel(const float* __restrict__ x, u16* __restrict__ xb, int n,
                                const float* __restrict__ uW1, const float* __restrict__ uW2,
                                const float* __restrict__ uW3, u16* __restrict__ wt1,
                                u16* __restrict__ wt2, u16* __restrict__ wt3,
                                const float* __restrict__ poolw, double* __restrict__ sqn,
                                u16* __restrict__ z0, u16* __restrict__ z1,
                                u16* __restrict__ z2, int* __restrict__ histAll,
                                int nbX, int nbHZ, int nHist) {
  int b = blockIdx.x;
  if (b < nbX) {  // xconv
    int gid = b * 256 + threadIdx.x;
    if (gid < n * 32) {
      float4 a = *(const float4*)&x[(size_t)gid * 4];
      *(ushort4*)&xb[(size_t)gid * 4] =
          make_ushort4(f2bf(a.x), f2bf(a.y), f2bf(a.z), f2bf(a.w));
    }
    return;
  }
  b -= nbX;
  if (b < 768) {  // wconv: 3*65536 elements exactly
    int i = b * 256 + threadIdx.x;
    int lvl = i >> 16, rem = i & 65535;
    if (rem < 32768) {  // W1: [256][128] -> [128][256]
      int k = rem >> 7, c = rem & 127;
      wt1[(size_t)lvl * 32768 + c * 256 + k] = f2bf(uW1[(size_t)lvl * 32768 + rem]);
    } else if (rem < 49152) {
      int j = rem - 32768; int k = j >> 7, c = j & 127;
      wt2[(size_t)lvl * 16384 + c * 128 + k] = f2bf(uW2[(size_t)lvl * 16384 + j]);
    } else {
      int j = rem - 49152; int k = j >> 7, c = j & 127;
      wt3[(size_t)lvl * 16384 + c * 128 + k] = f2bf(uW3[(size_t)lvl * 16384 + j]);
    }
    return;
  }
  b -= 768;
  if (b == 0) {  // wnorm (one wave)
    if (threadIdx.x < 64) {
      int lane = threadIdx.x;
      for (int l = 0; l < 3; ++l) {
        float2 wv = *(const float2*)&poolw[l * 128 + lane * 2];
        double nw = (double)wv.x * wv.x + (double)wv.y * wv.y;
        for (int o = 32; o; o >>= 1) nw += __shfl_down(nw, o, 64);
        if (lane == 0) sqn[l] = sqrt(nw);
      }
    }
    return;
  }
  b -= 1;
  if (b == 0) {  // zero dummy rows (128 u16 each)
    int t = threadIdx.x;
    if (t < 128) { z0[t] = 0; z1[t] = 0; z2[t] = 0; }
    return;
  }
  b -= 1;
  {  // zero hist regions
    int i = b * 256 + threadIdx.x;
    if (i < nHist) histAll[i] = 0;
  }
}

// ---- histograms; csum accumulated in LDS per block, flushed with few atomics ----
__global__ void hist_hi_kernel(const float* __restrict__ key, int* __restrict__ hist,
                               int* __restrict__ csum, int n) {
  __shared__ int lc[256];
  lc[threadIdx.x] = 0;
  __syncthreads();
  int i = blockIdx.x * 256 + threadIdx.x;
  if (i < n) {
    unsigned b = fkey(key[i]) >> 16;
    atomicAdd(&hist[b], 1);
    atomicAdd(&lc[b >> 8], 1);
  }
  __syncthreads();
  int v = lc[threadIdx.x];
  if (v) atomicAdd(&csum[threadIdx.x], v);
}

__global__ void hist_lo_kernel(const float* __restrict__ key, const int* __restrict__ meta,
                               int* __restrict__ hist, int* __restrict__ csum, int n) {
  __shared__ int lc[256];
  lc[threadIdx.x] = 0;
  __syncthreads();
  int i = blockIdx.x * 256 + threadIdx.x;
  if (i < n) {
    unsigned u = fkey(key[i]);
    if ((u >> 16) == (unsigned)meta[0]) {
      unsigned b = u & 0xFFFFu;
      atomicAdd(&hist[b], 1);
      atomicAdd(&lc[b >> 8], 1);
    }
  }
  __syncthreads();
  int v = lc[threadIdx.x];
  if (v) atomicAdd(&csum[threadIdx.x], v);
}

// parallel suffix inclusive scan over 256 LDS ints
__device__ __forceinline__ void suffix_scan256(int* sA, int t) {
  for (int o = 1; o < 256; o <<= 1) {
    int add = (t + o < 256) ? sA[t + o] : 0;
    __syncthreads();
    sA[t] += add;
    __syncthreads();
  }
}

__global__ void find_hi2_kernel(const int* __restrict__ hist, const int* __restrict__ csum,
                                int* __restrict__ meta, int k) {
  __shared__ int sA[256];
  __shared__ int cSh, cumSh;
  int t = threadIdx.x;
  sA[t] = csum[t];
  __syncthreads();
  suffix_scan256(sA, t);
  int nxt = (t == 255) ? 0 : sA[t + 1];
  if (sA[t] >= k && nxt < k) { cSh = t; cumSh = nxt; }
  __syncthreads();
  int c = cSh;
  int k2 = k - cumSh;
  sA[t] = hist[c * 256 + t];
  __syncthreads();
  suffix_scan256(sA, t);
  nxt = (t == 255) ? 0 : sA[t + 1];
  if (sA[t] >= k2 && nxt < k2) {
    meta[0] = c * 256 + t;
    meta[1] = k2 - nxt;
  }
}

__global__ void find_lo2_kernel(const int* __restrict__ hist, const int* __restrict__ csum,
                                int* __restrict__ meta) {
  __shared__ int sA[256];
  __shared__ int cSh, cumSh;
  int t = threadIdx.x;
  int m = meta[1], B = meta[0];
  sA[t] = csum[t];
  __syncthreads();
  suffix_scan256(sA, t);
  int nxt = (t == 255) ? 0 : sA[t + 1];
  if (sA[t] >= m && nxt < m) { cSh = t; cumSh = nxt; }
  __syncthreads();
  int c = cSh;
  int m2 = m - cumSh;
  sA[t] = hist[c * 256 + t];
  __syncthreads();
  suffix_scan256(sA, t);
  nxt = (t == 255) ? 0 : sA[t + 1];
  if (sA[t] >= m2 && nxt < m2) {
    meta[3] = (int)((((unsigned)B) << 16) | (unsigned)(c * 256 + t));
    meta[4] = m2 - nxt;
  }
  if (t == 0) meta[5] = 0;
}

__global__ void tie_count_kernel(const float* __restrict__ key, const int* __restrict__ meta,
                                 int* __restrict__ tcnt, int n) {
  __shared__ int cnt[4];
  unsigned uT = (unsigned)meta[3];
  int i = blockIdx.x * 256 + threadIdx.x;
  bool tie = (i < n) && (fkey(key[i]) == uT);
  unsigned long long m = __ballot(tie);
  int lane = threadIdx.x & 63, w = threadIdx.x >> 6;
  if (lane == 0) cnt[w] = __popcll(m);
  __syncthreads();
  if (threadIdx.x == 0) tcnt[blockIdx.x] = cnt[0] + cnt[1] + cnt[2] + cnt[3];
}

// fused tie-mark + select
__global__ void tie_select_kernel(const float* __restrict__ key, const float* __restrict__ valt,
                                  const int* __restrict__ tcnt, int* __restrict__ meta,
                                  int* __restrict__ perm, float* __restrict__ vals,
                                  int* __restrict__ nmap, int n, int k) {
  __shared__ int red[256];
  __shared__ int woff[4];
  int t = threadIdx.x;
  red[t] = (t < (int)blockIdx.x) ? tcnt[t] : 0;
  __syncthreads();
  for (int s = 128; s; s >>= 1) {
    if (t < s) red[t] += red[t + s];
    __syncthreads();
  }
  int blockbase = red[0];
  unsigned uT = (unsigned)meta[3];
  int tsel = meta[4];
  int i = blockIdx.x * 256 + t;
  unsigned u = (i < n) ? fkey(key[i]) : 0u;
  bool tie = (i < n) && (u == uT);
  unsigned long long m = __ballot(tie);
  int lane = t & 63, w = t >> 6;
  if (lane == 0) woff[w] = __popcll(m);
  __syncthreads();
  if (t == 0) {
    int c = 0;
    for (int q = 0; q < 4; ++q) { int v = woff[q]; woff[q] = c; c += v; }
  }
  __syncthreads();
  if (i > n) return;
  if (i == n) { nmap[n] = k; return; }
  bool sel;
  if (tie) {
    int pre = __popcll(m & ((1ull << lane) - 1ull));
    int rank = blockbase + woff[w] + pre;
    sel = (rank < tsel);
  } else {
    sel = (u > uT);
  }
  if (sel) {
    int slot = atomicAdd(&meta[5], 1);
    perm[slot] = i; vals[slot] = valt[i]; nmap[i] = slot;
  } else {
    nmap[i] = k;
  }
}

__global__ void pool_kernel(const float* __restrict__ x, const int* __restrict__ perm,
                            const float* __restrict__ vals, float* __restrict__ xp, int k) {
  int gid = blockIdx.x * 256 + threadIdx.x;
  int t = gid >> 5;
  if (t >= k) return;
  int c = (gid & 31) << 2;
  float v = vals[t];
  float4 a = *(const float4*)&x[(size_t)perm[t] * 128 + c];
  a.x *= v; a.y *= v; a.z *= v; a.w *= v;
  *(float4*)&xp[(size_t)t * 128 + c] = a;
}

// ---- level-0 CSR: deterministic counting sort, 20KB LDS histograms ----
__global__ void csr_count_kernel(const int* __restrict__ s, const int* __restrict__ r,
                                 int* __restrict__ H, int N, int E, int CH) {
  __shared__ int cnt[SUBR];
  int b = blockIdx.x & (NB - 1);
  int sub = blockIdx.x >> NB_LOG;
  int base = sub * SUBR;
  int top = base + SUBR; if (top > N) top = N;
  int span = top - base;
  for (int t = threadIdx.x; t < span; t += 256) cnt[t] = 0;
  __syncthreads();
  int lo = b * CH, hi = lo + CH; if (hi > E) hi = E;
  for (int e = lo + threadIdx.x; e < hi; e += 256) {
    int sv = s[e], rv = r[e];
    if ((unsigned)(rv - base) < (unsigned)span) atomicAdd(&cnt[rv - base], 1);
    if ((unsigned)(sv - base) < (unsigned)span) atomicAdd(&cnt[sv - base], 1);
  }
  __syncthreads();
  int* Hb = H + (size_t)b * N + base;
  for (int t = threadIdx.x; t < span; t += 256) Hb[t] = cnt[t];
}

__global__ void colsum_part_kernel(const int* __restrict__ H, int* __restrict__ deg,
                                   int* __restrict__ bsum, int n) {
  __shared__ int l[256];
  int i = blockIdx.x * 256 + threadIdx.x;
  int v = 0;
  if (i < n) {
#pragma unroll 4
    for (int b = 0; b < NB; ++b) v += H[(size_t)b * n + i];
    deg[i] = v;
  }
  l[threadIdx.x] = (i < n) ? v : 0;
  __syncthreads();
  for (int s = 128; s; s >>= 1) {
    if (threadIdx.x < s) l[threadIdx.x] += l[threadIdx.x + s];
    __syncthreads();
  }
  if (threadIdx.x == 0) bsum[blockIdx.x] = l[0];
}

__global__ void scanfix_kernel(const int* __restrict__ deg, const int* __restrict__ bsum,
                               int* __restrict__ off, int* __restrict__ H, int n) {
  __shared__ int red[256];
  __shared__ int l[256];
  int i = blockIdx.x * 256 + threadIdx.x;
  int t = threadIdx.x;
  red[t] = (t < (int)blockIdx.x) ? bsum[t] : 0;
  __syncthreads();
  for (int s = 128; s; s >>= 1) {
    if (t < s) red[t] += red[t + s];
    __syncthreads();
  }
  int base = red[0];
  int v = (i < n) ? deg[i] : 0;
  l[t] = v;
  __syncthreads();
#pragma unroll
  for (int s = 1; s < 256; s <<= 1) {
    int add = (t >= s) ? l[t - s] : 0;
    __syncthreads();
    l[t] += add;
    __syncthreads();
  }
  int incl = l[t];
  if (i < n) {
    int e = base + incl - v;
    off[i] = e;
    if (i == n - 1) off[n] = base + incl;
    int run = e;
#pragma unroll 4
    for (int b = 0; b < NB; ++b) {
      size_t id = (size_t)b * n + i;
      int tv = H[id];
      H[id] = run;
      run += tv;
    }
  }
}

__global__ void csr_scatter_lds_kernel(const int* __restrict__ s, const int* __restrict__ r,
                                       const int* __restrict__ H, int* __restrict__ idx,
                                       int N, int E, int CH) {
  __shared__ int cnt[SUBR];
  int b = blockIdx.x & (NB - 1);
  int sub = blockIdx.x >> NB_LOG;
  int base = sub * SUBR;
  int top = base + SUBR; if (top > N) top = N;
  int span = top - base;
  for (int t = threadIdx.x; t < span; t += 256) cnt[t] = 0;
  __syncthreads();
  int lo = b * CH, hi = lo + CH; if (hi > E) hi = E;
  const int* Hb = H + (size_t)b * N;
  for (int e = lo + threadIdx.x; e < hi; e += 256) {
    int sv = s[e], rv = r[e];
    if ((unsigned)(rv - base) < (unsigned)span) {
      int loc = atomicAdd(&cnt[rv - base], 1);
      idx[Hb[rv] + loc] = sv;
    }
    if ((unsigned)(sv - base) < (unsigned)span) {
      int loc = atomicAdd(&cnt[sv - base], 1);
      idx[Hb[sv] + loc] = rv;
    }
  }
}

// ---- derived CSR (levels 1-3) ----
__global__ void derive_deg_kernel(const int* __restrict__ permL, const int* __restrict__ nm,
                                  const int* __restrict__ offP, const int* __restrict__ idxP,
                                  int* __restrict__ deg, int k) {
  int wave = threadIdx.x >> 6, lane = threadIdx.x & 63;
  int v = blockIdx.x * 4 + wave;
  if (v >= k) return;
  int p = permL[v];
  int lo = __builtin_amdgcn_readfirstlane(offP[p]);
  int hi = __builtin_amdgcn_readfirstlane(offP[p + 1]);
  int cnt = 0;
  for (int j0 = lo; j0 < hi; j0 += 64) {
    int j = j0 + lane;
    bool ok = (j < hi) && (nm[idxP[j]] < k);
    unsigned long long msk = __ballot(ok);
    cnt += __popcll(msk);
  }
  if (lane == 0) deg[v] = cnt;
}

__global__ void derive_fill_kernel(const int* __restrict__ permL, const int* __restrict__ nm,
                                   const int* __restrict__ offP, const int* __restrict__ idxP,
                                   const int* __restrict__ offL, int* __restrict__ idxL,
                                   int k) {
  int wave = threadIdx.x >> 6, lane = threadIdx.x & 63;
  int v = blockIdx.x * 4 + wave;
  if (v >= k) return;
  int p = permL[v];
  int lo = __builtin_amdgcn_readfirstlane(offP[p]);
  int hi = __builtin_amdgcn_readfirstlane(offP[p + 1]);
  int base = __builtin_amdgcn_readfirstlane(offL[v]);
  for (int j0 = lo; j0 < hi; j0 += 64) {
    int j = j0 + lane;
    int m = k;
    if (j < hi) m = nm[idxP[j]];
    bool ok = m < k;
    unsigned long long msk = __ballot(ok);
    int rank = __popcll(msk & ((1ull << lane) - 1ull));
    if (ok) idxL[base + rank] = m;
    base += __popcll(msk);
  }
}

// ---- 2-pass parallel exclusive scan ----
__global__ void scan_part_kernel(const int* __restrict__ deg, int* __restrict__ bsum, int n) {
  __shared__ int l[256];
  int i = blockIdx.x * 256 + threadIdx.x;
  l[threadIdx.x] = (i < n) ? deg[i] : 0;
  __syncthreads();
  for (int s = 128; s; s >>= 1) {
    if (threadIdx.x < s) l[threadIdx.x] += l[threadIdx.x + s];
    __syncthreads();
  }
  if (threadIdx.x == 0) bsum[blockIdx.x] = l[0];
}

__global__ void scan_final_kernel(const int* __restrict__ deg, const int* __restrict__ bsum,
                                  int* __restrict__ off, int n) {
  __shared__ int red[256];
  __shared__ int l[256];
  int i = blockIdx.x * 256 + threadIdx.x;
  int t = threadIdx.x;
  red[t] = (t < (int)blockIdx.x) ? bsum[t] : 0;
  __syncthreads();
  for (int s = 128; s; s >>= 1) {
    if (t < s) red[t] += red[t + s];
    __syncthreads();
  }
  int base = red[0];
  int v = (i < n) ? deg[i] : 0;
  l[t] = v;
  __syncthreads();
#pragma unroll
  for (int s = 1; s < 256; s <<= 1) {
    int add = (t >= s) ? l[t - s] : 0;
    __syncthreads();
    l[t] += add;
    __syncthreads();
  }
  int incl = l[t];
  if (i < n) {
    int e = base + incl - v;
    off[i] = e;
    if (i == n - 1) off[n] = base + incl;
  }
}

// fused 1-hop remap for the up gather, 3 levels
__global__ void idxup3_kernel(const int* __restrict__ idxA, const int* __restrict__ nmA,
                              const int* __restrict__ lenA, int* __restrict__ outA,
                              const int* __restrict__ idxB, const int* __restrict__ nmB,
                              const int* __restrict__ lenB, int* __restrict__ outB,
                              const int* __restrict__ idxC, const int* __restrict__ nmC,
                              const int* __restrict__ lenC, int* __restrict__ outC,
                              int nbSeg, int maxlen) {
  int seg = blockIdx.x / nbSeg;
  int j = (blockIdx.x - seg * nbSeg) * 256 + threadIdx.x;
  if (j >= maxlen) return;
  const int* idx; const int* nm; const int* len; int* out;
  if (seg == 0)      { idx = idxA; nm = nmA; len = lenA; out = outA; }
  else if (seg == 1) { idx = idxB; nm = nmB; len = lenB; out = outB; }
  else               { idx = idxC; nm = nmC; len = lenC; out = outC; }
  if (j >= len[0]) return;
  out[j] = nm[idx[j]];
}

// ---- down-path f32 aggregation ----
__global__ void agg_kernel(const float* __restrict__ x, const int* __restrict__ off,
                           const int* __restrict__ idx, float* __restrict__ agg, int n) {
  int wave = threadIdx.x >> 6, lane = threadIdx.x & 63;
  int v = blockIdx.x * 4 + wave;
  if (v >= n) return;
  int lo = __builtin_amdgcn_readfirstlane(off[v]);
  int hi = __builtin_amdgcn_readfirstlane(off[v + 1]);
  int g = lane >> 5, sl = lane & 31;
  const float* bp = x + sl * 4;
  float4 acc = {0.f, 0.f, 0.f, 0.f};
#define ACC_F(EE)                                        \
  do {                                                   \
    float4 w_ = *(const float4*)(bp + (size_t)(EE) * 128);\
    acc.x += w_.x; acc.y += w_.y; acc.z += w_.z; acc.w += w_.w; \
  } while (0)
  int j = lo;
  for (; j + 8 <= hi; j += 8) {
    int q0 = idx[j],     q1 = idx[j + 1], q2 = idx[j + 2], q3 = idx[j + 3];
    int q4 = idx[j + 4], q5 = idx[j + 5], q6 = idx[j + 6], q7 = idx[j + 7];
    ACC_F(g ? q1 : q0);
    ACC_F(g ? q3 : q2);
    ACC_F(g ? q5 : q4);
    ACC_F(g ? q7 : q6);
  }
  for (; j + 2 <= hi; j += 2) {
    int q0 = idx[j], q1 = idx[j + 1];
    ACC_F(g ? q1 : q0);
  }
  if (j < hi) {
    int q0 = idx[j];
    if (!g) ACC_F(q0);
  }
#undef ACC_F
  acc.x += __shfl_xor(acc.x, 32, 64);
  acc.y += __shfl_xor(acc.y, 32, 64);
  acc.z += __shfl_xor(acc.z, 32, 64);
  acc.w += __shfl_xor(acc.w, 32, 64);
  if (!g) *(float4*)&agg[(size_t)v * 128 + sl * 4] = acc;
}

// ---- merged up-path gather (res half + up half in one launch) ----
__global__ void agg_gather2_kernel(const u16* __restrict__ tabR, const int* __restrict__ idxR,
                                   const u16* __restrict__ tabU, const int* __restrict__ idxU,
                                   const int* __restrict__ off, u16* __restrict__ agg,
                                   int n, int nbHalf) {
  bool upH = (int)blockIdx.x >= nbHalf;
  int blk = upH ? (int)blockIdx.x - nbHalf : (int)blockIdx.x;
  const u16* tab = upH ? tabU : tabR;
  const int* idx = upH ? idxU : idxR;
  int OFS = upH ? 128 : 0;
  int wave = threadIdx.x >> 6, lane = threadIdx.x & 63;
  int v = blk * 4 + wave;
  if (v >= n) return;
  int lo = __builtin_amdgcn_readfirstlane(off[v]);
  int hi = __builtin_amdgcn_readfirstlane(off[v + 1]);
  int g = lane >> 4, sl = lane & 15;
  const u16* bp = tab + sl * 8;
  float4 a0 = {0.f, 0.f, 0.f, 0.f}, a1 = {0.f, 0.f, 0.f, 0.f};

#define ACC_ROW(EE)                                     \
  do {                                                  \
    uint4 wq = *(const uint4*)(bp + (size_t)(EE) * 128);\
    a0.x += __uint_as_float(wq.x << 16);                \
    a0.y += __uint_as_float(wq.x & 0xffff0000u);        \
    a0.z += __uint_as_float(wq.y << 16);                \
    a0.w += __uint_as_float(wq.y & 0xffff0000u);        \
    a1.x += __uint_as_float(wq.z << 16);                \
    a1.y += __uint_as_float(wq.z & 0xffff0000u);        \
    a1.z += __uint_as_float(wq.w << 16);                \
    a1.w += __uint_as_float(wq.w & 0xffff0000u);        \
  } while (0)

  int j = lo;
  for (; j + 16 <= hi; j += 16) {
    int e0 = idx[j + g];
    int e1 = idx[j + g + 4];
    int e2 = idx[j + g + 8];
    int e3 = idx[j + g + 12];
    ACC_ROW(e0); ACC_ROW(e1); ACC_ROW(e2); ACC_ROW(e3);
  }
  for (; j + 4 <= hi; j += 4) {
    int e0 = idx[j + g];
    ACC_ROW(e0);
  }
  int rmn = hi - j;
  if (g < rmn) {
    int e = idx[j + g];
    ACC_ROW(e);
  }
#undef ACC_ROW

  a0.x += __shfl_xor(a0.x, 16, 64);
  a0.y += __shfl_xor(a0.y, 16, 64);
  a0.z += __shfl_xor(a0.z, 16, 64);
  a0.w += __shfl_xor(a0.w, 16, 64);
  a1.x += __shfl_xor(a1.x, 16, 64);
  a1.y += __shfl_xor(a1.y, 16, 64);
  a1.z += __shfl_xor(a1.z, 16, 64);
  a1.w += __shfl_xor(a1.w, 16, 64);
  a0.x += __shfl_xor(a0.x, 32, 64);
  a0.y += __shfl_xor(a0.y, 32, 64);
  a0.z += __shfl_xor(a0.z, 32, 64);
  a0.w += __shfl_xor(a0.w, 32, 64);
  a1.x += __shfl_xor(a1.x, 32, 64);
  a1.y += __shfl_xor(a1.y, 32, 64);
  a1.z += __shfl_xor(a1.z, 32, 64);
  a1.w += __shfl_xor(a1.w, 32, 64);

  if (lane < 16) {
    bf16x8 ov;
    ov[0] = (short)f2bf(a0.x); ov[1] = (short)f2bf(a0.y);
    ov[2] = (short)f2bf(a0.z); ov[3] = (short)f2bf(a0.w);
    ov[4] = (short)f2bf(a1.x); ov[5] = (short)f2bf(a1.y);
    ov[6] = (short)f2bf(a1.z); ov[7] = (short)f2bf(a1.w);
    *(bf16x8*)&agg[(size_t)v * 256 + OFS + sl * 8] = ov;
  }
}

// ---- down-path f32 GEMM (CIN=128), 32-row tile ----
template <bool GELU>
__global__ __launch_bounds__(256) void gemm_kernel(const float* __restrict__ A,
                                                   const float* __restrict__ W,
                                                   const float* __restrict__ bias,
                                                   float* __restrict__ out, int n) {
  __shared__ float As[32 * 32];
  __shared__ float Ws[32 * 128];
  int t = threadIdx.x;
  int row0 = blockIdx.x * 32;
  int colg = (t & 31) << 2;
  int rowg = (t >> 5) << 2;
  float acc[4][4];
#pragma unroll
  for (int i = 0; i < 4; ++i)
#pragma unroll
    for (int j = 0; j < 4; ++j) acc[i][j] = 0.f;

  for (int k0 = 0; k0 < 128; k0 += 32) {
    __syncthreads();
    {
      int ar = t >> 3, ac = (t & 7) << 2;
      float4 av = make_float4(0.f, 0.f, 0.f, 0.f);
      if (row0 + ar < n) av = *(const float4*)&A[(size_t)(row0 + ar) * 128 + k0 + ac];
      *(float4*)&As[ar * 32 + ac] = av;
    }
#pragma unroll
    for (int l = 0; l < 4; ++l) {
      int id = t + l * 256;
      int kk = id >> 5, wc = (id & 31) << 2;
      *(float4*)&Ws[kk * 128 + wc] = *(const float4*)&W[(size_t)(k0 + kk) * 128 + wc];
    }
    __syncthreads();
#pragma unroll
    for (int kk = 0; kk < 32; kk += 4) {
      float4 wv[4];
#pragma unroll
      for (int j = 0; j < 4; ++j) wv[j] = *(const float4*)&Ws[(kk + j) * 128 + colg];
#pragma unroll
      for (int i = 0; i < 4; ++i) {
        float4 av = *(const float4*)&As[(rowg + i) * 32 + kk];
        acc[i][0] += av.x * wv[0].x + av.y * wv[1].x + av.z * wv[2].x + av.w * wv[3].x;
        acc[i][1] += av.x * wv[0].y + av.y * wv[1].y + av.z * wv[2].y + av.w * wv[3].y;
        acc[i][2] += av.x * wv[0].z + av.y * wv[1].z + av.z * wv[2].z + av.w * wv[3].z;
        acc[i][3] += av.x * wv[0].w + av.y * wv[1].w + av.z * wv[2].w + av.w * wv[3].w;
      }
    }
  }
  float4 bv = *(const float4*)&bias[colg];
#pragma unroll
  for (int i = 0; i < 4; ++i) {
    int rr = row0 + rowg + i;
    if (rr < n) {
      float4 o = make_float4(acc[i][0] + bv.x, acc[i][1] + bv.y, acc[i][2] + bv.z, acc[i][3] + bv.w);
      if (GELU) { o.x = gelu_f(o.x); o.y = gelu_f(o.y); o.z = gelu_f(o.z); o.w = gelu_f(o.w); }
      *(float4*)&out[(size_t)rr * 128 + colg] = o;
    }
  }
}

// ---- down-path LN (+ bf16 copy, + optional fused next-level score) ----
template <bool SCORE, bool WBF>
__global__ void ln_kernel(const float* __restrict__ h, const float* __restrict__ g,
                          const float* __restrict__ beta, float* __restrict__ out,
                          u16* __restrict__ outbf, const float* __restrict__ wnext,
                          const double* __restrict__ sqn, float* __restrict__ key,
                          float* __restrict__ valt, int n) {
  int wave = threadIdx.x >> 6, lane = threadIdx.x & 63;
  int i = blockIdx.x * 4 + wave;
  if (i >= n) return;
  float2 hv = *(const float2*)&h[(size_t)i * 128 + lane * 2];
  float s = hv.x + hv.y;
  for (int o = 32; o; o >>= 1) s += __shfl_down(s, o, 64);
  float mu = __shfl(s, 0, 64) * (1.0f / 128.0f);
  float dx = hv.x - mu, dy = hv.y - mu;
  float q = dx * dx + dy * dy;
  for (int o = 32; o; o >>= 1) q += __shfl_down(q, o, 64);
  float var = __shfl(q, 0, 64) * (1.0f / 128.0f);
  float rs = rsqrtf(var + 1e-5f);
  float2 gv = *(const float2*)&g[lane * 2];
  float2 bv = *(const float2*)&beta[lane * 2];
  float2 o2; o2.x = gv.x * dx * rs + bv.x; o2.y = gv.y * dy * rs + bv.y;
  *(float2*)&out[(size_t)i * 128 + lane * 2] = o2;
  if (WBF)
    *(ushort2*)&outbf[(size_t)i * 128 + lane * 2] = make_ushort2(f2bf(o2.x), f2bf(o2.y));
  if (SCORE) {
    float2 wv = *(const float2*)&wnext[lane * 2];
    double d = (double)o2.x * wv.x + (double)o2.y * wv.y;
    for (int o = 32; o; o >>= 1) d += __shfl_down(d, o, 64);
    if (lane == 0) {
      key[i]  = (float)d;
      valt[i] = (float)tanh(d / sqn[0]);
    }
  }
}

// ---- FUSED up-path MLP: 3x MFMA GEMM (K=256,128,128) + gelu + LN ----------
template <bool WF32, bool WBF>
__global__ __launch_bounds__(256) void mlp_up_kernel(
    const u16* __restrict__ A,
    const u16* __restrict__ WT1, const float* __restrict__ b1,
    const u16* __restrict__ WT2, const float* __restrict__ b2,
    const u16* __restrict__ WT3, const float* __restrict__ b3,
    const float* __restrict__ g, const float* __restrict__ beta,
    float* __restrict__ out, u16* __restrict__ outbf, int n) {
  __shared__ u16 As[64 * 72];
  __shared__ u16 Ws[128 * 72];
  __shared__ u16 cur[64 * 136];
  int t = threadIdx.x;
  int lane = t & 63, wave = t >> 6;
  int row0 = blockIdx.x * 64;
  int colb = lane & 15, rquad = lane >> 4;
  f32x4 acc[8];

  // ---- layer 1: K=256, A from global ----
#pragma unroll
  for (int i = 0; i < 8; ++i) acc[i] = (f32x4){0.f, 0.f, 0.f, 0.f};
  for (int k0 = 0; k0 < 256; k0 += 64) {
    __syncthreads();
#pragma unroll
    for (int i = 0; i < 2; ++i) {
      int c = t + i * 256;
      int r = c >> 3, seg = c & 7;
      bf16x8 v = {0, 0, 0, 0, 0, 0, 0, 0};
      if (row0 + r < n) v = *(const bf16x8*)&A[(size_t)(row0 + r) * 256 + k0 + seg * 8];
      *(bf16x8*)&As[r * 72 + seg * 8] = v;
    }
#pragma unroll
    for (int i = 0; i < 4; ++i) {
      int c = t + i * 256;
      int r = c >> 3, seg = c & 7;
      *(bf16x8*)&Ws[r * 72 + seg * 8] = *(const bf16x8*)&WT1[(size_t)r * 256 + k0 + seg * 8];
    }
    __syncthreads();
#pragma unroll
    for (int kk = 0; kk < 64; kk += 32) {
      bf16x8 a = *(const bf16x8*)&As[(wave * 16 + (lane & 15)) * 72 + kk + (lane >> 4) * 8];
#pragma unroll
      for (int ct = 0; ct < 8; ++ct) {
        bf16x8 b = *(const bf16x8*)&Ws[(ct * 16 + (lane & 15)) * 72 + kk + (lane >> 4) * 8];
        acc[ct] = __builtin_amdgcn_mfma_f32_16x16x32_bf16(a, b, acc[ct], 0, 0, 0);
      }
    }
  }
  __syncthreads();
#pragma unroll
  for (int ct = 0; ct < 8; ++ct) {
    int col = ct * 16 + colb;
    float bb = b1[col];
#pragma unroll
    for (int r = 0; r < 4; ++r) {
      int row = wave * 16 + rquad * 4 + r;
      cur[row * 136 + col] = f2bf(gelu_f(acc[ct][r] + bb));
    }
  }

  // ---- layer 2: K=128, A from cur ----
#pragma unroll
  for (int i = 0; i < 8; ++i) acc[i] = (f32x4){0.f, 0.f, 0.f, 0.f};
  for (int k0 = 0; k0 < 128; k0 += 64) {
    __syncthreads();
#pragma unroll
    for (int i = 0; i < 4; ++i) {
      int c = t + i * 256;
      int r = c >> 3, seg = c & 7;
      *(bf16x8*)&Ws[r * 72 + seg * 8] = *(const bf16x8*)&WT2[(size_t)r * 128 + k0 + seg * 8];
    }
    __syncthreads();
#pragma unroll
    for (int kk = 0; kk < 64; kk += 32) {
      bf16x8 a = *(const bf16x8*)&cur[(wave * 16 + (lane & 15)) * 136 + k0 + kk + (lane >> 4) * 8];
#pragma unroll
      for (int ct = 0; ct < 8; ++ct) {
        bf16x8 b = *(const bf16x8*)&Ws[(ct * 16 + (lane & 15)) * 72 + kk + (lane >> 4) * 8];
        acc[ct] = __builtin_amdgcn_mfma_f32_16x16x32_bf16(a, b, acc[ct], 0, 0, 0);
      }
    }
  }
  __syncthreads();  // all cur reads done before overwrite
#pragma unroll
  for (int ct = 0; ct < 8; ++ct) {
    int col = ct * 16 + colb;
    float bb = b2[col];
#pragma unroll
    for (int r = 0; r < 4; ++r) {
      int row = wave * 16 + rquad * 4 + r;
      cur[row * 136 + col] = f2bf(gelu_f(acc[ct][r] + bb));
    }
  }

  // ---- layer 3: K=128, A from cur, epilogue LN ----
#pragma unroll
  for (int i = 0; i < 8; ++i) acc[i] = (f32x4){0.f, 0.f, 0.f, 0.f};
  for (int k0 = 0; k0 < 128; k0 += 64) {
    __syncthreads();
#pragma unroll
    for (int i = 0; i < 4; ++i) {
      int c = t + i * 256;
      int r = c >> 3, seg = c & 7;
      *(bf16x8*)&Ws[r * 72 + seg * 8] = *(const bf16x8*)&WT3[(size_t)r * 128 + k0 + seg * 8];
    }
    __syncthreads();
#pragma unroll
    for (int kk = 0; kk < 64; kk += 32) {
      bf16x8 a = *(const bf16x8*)&cur[(wave * 16 + (lane & 15)) * 136 + k0 + kk + (lane >> 4) * 8];
#pragma unroll
      for (int ct = 0; ct < 8; ++ct) {
        bf16x8 b = *(const bf16x8*)&Ws[(ct * 16 + (lane & 15)) * 72 + kk + (lane >> 4) * 8];
        acc[ct] = __builtin_amdgcn_mfma_f32_16x16x32_bf16(a, b, acc[ct], 0, 0, 0);
      }
    }
  }
  float bv[8], gv[8], bev[8];
#pragma unroll
  for (int ct = 0; ct < 8; ++ct) {
    int col = ct * 16 + colb;
    bv[ct] = b3[col]; gv[ct] = g[col]; bev[ct] = beta[col];
  }
#pragma unroll
  for (int r = 0; r < 4; ++r) {
    float s1 = 0.f;
#pragma unroll
    for (int ct = 0; ct < 8; ++ct) s1 += acc[ct][r] + bv[ct];
#pragma unroll
    for (int o = 1; o <= 8; o <<= 1) s1 += __shfl_xor(s1, o, 64);
    float mu = s1 * (1.0f / 128.0f);
    float s2 = 0.f;
#pragma unroll
    for (int ct = 0; ct < 8; ++ct) { float d = acc[ct][r] + bv[ct] - mu; s2 += d * d; }
#pragma unroll
    for (int o = 1; o <= 8; o <<= 1) s2 += __shfl_xor(s2, o, 64);
    float rs = rsqrtf(s2 * (1.0f / 128.0f) + 1e-5f);
    int row = row0 + wave * 16 + rquad * 4 + r;
    if (row < n) {
#pragma unroll
      for (int ct = 0; ct < 8; ++ct) {
        int col = ct * 16 + colb;
        float o = gv[ct] * (acc[ct][r] + bv[ct] - mu) * rs + bev[ct];
        if (WF32) out[(size_t)row * 128 + col] = o;
        if (WBF)  outbf[(size_t)row * 128 + col] = f2bf(o);
      }
    }
  }
}

// ---------------------------------------------------------------------------

static inline int cdiv(int a, int b) { return (a + b - 1) / b; }

extern "C" void kernel_launch(void* const* d_in, const int* in_sizes, int n_in,
                              void* d_out, int out_size, void* d_ws, size_t ws_size,
                              hipStream_t stream) {
  const float* x0   = (const float*)d_in[0];
  const int*   snd  = (const int*)d_in[1];
  const int*   rcv  = (const int*)d_in[2];
  const float* poolw = (const float*)d_in[3];
  const float* dW1 = (const float*)d_in[4];
  const float* db1 = (const float*)d_in[5];
  const float* dW2 = (const float*)d_in[6];
  const float* db2 = (const float*)d_in[7];
  const float* dW3 = (const float*)d_in[8];
  const float* db3 = (const float*)d_in[9];
  const float* dg  = (const float*)d_in[10];
  const float* dbe = (const float*)d_in[11];
  const float* uW1 = (const float*)d_in[12];
  const float* ub1 = (const float*)d_in[13];
  const float* uW2 = (const float*)d_in[14];
  const float* ub2 = (const float*)d_in[15];
  const float* uW3 = (const float*)d_in[16];
  const float* ub3 = (const float*)d_in[17];
  const float* ug  = (const float*)d_in[18];
  const float* ube = (const float*)d_in[19];

  const int N0 = in_sizes[0] / 128;
  const int E  = in_sizes[1];
  const int N1 = (N0 + 1) / 2, N2 = (N1 + 1) / 2, N3 = (N2 + 1) / 2;

  // ---- workspace carve ----
  char* p = (char*)d_ws;
  auto alloc = [&](size_t bytes) -> void* {
    void* r = (void*)p;
    p += (bytes + 255) & ~(size_t)255;
    return r;
  };
  float* key  = (float*)alloc((size_t)N0 * 4);
  float* valt = (float*)alloc((size_t)N0 * 4);
  int*   histAll = (int*)alloc((size_t)3 * HIST_STRIDE * 4);
  int*   meta = (int*)alloc(64 * 4);
  int*   tcnt = (int*)alloc(512 * 4);
  int*   bsum = (int*)alloc(256 * 4);
  int*   nm1 = (int*)alloc((size_t)(N0 + 1) * 4);
  int*   nm2 = (int*)alloc((size_t)(N1 + 1) * 4);
  int*   nm3 = (int*)alloc((size_t)(N2 + 1) * 4);
  int*   perm0 = (int*)alloc((size_t)N1 * 4);
  int*   perm1 = (int*)alloc((size_t)N2 * 4);
  int*   perm2 = (int*)alloc((size_t)N3 * 4);
  float* vals  = (float*)alloc((size_t)N1 * 4);
  double* sqn  = (double*)alloc(8 * 8);
  float* x1 = (float*)alloc((size_t)N1 * 128 * 4);
  float* x2 = (float*)alloc((size_t)N2 * 128 * 4);
  float* x3 = (float*)alloc((size_t)N3 * 128 * 4);
  float* xp = (float*)alloc((size_t)N1 * 128 * 4);
  float* aggf = (float*)alloc((size_t)N1 * 128 * 4);
  float* h1f  = (float*)alloc((size_t)N1 * 128 * 4);
  float* h2f  = (float*)alloc((size_t)N1 * 128 * 4);
  u16* agg_bf = (u16*)alloc((size_t)N0 * 256 * 2);
  u16* res0_bf = (u16*)alloc((size_t)N0 * 128 * 2);
  u16* res1_bf = (u16*)alloc((size_t)N1 * 128 * 2);
  u16* res2_bf = (u16*)alloc((size_t)N2 * 128 * 2);
  u16* x3_bf   = (u16*)alloc((size_t)(N3 + 1) * 128 * 2);  // +1 zero row
  u16* xu2_bf  = (u16*)alloc((size_t)(N2 + 1) * 128 * 2);  // +1 zero row
  u16* xu1_bf  = (u16*)alloc((size_t)(N1 + 1) * 128 * 2);  // +1 zero row
  u16* wt1 = (u16*)alloc((size_t)3 * 128 * 256 * 2);
  u16* wt2 = (u16*)alloc((size_t)3 * 128 * 128 * 2);
  u16* wt3 = (u16*)alloc((size_t)3 * 128 * 128 * 2);
  int* degAll = (int*)alloc((size_t)(N0 + N1 + N2 + N3) * 4);
  int* deg0 = degAll;
  int* deg1 = degAll + N0;
  int* deg2 = deg1 + N1;
  int* deg3 = deg2 + N2;
  int* off0 = (int*)alloc((size_t)(N0 + 1) * 4);
  int* idx0 = (int*)alloc((size_t)2 * E * 4);
  int* off1 = (int*)alloc((size_t)(N1 + 1) * 4);
  int* idx1 = (int*)alloc((size_t)2 * E * 4);
  int* off2 = (int*)alloc((size_t)(N2 + 1) * 4);
  int* idx2 = (int*)alloc((size_t)2 * E * 4);
  int* off3 = (int*)alloc((size_t)(N3 + 1) * 4);
  int* idx3 = (int*)alloc((size_t)2 * E * 4);
  int* idxu0 = (int*)alloc((size_t)2 * E * 4);   // remapped idx0 (up lvl 2)
  int* idxu1 = (int*)alloc((size_t)2 * E * 4);   // remapped idx1 (up lvl 1)
  int* idxu2 = (int*)alloc((size_t)2 * E * 4);   // remapped idx2 (up lvl 0)
  int* H = (int*)alloc((size_t)NB * N0 * 4);     // level-0 count/base matrix

  // ---- fused one-time preamble ----
  {
    int nbX = cdiv(N0 * 32, 256);
    int nHist = 3 * HIST_STRIDE;
    int nbHZ = cdiv(nHist, 256);
    preamble_kernel<<<nbX + 768 + 1 + 1 + nbHZ, 256, 0, stream>>>(
        x0, res0_bf, N0, uW1, uW2, uW3, wt1, wt2, wt3, poolw, sqn,
        x3_bf + (size_t)N3 * 128, xu2_bf + (size_t)N2 * 128,
        xu1_bf + (size_t)N1 * 128, histAll, nbX, nbHZ, nHist);
  }

  // ---- level-0 CSR: counting sort with LDS histograms ----
  {
    int nSub = cdiv(N0, SUBR);
    int CH = cdiv(E, NB);
    int nbN = cdiv(N0, 256);
    csr_count_kernel<<<NB * nSub, 256, 0, stream>>>(snd, rcv, H, N0, E, CH);
    colsum_part_kernel<<<nbN, 256, 0, stream>>>(H, deg0, bsum, N0);
    scanfix_kernel<<<nbN, 256, 0, stream>>>(deg0, bsum, off0, H, N0);
    csr_scatter_lds_kernel<<<NB * nSub, 256, 0, stream>>>(snd, rcv, H, idx0, N0, E, CH);
  }

  auto run_scan = [&](int* degB, int* offB, int n) {
    int nb = cdiv(n, 256);
    scan_part_kernel<<<nb, 256, 0, stream>>>(degB, bsum, n);
    scan_final_kernel<<<nb, 256, 0, stream>>>(degB, bsum, offB, n);
  };

  // ---- generic down step: top-k + derived CSR + agg + gemm3 + ln ----
  auto down_step = [&](int n, int k, const float* xcur, int* permL, int* nmL,
                       float* xnext, u16* xnext_bf, int lvl,
                       const int* offP, const int* idxP,
                       int* offL, int* degL, int* idxL) {
    int nb = cdiv(n, 256);
    int* histL = histAll + (size_t)lvl * HIST_STRIDE;
    int* csum_hi = histL + 2 * 65536;
    int* csum_lo = csum_hi + 256;
    hist_hi_kernel<<<nb, 256, 0, stream>>>(key, histL, csum_hi, n);
    find_hi2_kernel<<<1, 256, 0, stream>>>(histL, csum_hi, meta, k);
    hist_lo_kernel<<<nb, 256, 0, stream>>>(key, meta, histL + 65536, csum_lo, n);
    find_lo2_kernel<<<1, 256, 0, stream>>>(histL + 65536, csum_lo, meta);
    tie_count_kernel<<<nb, 256, 0, stream>>>(key, meta, tcnt, n);
    tie_select_kernel<<<cdiv(n + 1, 256), 256, 0, stream>>>(
        key, valt, tcnt, meta, permL, vals, nmL, n, k);
    pool_kernel<<<cdiv(k * 32, 256), 256, 0, stream>>>(xcur, permL, vals, xp, k);
    derive_deg_kernel<<<cdiv(k, 4), 256, 0, stream>>>(permL, nmL, offP, idxP, degL, k);
    run_scan(degL, offL, k);
    derive_fill_kernel<<<cdiv(k, 4), 256, 0, stream>>>(permL, nmL, offP, idxP, offL, idxL, k);
    agg_kernel<<<cdiv(k, 4), 256, 0, stream>>>(xp, offL, idxL, aggf, k);
    gemm_kernel<true><<<cdiv(k, 32), 256, 0, stream>>>(
        aggf, dW1 + (size_t)lvl * 128 * 128, db1 + (size_t)lvl * 128, h1f, k);
    gemm_kernel<true><<<cdiv(k, 32), 256, 0, stream>>>(
        h1f, dW2 + (size_t)lvl * 128 * 128, db2 + (size_t)lvl * 128, h2f, k);
    gemm_kernel<false><<<cdiv(k, 32), 256, 0, stream>>>(
        h2f, dW3 + (size_t)lvl * 128 * 128, db3 + (size_t)lvl * 128, h1f, k);
    if (lvl < 2)
      ln_kernel<true, true><<<cdiv(k, 4), 256, 0, stream>>>(
          h1f, dg + (size_t)lvl * 128, dbe + (size_t)lvl * 128, xnext, xnext_bf,
          poolw + (size_t)(lvl + 1) * 128, sqn + (lvl + 1), key, valt, k);
    else
      ln_kernel<false, true><<<cdiv(k, 4), 256, 0, stream>>>(
          h1f, dg + (size_t)lvl * 128, dbe + (size_t)lvl * 128, xnext, xnext_bf,
          nullptr, nullptr, nullptr, nullptr, k);
  };

  // level-0 score from x0
  score_kernel<<<cdiv(N0, 4), 256, 0, stream>>>(x0, poolw, key, valt, N0);
  down_step(N0, N1, x0, perm0, nm1, x1, res1_bf, 0, off0, idx0, off1, deg1, idx1);
  down_step(N1, N2, x1, perm1, nm2, x2, res2_bf, 1, off1, idx1, off2, deg2, idx2);
  down_step(N2, N3, x2, perm2, nm3, x3, x3_bf,   2, off2, idx2, off3, deg3, idx3);

  // ---- remapped up-gather indices (1-hop), fused 3 levels ----
  {
    int nbSeg = cdiv(2 * E, 256);
    idxup3_kernel<<<3 * nbSeg, 256, 0, stream>>>(
        idx2, nm3, off2 + N2, idxu2,
        idx1, nm2, off1 + N1, idxu1,
        idx0, nm1, off0 + N0, idxu0, nbSeg, 2 * E);
  }

  // ---- generic up step (merged gathers + fused MFMA MLP/LN) ----
  auto up_step = [&](int n, const u16* resb, const u16* xdb, int lvl,
                     const int* offL, const int* idxL, const int* idxUL,
                     bool wantF32, float* outF32, u16* outBF) {
    int nbh = cdiv(n, 4);
    agg_gather2_kernel<<<2 * nbh, 256, 0, stream>>>(
        resb, idxL, xdb, idxUL, offL, agg_bf, n, nbh);
    if (wantF32)
      mlp_up_kernel<true, false><<<cdiv(n, 64), 256, 0, stream>>>(
          agg_bf,
          wt1 + (size_t)lvl * 128 * 256, ub1 + (size_t)lvl * 128,
          wt2 + (size_t)lvl * 128 * 128, ub2 + (size_t)lvl * 128,
          wt3 + (size_t)lvl * 128 * 128, ub3 + (size_t)lvl * 128,
          ug + (size_t)lvl * 128, ube + (size_t)lvl * 128,
          outF32, nullptr, n);
    else
      mlp_up_kernel<false, true><<<cdiv(n, 64), 256, 0, stream>>>(
          agg_bf,
          wt1 + (size_t)lvl * 128 * 256, ub1 + (size_t)lvl * 128,
          wt2 + (size_t)lvl * 128 * 128, ub2 + (size_t)lvl * 128,
          wt3 + (size_t)lvl * 128 * 128, ub3 + (size_t)lvl * 128,
          ug + (size_t)lvl * 128, ube + (size_t)lvl * 128,
          nullptr, outBF, n);
  };

  up_step(N2, res2_bf, x3_bf,  0, off2, idx2, idxu2, false, nullptr, xu2_bf);
  up_step(N1, res1_bf, xu2_bf, 1, off1, idx1, idxu1, false, nullptr, xu1_bf);
  up_step(N0, res0_bf, xu1_bf, 2, off0, idx0, idxu0, true, (float*)d_out, nullptr);

  (void)n_in; (void)out_size; (void)ws_size;
}